// Round 1
// 998.256 us; speedup vs baseline: 1.0096x; 1.0096x over previous
//
#include <hip/hip_runtime.h>
#include <hip/hip_bf16.h>

#define C 128
#define THREADS 256      // 4 waves/block
#define TILE 64          // node rows per block (fp32 kernels)
#define EPW 16           // edges per wave-tile
#define GTILES 8         // tiles per wave, steady-state loop (NOT unrolled)
#define LDSPAD 8
#define LDSW (C + LDSPAD)    // 136 ushorts/row

typedef unsigned short ushortT;
typedef __attribute__((ext_vector_type(8))) short short8;
typedef __attribute__((ext_vector_type(8))) ushortT ushort8;
typedef __attribute__((ext_vector_type(4))) float floatx4;
typedef __attribute__((ext_vector_type(4))) unsigned uintx4;

// ---- bf16 helpers ----
__device__ __forceinline__ ushortT f2bf(float x) {
    union { float f; unsigned u; } v; v.f = x;
    unsigned r = v.u + 0x7FFFu + ((v.u >> 16) & 1u);
    return (ushortT)(r >> 16);
}
__device__ __forceinline__ float bf2f(ushortT h) {
    union { unsigned u; float f; } v; v.u = ((unsigned)h) << 16;
    return v.f;
}
__device__ __forceinline__ float2 upk2(unsigned u) {            // 2x bf16 -> float2
    union { unsigned u; __hip_bfloat162 h; } cv; cv.u = u;
    return __bfloat1622float2(cv.h);
}
__device__ __forceinline__ unsigned pk2(float a, float b) {     // float2 -> 2x bf16 (RNE)
    float2 f; f.x = a; f.y = b;
    union { unsigned u; __hip_bfloat162 h; } cv; cv.h = __float22bfloat162_rn(f);
    return cv.u;
}
// device-scope: sc1, executes at memory-side coherence point (slow fabric RTT)
__device__ __forceinline__ void atomic_add_dev(float* p, float v) {
    __hip_atomic_fetch_add(p, v, __ATOMIC_RELAXED, __HIP_MEMORY_SCOPE_AGENT);
}
// workgroup-scope: no sc1, executes in the issuing XCD's own L2.
// SAFE ONLY on a buffer private to that XCD (per-XCD privatized copies):
// all CUs of one XCD share one L2, so the L2 is the atomic point XCD-wide.
__device__ __forceinline__ void atomic_add_xcd(float* p, float v) {
    __hip_atomic_fetch_add(p, v, __ATOMIC_RELAXED, __HIP_MEMORY_SCOPE_WORKGROUP);
}

// ============================================================================
// fp32 micro-GEMM helpers for node-level kernels
// ============================================================================
__device__ __forceinline__ void zero_acc(float acc[8][4]) {
#pragma unroll
    for (int j = 0; j < 8; ++j)
#pragma unroll
        for (int i = 0; i < 4; ++i) acc[j][i] = 0.f;
}

__device__ __forceinline__ void tile_gemm(const float* __restrict__ s_in,
                                          const float* __restrict__ W,
                                          float acc[8][4], int rg, int oc0)
{
#pragma unroll 2
    for (int kc = 0; kc < C; kc += 4) {
        const float4 w0 = *(const float4*)(W + (kc + 0) * C + oc0);
        const float4 w1 = *(const float4*)(W + (kc + 1) * C + oc0);
        const float4 w2 = *(const float4*)(W + (kc + 2) * C + oc0);
        const float4 w3 = *(const float4*)(W + (kc + 3) * C + oc0);
#pragma unroll
        for (int j = 0; j < 8; ++j) {
            const float4 a = *(const float4*)(s_in + (rg * 8 + j) * C + kc);
            acc[j][0] = fmaf(a.w, w3.x, fmaf(a.z, w2.x, fmaf(a.y, w1.x, fmaf(a.x, w0.x, acc[j][0]))));
            acc[j][1] = fmaf(a.w, w3.y, fmaf(a.z, w2.y, fmaf(a.y, w1.y, fmaf(a.x, w0.y, acc[j][1]))));
            acc[j][2] = fmaf(a.w, w3.z, fmaf(a.z, w2.z, fmaf(a.y, w1.z, fmaf(a.x, w0.z, acc[j][2]))));
            acc[j][3] = fmaf(a.w, w3.w, fmaf(a.z, w2.w, fmaf(a.y, w1.w, fmaf(a.x, w0.w, acc[j][3]))));
        }
    }
}

__device__ __forceinline__ void bias_relu(float acc[8][4], const float* __restrict__ b, int oc0) {
    const float4 bv = *(const float4*)(b + oc0);
#pragma unroll
    for (int j = 0; j < 8; ++j) {
        acc[j][0] = fmaxf(acc[j][0] + bv.x, 0.f);
        acc[j][1] = fmaxf(acc[j][1] + bv.y, 0.f);
        acc[j][2] = fmaxf(acc[j][2] + bv.z, 0.f);
        acc[j][3] = fmaxf(acc[j][3] + bv.w, 0.f);
    }
}

__device__ __forceinline__ void store_tile(float* __restrict__ s, const float acc[8][4], int rg, int oc0) {
#pragma unroll
    for (int j = 0; j < 8; ++j) {
        float4 t; t.x = acc[j][0]; t.y = acc[j][1]; t.z = acc[j][2]; t.w = acc[j][3];
        *(float4*)(s + (rg * 8 + j) * C + oc0) = t;
    }
}

// ============================================================================
// pack 4 weight matrices into MFMA B-fragment order (bf16), f = ks*8+nt
// lane L holds k = ks*32 + (L>>4)*8 + j,  n = nt*16 + (L&15)
// ============================================================================
extern "C" __global__ void pack_w(const float* __restrict__ w0, const float* __restrict__ w1,
                                  const float* __restrict__ w2, const float* __restrict__ w3,
                                  ushortT* __restrict__ out)
{
    const int t = blockIdx.x * 256 + threadIdx.x;      // 65536 threads
    const int j = t & 7, lane = (t >> 3) & 63, f = (t >> 9) & 31, s = t >> 14;
    const float* W = (s == 0) ? w0 : (s == 1) ? w1 : (s == 2) ? w2 : w3;
    const int nt = f & 7, ks = f >> 3;
    const int n = nt * 16 + (lane & 15);
    const int k = ks * 32 + (lane >> 4) * 8 + j;
    out[t] = f2bf(W[k * C + n]);
}

extern "C" __global__ void cvt_bf(const float* __restrict__ in, ushortT* __restrict__ out, int n)
{
    const int t = blockIdx.x * 256 + threadIdx.x;
    if (t < n) out[t] = f2bf(in[t]);
}

// ============================================================================
// kernel 1: h = relu(x@W_in+b_in); q_bf; k_bf; v_bf
// ============================================================================
extern "C" __global__ void __launch_bounds__(THREADS)
node_qkv(const float* __restrict__ x,
         const float* __restrict__ W_in, const float* __restrict__ b_in,
         const float* __restrict__ W_lin, const float* __restrict__ W_src, const float* __restrict__ W_dst,
         ushortT* __restrict__ q_bf, ushortT* __restrict__ k_bf, ushortT* __restrict__ v_bf, int N)
{
    __shared__ __align__(16) float s_in[TILE * C];
    const int tx = threadIdx.x;
    const int rg = tx >> 5;
    const int oc0 = (tx & 31) << 2;
    const int row0 = blockIdx.x * TILE;

#pragma unroll
    for (int j = 0; j < 8; ++j) {
        const int r = rg * 8 + j, n = row0 + r;
        float4 xv; xv.x = xv.y = xv.z = xv.w = 0.f;
        if (n < N) xv = *(const float4*)(x + n * C + oc0);
        *(float4*)(s_in + r * C + oc0) = xv;
    }

    float acc[8][4];
    zero_acc(acc);
    tile_gemm(s_in, W_in, acc, rg, oc0);
    bias_relu(acc, b_in, oc0);
    store_tile(s_in, acc, rg, oc0);          // s_in = h

    ushortT* outs[3];
    const float* Ws[3];
    outs[0] = q_bf; outs[1] = k_bf; outs[2] = v_bf;
    Ws[0] = W_dst;  Ws[1] = W_src;  Ws[2] = W_lin;
#pragma unroll 1
    for (int m = 0; m < 3; ++m) {
        zero_acc(acc);
        tile_gemm(s_in, Ws[m], acc, rg, oc0);
#pragma unroll
        for (int j = 0; j < 8; ++j) {
            const int n = row0 + rg * 8 + j;
            if (n < N) {
                ushort4 t; t.x = f2bf(acc[j][0]); t.y = f2bf(acc[j][1]);
                t.z = f2bf(acc[j][2]); t.w = f2bf(acc[j][3]);
                *(ushort4*)(outs[m] + (size_t)n * C + oc0) = t;
            }
        }
    }
}

// ============================================================================
// kernel 2 (MFMA): line-coherent gathers. Lane mapping: row = lane>>2,
// li = lane&3; per instruction the 4 lanes of a row-group read ONE contiguous
// 64B line (node*256B + i*64B + li*16B) -> 16 lines/inst instead of 64.
// 16 edges/wave-tile, GTILES-deep rolled loop, per-wave LDS slabs, NO barriers.
// A-frag:  A[m=lane&15][k=quad*8+j]     C-frag: C[m=quad*4+r][n=lane&15]
// Epilogue: per-XCD privatized (z,agg) copies + L2-scope atomics when the
// workspace is large enough; agent-scope atomics into a single copy otherwise.
// ============================================================================
__device__ __forceinline__ void gather4(const ushortT* __restrict__ base, int node, int li,
                                        ushort8 dst[4])
{
    const ushort8* p = (const ushort8*)(base + (size_t)node * C) + li;
    dst[0] = p[0]; dst[1] = p[4]; dst[2] = p[8]; dst[3] = p[12];   // chunk i at ushort8 index i*4+li
}

__device__ __forceinline__ void wave_gemm(const ushortT (*A)[LDSW],
                                          const ushortT* __restrict__ Bp,
                                          int quad, int m16, int lane,
                                          floatx4 acc[8])
{
#pragma unroll
    for (int nt = 0; nt < 8; ++nt) { acc[nt][0]=0.f; acc[nt][1]=0.f; acc[nt][2]=0.f; acc[nt][3]=0.f; }
#pragma unroll 1
    for (int ks = 0; ks < 4; ++ks) {
        const short8 af = *(const short8*)&A[m16][ks * 32 + quad * 8];
        const ushortT* bpk = Bp + (size_t)ks * 4096 + (size_t)lane * 8;
#pragma unroll
        for (int nt = 0; nt < 8; ++nt) {
            const short8 bf = *(const short8*)(bpk + nt * 512);
            acc[nt] = __builtin_amdgcn_mfma_f32_16x16x32_bf16(af, bf, acc[nt], 0, 0, 0);
        }
    }
}

__device__ __forceinline__ void cstore_relu_r(ushortT (*A)[LDSW], floatx4 acc[8],
                                              const float bias[8], int quad, int m16)
{
#pragma unroll
    for (int nt = 0; nt < 8; ++nt) {
        const float b = bias[nt];
#pragma unroll
        for (int r = 0; r < 4; r += 2) {
            const unsigned p = pk2(fmaxf(acc[nt][r] + b, 0.f), fmaxf(acc[nt][r + 1] + b, 0.f));
            A[quad * 4 + r][nt * 16 + m16]     = (ushortT)(p & 0xffffu);
            A[quad * 4 + r + 1][nt * 16 + m16] = (ushortT)(p >> 16);
        }
    }
}

extern "C" __global__ void __launch_bounds__(THREADS)
edge_mfma(const ushortT* __restrict__ pos_bf, const int* __restrict__ ei,
          const ushortT* __restrict__ q_bf, const ushortT* __restrict__ k_bf,
          const ushortT* __restrict__ v_bf, const ushortT* __restrict__ Bpack,
          const float* __restrict__ pb1, const float* __restrict__ pb2,
          const float* __restrict__ ab1, const float* __restrict__ ab2,
          float* __restrict__ acc_base, unsigned long long NCs, int use_priv, int E)
{
    __shared__ ushortT Aslab[4][EPW][LDSW];   // 17.4 KB
    __shared__ ushortT Vslab[4][EPW][LDSW];   // 17.4 KB
    const int tid = threadIdx.x;
    const int wv = tid >> 6, lane = tid & 63;
    const int quad = lane >> 4, m16 = lane & 15;
    const int row = lane >> 2, li = lane & 3;      // line-coherent staging mapping
    ushortT (*A)[LDSW] = Aslab[wv];
    ushortT (*V)[LDSW] = Vslab[wv];

    // select accumulator copy: physical XCD id -> private (z,agg) pair.
    // HW_REG_XCC_ID verified on gfx950 (returns 0..7).
    float* zarr = acc_base;
    if (use_priv) {
        unsigned xcc;
        asm volatile("s_getreg_b32 %0, hwreg(HW_REG_XCC_ID, 0, 32)" : "=s"(xcc));
        zarr = acc_base + (size_t)(xcc & 7) * (2 * NCs);
    }
    float* garr = zarr + NCs;

    // tile-invariant: biases in registers
    float pb1v[8], pb2v[8], ab1v[8], ab2v[8];
#pragma unroll
    for (int nt = 0; nt < 8; ++nt) {
        pb1v[nt] = pb1[nt * 16 + m16]; pb2v[nt] = pb2[nt * 16 + m16];
        ab1v[nt] = ab1[nt * 16 + m16]; ab2v[nt] = ab2[nt * 16 + m16];
    }

    const ushortT* B0 = Bpack;
    const ushortT* B1 = Bpack + 16384;
    const ushortT* B2 = Bpack + 32768;
    const ushortT* B3 = Bpack + 49152;

    const int wave_base = (blockIdx.x * 4 + wv) * (GTILES * EPW);

#pragma unroll 1
    for (int t = 0; t < GTILES; ++t) {
        const int e_base = wave_base + t * EPW;
        const int eidx = min(e_base + row, E - 1);
        const int es = ei[eidx], ed = ei[E + eidx];
        int sdr[4];
#pragma unroll
        for (int r = 0; r < 4; ++r)
            sdr[r] = ei[E + min(e_base + quad * 4 + r, E - 1)];

        ushort8 Pd[4], Ps[4], Qv[4], Kv[4], Vv[4];
        gather4(pos_bf, ed, li, Pd); gather4(pos_bf, es, li, Ps);
        gather4(q_bf,  ed, li, Qv); gather4(k_bf,  es, li, Kv);
        gather4(v_bf,  es, li, Vv);

        // ---- A0 = bf16(pos[dst] - pos[src]); stage v into Vslab ----
        // lane's chunk i lives at ushort offset i*32 + li*8 within the row
#pragma unroll
        for (int i = 0; i < 4; ++i) {
            const uintx4 pd = *(const uintx4*)&Pd[i];
            const uintx4 ps = *(const uintx4*)&Ps[i];
            uintx4 o;
#pragma unroll
            for (int w = 0; w < 4; ++w) {
                const float2 a = upk2(pd[w]), b = upk2(ps[w]);
                o[w] = pk2(a.x - b.x, a.y - b.y);
            }
            *(uintx4*)&A[row][i * 32 + li * 8] = o;
            *(ushort8*)&V[row][i * 32 + li * 8] = Vv[i];
        }

        floatx4 acc[8];

        // ---- pos_nn layer 1 ----
        wave_gemm(A, B0, quad, m16, lane, acc);
        cstore_relu_r(A, acc, pb1v, quad, m16);

        // ---- pos_nn layer 2 -> delta (packed regs + slab) ----
        wave_gemm(A, B1, quad, m16, lane, acc);
        unsigned dlp[8][2];
#pragma unroll
        for (int nt = 0; nt < 8; ++nt) {
            const float b = pb2v[nt];
            const unsigned p0 = pk2(fmaxf(acc[nt][0] + b, 0.f), fmaxf(acc[nt][1] + b, 0.f));
            const unsigned p1 = pk2(fmaxf(acc[nt][2] + b, 0.f), fmaxf(acc[nt][3] + b, 0.f));
            dlp[nt][0] = p0; dlp[nt][1] = p1;
            A[quad * 4 + 0][nt * 16 + m16] = (ushortT)(p0 & 0xffffu);
            A[quad * 4 + 1][nt * 16 + m16] = (ushortT)(p0 >> 16);
            A[quad * 4 + 2][nt * 16 + m16] = (ushortT)(p1 & 0xffffu);
            A[quad * 4 + 3][nt * 16 + m16] = (ushortT)(p1 >> 16);
        }

        // ---- A2 = bf16( q[dst] - k[src] + delta ) ----
#pragma unroll
        for (int i = 0; i < 4; ++i) {
            const uintx4 dv = *(const uintx4*)&A[row][i * 32 + li * 8];
            const uintx4 qv = *(const uintx4*)&Qv[i];
            const uintx4 kv = *(const uintx4*)&Kv[i];
            uintx4 o;
#pragma unroll
            for (int w = 0; w < 4; ++w) {
                const float2 qq = upk2(qv[w]), kk = upk2(kv[w]), dd = upk2(dv[w]);
                o[w] = pk2(qq.x - kk.x + dd.x, qq.y - kk.y + dd.y);
            }
            *(uintx4*)&A[row][i * 32 + li * 8] = o;
        }

        // ---- attn_nn layer 1 ----
        wave_gemm(A, B2, quad, m16, lane, acc);
        cstore_relu_r(A, acc, ab1v, quad, m16);

        // ---- attn_nn layer 2 -> ea = exp(relu(alpha+b)) ----
        wave_gemm(A, B3, quad, m16, lane, acc);
#pragma unroll
        for (int nt = 0; nt < 8; ++nt) {
            const float b = ab2v[nt];
#pragma unroll
            for (int r = 0; r < 4; ++r)
                acc[nt][r] = __expf(fmaxf(acc[nt][r] + b, 0.f));  // alpha>=0, O(1): no max-shift
        }

        // ---- zero ea for out-of-range edges ----
        if (e_base + EPW > E) {
#pragma unroll
            for (int r = 0; r < 4; ++r)
                if (e_base + quad * 4 + r >= E) {
#pragma unroll
                    for (int nt = 0; nt < 8; ++nt) acc[nt][r] = 0.f;
                }
        }

        // ---- epilogue: z += ea; agg += ea*(v+delta) ----
        if (use_priv) {
#pragma unroll
            for (int r = 0; r < 4; ++r) {
                float* zp = zarr + (size_t)sdr[r] * C + m16;
                float* gp = garr + (size_t)sdr[r] * C + m16;
#pragma unroll
                for (int nt = 0; nt < 8; ++nt) {
                    const float ea  = acc[nt][r];
                    const float2 dpair = upk2(dlp[nt][r >> 1]);
                    const float dlv = (r & 1) ? dpair.y : dpair.x;
                    const float vv  = bf2f(V[quad * 4 + r][nt * 16 + m16]);
                    atomic_add_xcd(zp + nt * 16, ea);
                    atomic_add_xcd(gp + nt * 16, ea * (vv + dlv));
                }
            }
        } else {
#pragma unroll
            for (int r = 0; r < 4; ++r) {
                float* zp = zarr + (size_t)sdr[r] * C + m16;
                float* gp = garr + (size_t)sdr[r] * C + m16;
#pragma unroll
                for (int nt = 0; nt < 8; ++nt) {
                    const float ea  = acc[nt][r];
                    const float2 dpair = upk2(dlp[nt][r >> 1]);
                    const float dlv = (r & 1) ? dpair.y : dpair.x;
                    const float vv  = bf2f(V[quad * 4 + r][nt * 16 + m16]);
                    atomic_add_dev(zp + nt * 16, ea);
                    atomic_add_dev(gp + nt * 16, ea * (vv + dlv));
                }
            }
        }
    }
}

// ============================================================================
// kernel 3: out = relu( (sum_x agg_x / (sum_x z_x + 1e-16)) @ W_out + b_out )
// ============================================================================
extern "C" __global__ void __launch_bounds__(THREADS)
out_kernel(const float* __restrict__ acc_base, unsigned long long NCs, int XC,
           const float* __restrict__ W_out, const float* __restrict__ b_out,
           float* __restrict__ out, int N)
{
    __shared__ __align__(16) float s_in[TILE * C];
    const int tx = threadIdx.x;
    const int rg = tx >> 5;
    const int oc0 = (tx & 31) << 2;
    const int row0 = blockIdx.x * TILE;

#pragma unroll
    for (int j = 0; j < 8; ++j) {
        const int r = rg * 8 + j, n = row0 + r;
        float4 a; a.x = a.y = a.z = a.w = 0.f;
        if (n < N) {
            float gx = 0.f, gy = 0.f, gz = 0.f, gw = 0.f;
            float zx = 0.f, zy = 0.f, zz = 0.f, zw = 0.f;
#pragma unroll 1
            for (int x = 0; x < XC; ++x) {
                const float* base = acc_base + (size_t)x * 2 * NCs;
                const float4 g  = *(const float4*)(base + NCs + (size_t)n * C + oc0);
                const float4 zv = *(const float4*)(base + (size_t)n * C + oc0);
                gx += g.x;  gy += g.y;  gz += g.z;  gw += g.w;
                zx += zv.x; zy += zv.y; zz += zv.z; zw += zv.w;
            }
            a.x = gx / (zx + 1e-16f);
            a.y = gy / (zy + 1e-16f);
            a.z = gz / (zz + 1e-16f);
            a.w = gw / (zw + 1e-16f);
        }
        *(float4*)(s_in + r * C + oc0) = a;
    }

    float acc[8][4];
    zero_acc(acc);
    tile_gemm(s_in, W_out, acc, rg, oc0);
    bias_relu(acc, b_out, oc0);
#pragma unroll
    for (int j = 0; j < 8; ++j) {
        const int n = row0 + rg * 8 + j;
        if (n < N) { float4 t; t.x=acc[j][0]; t.y=acc[j][1]; t.z=acc[j][2]; t.w=acc[j][3];
                     *(float4*)(out + (size_t)n * C + oc0) = t; }
    }
}

// ---------------------------------------------------------------------------
extern "C" void kernel_launch(void* const* d_in, const int* in_sizes, int n_in,
                              void* d_out, int out_size, void* d_ws, size_t ws_size,
                              hipStream_t stream)
{
    const float* x     = (const float*)d_in[0];
    const float* pos   = (const float*)d_in[1];
    const int*   ei    = (const int*)  d_in[2];
    const float* W_in  = (const float*)d_in[3];
    const float* b_in  = (const float*)d_in[4];
    const float* W_lin = (const float*)d_in[5];
    const float* W_src = (const float*)d_in[6];
    const float* W_dst = (const float*)d_in[7];
    const float* pw1   = (const float*)d_in[8];
    const float* pb1   = (const float*)d_in[9];
    const float* pw2   = (const float*)d_in[10];
    const float* pb2   = (const float*)d_in[11];
    const float* aw1   = (const float*)d_in[12];
    const float* ab1   = (const float*)d_in[13];
    const float* aw2   = (const float*)d_in[14];
    const float* ab2   = (const float*)d_in[15];
    const float* W_out = (const float*)d_in[16];
    const float* b_out = (const float*)d_in[17];

    const int N = in_sizes[0] / C;
    const int E = in_sizes[2] / 2;
    const size_t NC = (size_t)N * C;

    // workspace: [XC][2][N][C] f32 accumulators, then bf16 q/k/v/pos, then Bpack
    const size_t need_priv = 16 * NC * sizeof(float)      // 8 copies x (z, agg)
                           + 4 * NC * sizeof(ushortT)     // q/k/v/pos bf16
                           + 65536 * sizeof(ushortT);     // Bpack
    const int use_priv = (ws_size >= need_priv) ? 1 : 0;
    const int XC = use_priv ? 8 : 1;

    float*   acc_b  = (float*)d_ws;                          // [XC][2*NC]
    ushortT* q_bf   = (ushortT*)(acc_b + (size_t)2 * NC * XC);
    ushortT* k_bf   = q_bf + NC;
    ushortT* v_bf   = k_bf + NC;
    ushortT* pos_bf = v_bf + NC;
    ushortT* Bpack  = pos_bf + NC;                           // 65536 bf16 = 128 KB

    hipMemsetAsync(acc_b, 0, (size_t)2 * NC * XC * sizeof(float), stream);

    pack_w<<<256, 256, 0, stream>>>(pw1, pw2, aw1, aw2, Bpack);
    cvt_bf<<<((int)NC + 255) / 256, 256, 0, stream>>>(pos, pos_bf, (int)NC);

    const int nb = (N + TILE - 1) / TILE;
    const int edges_per_block = 4 * GTILES * EPW;            // 512
    const int eb = (E + edges_per_block - 1) / edges_per_block;

    node_qkv<<<nb, THREADS, 0, stream>>>(x, W_in, b_in, W_lin, W_src, W_dst, q_bf, k_bf, v_bf, N);
    edge_mfma<<<eb, THREADS, 0, stream>>>(pos_bf, ei, q_bf, k_bf, v_bf, Bpack,
                                          pb1, pb2, ab1, ab2,
                                          acc_b, (unsigned long long)NC, use_priv, E);
    out_kernel<<<nb, THREADS, 0, stream>>>(acc_b, (unsigned long long)NC, XC,
                                           W_out, b_out, (float*)d_out, N);
}

// Round 2
// 806.225 us; speedup vs baseline: 1.2501x; 1.2382x over previous
//
#include <hip/hip_runtime.h>
#include <hip/hip_bf16.h>

#define C 128
#define THREADS 256      // 4 waves/block
#define TILE 64          // node rows per block (fp32 kernels)
#define EPW 16           // edges per wave-tile
#define GTILES 8         // tiles per wave, steady-state loop (NOT unrolled)
#define LDSPAD 8
#define LDSW (C + LDSPAD)    // 136 ushorts/row

typedef unsigned short ushortT;
typedef __attribute__((ext_vector_type(8))) short short8;
typedef __attribute__((ext_vector_type(8))) ushortT ushort8;
typedef __attribute__((ext_vector_type(4))) float floatx4;
typedef __attribute__((ext_vector_type(4))) unsigned uintx4;

// ---- bf16 helpers ----
__device__ __forceinline__ ushortT f2bf(float x) {
    union { float f; unsigned u; } v; v.f = x;
    unsigned r = v.u + 0x7FFFu + ((v.u >> 16) & 1u);
    return (ushortT)(r >> 16);
}
__device__ __forceinline__ float bf2f(ushortT h) {
    union { unsigned u; float f; } v; v.u = ((unsigned)h) << 16;
    return v.f;
}
__device__ __forceinline__ float2 upk2(unsigned u) {            // 2x bf16 -> float2
    union { unsigned u; __hip_bfloat162 h; } cv; cv.u = u;
    return __bfloat1622float2(cv.h);
}
__device__ __forceinline__ unsigned pk2(float a, float b) {     // float2 -> 2x bf16 (RNE)
    float2 f; f.x = a; f.y = b;
    union { unsigned u; __hip_bfloat162 h; } cv; cv.h = __float22bfloat162_rn(f);
    return cv.u;
}
__device__ __forceinline__ void atomic_add_f32(float* p, float v) {
    __hip_atomic_fetch_add(p, v, __ATOMIC_RELAXED, __HIP_MEMORY_SCOPE_AGENT);
}

// ============================================================================
// fp32 micro-GEMM helpers for node-level kernels
// ============================================================================
__device__ __forceinline__ void zero_acc(float acc[8][4]) {
#pragma unroll
    for (int j = 0; j < 8; ++j)
#pragma unroll
        for (int i = 0; i < 4; ++i) acc[j][i] = 0.f;
}

__device__ __forceinline__ void tile_gemm(const float* __restrict__ s_in,
                                          const float* __restrict__ W,
                                          float acc[8][4], int rg, int oc0)
{
#pragma unroll 2
    for (int kc = 0; kc < C; kc += 4) {
        const float4 w0 = *(const float4*)(W + (kc + 0) * C + oc0);
        const float4 w1 = *(const float4*)(W + (kc + 1) * C + oc0);
        const float4 w2 = *(const float4*)(W + (kc + 2) * C + oc0);
        const float4 w3 = *(const float4*)(W + (kc + 3) * C + oc0);
#pragma unroll
        for (int j = 0; j < 8; ++j) {
            const float4 a = *(const float4*)(s_in + (rg * 8 + j) * C + kc);
            acc[j][0] = fmaf(a.w, w3.x, fmaf(a.z, w2.x, fmaf(a.y, w1.x, fmaf(a.x, w0.x, acc[j][0]))));
            acc[j][1] = fmaf(a.w, w3.y, fmaf(a.z, w2.y, fmaf(a.y, w1.y, fmaf(a.x, w0.y, acc[j][1]))));
            acc[j][2] = fmaf(a.w, w3.z, fmaf(a.z, w2.z, fmaf(a.y, w1.z, fmaf(a.x, w0.z, acc[j][2]))));
            acc[j][3] = fmaf(a.w, w3.w, fmaf(a.z, w2.w, fmaf(a.y, w1.w, fmaf(a.x, w0.w, acc[j][3]))));
        }
    }
}

__device__ __forceinline__ void bias_relu(float acc[8][4], const float* __restrict__ b, int oc0) {
    const float4 bv = *(const float4*)(b + oc0);
#pragma unroll
    for (int j = 0; j < 8; ++j) {
        acc[j][0] = fmaxf(acc[j][0] + bv.x, 0.f);
        acc[j][1] = fmaxf(acc[j][1] + bv.y, 0.f);
        acc[j][2] = fmaxf(acc[j][2] + bv.z, 0.f);
        acc[j][3] = fmaxf(acc[j][3] + bv.w, 0.f);
    }
}

__device__ __forceinline__ void store_tile(float* __restrict__ s, const float acc[8][4], int rg, int oc0) {
#pragma unroll
    for (int j = 0; j < 8; ++j) {
        float4 t; t.x = acc[j][0]; t.y = acc[j][1]; t.z = acc[j][2]; t.w = acc[j][3];
        *(float4*)(s + (rg * 8 + j) * C + oc0) = t;
    }
}

// ============================================================================
// edge sort by dst: histogram -> exclusive scan -> scatter (counting sort)
// ============================================================================
extern "C" __global__ void k_hist(const int* __restrict__ ei, int* __restrict__ deg, int E)
{
    const int e = blockIdx.x * 256 + threadIdx.x;
    if (e < E) atomicAdd(&deg[ei[E + e]], 1);
}

extern "C" __global__ void __launch_bounds__(1024)
k_scan(const int* __restrict__ deg, int* __restrict__ off, int n)
{
    __shared__ int part[1024];
    const int t = threadIdx.x;
    const int chunk = (n + 1023) / 1024;
    const int lo = t * chunk, hi = min(lo + chunk, n);
    int s = 0;
    for (int i = lo; i < hi; ++i) s += deg[i];
    part[t] = s;
    __syncthreads();
    for (int d = 1; d < 1024; d <<= 1) {
        int v = (t >= d) ? part[t - d] : 0;
        __syncthreads();
        part[t] += v;
        __syncthreads();
    }
    int run = (t == 0) ? 0 : part[t - 1];
    for (int i = lo; i < hi; ++i) { off[i] = run; run += deg[i]; }
}

extern "C" __global__ void k_scatter(const int* __restrict__ ei, const int* __restrict__ off,
                                     int* __restrict__ cur, int* __restrict__ ss,
                                     int* __restrict__ sd, int E)
{
    const int e = blockIdx.x * 256 + threadIdx.x;
    if (e < E) {
        const int d = ei[E + e];
        const int p = off[d] + atomicAdd(&cur[d], 1);
        ss[p] = ei[e];
        sd[p] = d;
    }
}

// ============================================================================
// pack 4 weight matrices into MFMA B-fragment order (bf16), f = ks*8+nt
// ============================================================================
extern "C" __global__ void pack_w(const float* __restrict__ w0, const float* __restrict__ w1,
                                  const float* __restrict__ w2, const float* __restrict__ w3,
                                  ushortT* __restrict__ out)
{
    const int t = blockIdx.x * 256 + threadIdx.x;      // 65536 threads
    const int j = t & 7, lane = (t >> 3) & 63, f = (t >> 9) & 31, s = t >> 14;
    const float* W = (s == 0) ? w0 : (s == 1) ? w1 : (s == 2) ? w2 : w3;
    const int nt = f & 7, ks = f >> 3;
    const int n = nt * 16 + (lane & 15);
    const int k = ks * 32 + (lane >> 4) * 8 + j;
    out[t] = f2bf(W[k * C + n]);
}

extern "C" __global__ void cvt_bf(const float* __restrict__ in, ushortT* __restrict__ out, int n)
{
    const int t = blockIdx.x * 256 + threadIdx.x;
    if (t < n) out[t] = f2bf(in[t]);
}

// ============================================================================
// kernel 1: h = relu(x@W_in+b_in); q_bf; k_bf; v_bf
// ============================================================================
extern "C" __global__ void __launch_bounds__(THREADS)
node_qkv(const float* __restrict__ x,
         const float* __restrict__ W_in, const float* __restrict__ b_in,
         const float* __restrict__ W_lin, const float* __restrict__ W_src, const float* __restrict__ W_dst,
         ushortT* __restrict__ q_bf, ushortT* __restrict__ k_bf, ushortT* __restrict__ v_bf, int N)
{
    __shared__ __align__(16) float s_in[TILE * C];
    const int tx = threadIdx.x;
    const int rg = tx >> 5;
    const int oc0 = (tx & 31) << 2;
    const int row0 = blockIdx.x * TILE;

#pragma unroll
    for (int j = 0; j < 8; ++j) {
        const int r = rg * 8 + j, n = row0 + r;
        float4 xv; xv.x = xv.y = xv.z = xv.w = 0.f;
        if (n < N) xv = *(const float4*)(x + n * C + oc0);
        *(float4*)(s_in + r * C + oc0) = xv;
    }

    float acc[8][4];
    zero_acc(acc);
    tile_gemm(s_in, W_in, acc, rg, oc0);
    bias_relu(acc, b_in, oc0);
    store_tile(s_in, acc, rg, oc0);          // s_in = h

    ushortT* outs[3];
    const float* Ws[3];
    outs[0] = q_bf; outs[1] = k_bf; outs[2] = v_bf;
    Ws[0] = W_dst;  Ws[1] = W_src;  Ws[2] = W_lin;
#pragma unroll 1
    for (int m = 0; m < 3; ++m) {
        zero_acc(acc);
        tile_gemm(s_in, Ws[m], acc, rg, oc0);
#pragma unroll
        for (int j = 0; j < 8; ++j) {
            const int n = row0 + rg * 8 + j;
            if (n < N) {
                ushort4 t; t.x = f2bf(acc[j][0]); t.y = f2bf(acc[j][1]);
                t.z = f2bf(acc[j][2]); t.w = f2bf(acc[j][3]);
                *(ushort4*)(outs[m] + (size_t)n * C + oc0) = t;
            }
        }
    }
}

// ============================================================================
// kernel 2 (MFMA): edges SORTED BY DST. Same MFMA pipeline; epilogue is a
// per-lane 2-channel segmented scan over the sorted edges (transpose ea and
// v+delta through the LDS slabs), with run-carry across the GTILES loop.
// Atomics only at run boundaries: ~#distinct-dsts-per-wave x 4 per lane,
// ~14M total vs 204.8M per-edge atomics before.
// ============================================================================
__device__ __forceinline__ void gather4(const ushortT* __restrict__ base, int node, int li,
                                        ushort8 dst[4])
{
    const ushort8* p = (const ushort8*)(base + (size_t)node * C) + li;
    dst[0] = p[0]; dst[1] = p[4]; dst[2] = p[8]; dst[3] = p[12];   // chunk i at ushort8 index i*4+li
}

__device__ __forceinline__ void wave_gemm(const ushortT (*A)[LDSW],
                                          const ushortT* __restrict__ Bp,
                                          int quad, int m16, int lane,
                                          floatx4 acc[8])
{
#pragma unroll
    for (int nt = 0; nt < 8; ++nt) { acc[nt][0]=0.f; acc[nt][1]=0.f; acc[nt][2]=0.f; acc[nt][3]=0.f; }
#pragma unroll 1
    for (int ks = 0; ks < 4; ++ks) {
        const short8 af = *(const short8*)&A[m16][ks * 32 + quad * 8];
        const ushortT* bpk = Bp + (size_t)ks * 4096 + (size_t)lane * 8;
#pragma unroll
        for (int nt = 0; nt < 8; ++nt) {
            const short8 bf = *(const short8*)(bpk + nt * 512);
            acc[nt] = __builtin_amdgcn_mfma_f32_16x16x32_bf16(af, bf, acc[nt], 0, 0, 0);
        }
    }
}

__device__ __forceinline__ void cstore_relu_r(ushortT (*A)[LDSW], floatx4 acc[8],
                                              const float bias[8], int quad, int m16)
{
#pragma unroll
    for (int nt = 0; nt < 8; ++nt) {
        const float b = bias[nt];
#pragma unroll
        for (int r = 0; r < 4; r += 2) {
            const unsigned p = pk2(fmaxf(acc[nt][r] + b, 0.f), fmaxf(acc[nt][r + 1] + b, 0.f));
            A[quad * 4 + r][nt * 16 + m16]     = (ushortT)(p & 0xffffu);
            A[quad * 4 + r + 1][nt * 16 + m16] = (ushortT)(p >> 16);
        }
    }
}

extern "C" __global__ void __launch_bounds__(THREADS)
edge_mfma(const ushortT* __restrict__ pos_bf,
          const int* __restrict__ ss, const int* __restrict__ sd,
          const ushortT* __restrict__ q_bf, const ushortT* __restrict__ k_bf,
          const ushortT* __restrict__ v_bf, const ushortT* __restrict__ Bpack,
          const float* __restrict__ pb1, const float* __restrict__ pb2,
          const float* __restrict__ ab1, const float* __restrict__ ab2,
          float* __restrict__ z, float* __restrict__ aggU, int E)
{
    __shared__ ushortT Aslab[4][EPW][LDSW];   // 17.4 KB
    __shared__ ushortT Vslab[4][EPW][LDSW];   // 17.4 KB
    __shared__ int     Dslab[4][EPW];         // 256 B: dsts of the tile's edges
    const int tid = threadIdx.x;
    const int wv = tid >> 6, lane = tid & 63;
    const int quad = lane >> 4, m16 = lane & 15;
    const int row = lane >> 2, li = lane & 3;      // line-coherent staging mapping
    ushortT (*A)[LDSW] = Aslab[wv];
    ushortT (*V)[LDSW] = Vslab[wv];

    // tile-invariant: biases in registers
    float pb1v[8], pb2v[8], ab1v[8], ab2v[8];
#pragma unroll
    for (int nt = 0; nt < 8; ++nt) {
        pb1v[nt] = pb1[nt * 16 + m16]; pb2v[nt] = pb2[nt * 16 + m16];
        ab1v[nt] = ab1[nt * 16 + m16]; ab2v[nt] = ab2[nt * 16 + m16];
    }

    const ushortT* B0 = Bpack;
    const ushortT* B1 = Bpack + 16384;
    const ushortT* B2 = Bpack + 32768;
    const ushortT* B3 = Bpack + 49152;

    const int wave_base = (blockIdx.x * 4 + wv) * (GTILES * EPW);

    // segmented-scan run state (per lane, channels c2 and c2+1)
    const int c2 = lane * 2;
    int   cur_dst = -1;
    float zs0 = 0.f, zs1 = 0.f, gs0 = 0.f, gs1 = 0.f;

#pragma unroll 1
    for (int t = 0; t < GTILES; ++t) {
        const int e_base = wave_base + t * EPW;
        const int eidx = min(e_base + row, E - 1);
        const int es = ss[eidx], ed = sd[eidx];
        int sdr[4];
#pragma unroll
        for (int r = 0; r < 4; ++r)
            sdr[r] = sd[min(e_base + quad * 4 + r, E - 1)];
        if (m16 == 0) {
#pragma unroll
            for (int r = 0; r < 4; ++r) Dslab[wv][quad * 4 + r] = sdr[r];
        }

        ushort8 Pd[4], Ps[4], Qv[4], Kv[4], Vv[4];
        gather4(pos_bf, ed, li, Pd); gather4(pos_bf, es, li, Ps);
        gather4(q_bf,  ed, li, Qv); gather4(k_bf,  es, li, Kv);
        gather4(v_bf,  es, li, Vv);

        // ---- A0 = bf16(pos[dst] - pos[src]); stage v into Vslab ----
#pragma unroll
        for (int i = 0; i < 4; ++i) {
            const uintx4 pd = *(const uintx4*)&Pd[i];
            const uintx4 ps = *(const uintx4*)&Ps[i];
            uintx4 o;
#pragma unroll
            for (int w = 0; w < 4; ++w) {
                const float2 a = upk2(pd[w]), b = upk2(ps[w]);
                o[w] = pk2(a.x - b.x, a.y - b.y);
            }
            *(uintx4*)&A[row][i * 32 + li * 8] = o;
            *(ushort8*)&V[row][i * 32 + li * 8] = Vv[i];
        }

        floatx4 acc[8];

        // ---- pos_nn layer 1 ----
        wave_gemm(A, B0, quad, m16, lane, acc);
        cstore_relu_r(A, acc, pb1v, quad, m16);

        // ---- pos_nn layer 2 -> delta (packed regs + slab) ----
        wave_gemm(A, B1, quad, m16, lane, acc);
        unsigned dlp[8][2];
#pragma unroll
        for (int nt = 0; nt < 8; ++nt) {
            const float b = pb2v[nt];
            const unsigned p0 = pk2(fmaxf(acc[nt][0] + b, 0.f), fmaxf(acc[nt][1] + b, 0.f));
            const unsigned p1 = pk2(fmaxf(acc[nt][2] + b, 0.f), fmaxf(acc[nt][3] + b, 0.f));
            dlp[nt][0] = p0; dlp[nt][1] = p1;
            A[quad * 4 + 0][nt * 16 + m16] = (ushortT)(p0 & 0xffffu);
            A[quad * 4 + 1][nt * 16 + m16] = (ushortT)(p0 >> 16);
            A[quad * 4 + 2][nt * 16 + m16] = (ushortT)(p1 & 0xffffu);
            A[quad * 4 + 3][nt * 16 + m16] = (ushortT)(p1 >> 16);
        }

        // ---- A2 = bf16( q[dst] - k[src] + delta ) ----
#pragma unroll
        for (int i = 0; i < 4; ++i) {
            const uintx4 dv = *(const uintx4*)&A[row][i * 32 + li * 8];
            const uintx4 qv = *(const uintx4*)&Qv[i];
            const uintx4 kv = *(const uintx4*)&Kv[i];
            uintx4 o;
#pragma unroll
            for (int w = 0; w < 4; ++w) {
                const float2 qq = upk2(qv[w]), kk = upk2(kv[w]), dd = upk2(dv[w]);
                o[w] = pk2(qq.x - kk.x + dd.x, qq.y - kk.y + dd.y);
            }
            *(uintx4*)&A[row][i * 32 + li * 8] = o;
        }

        // ---- attn_nn layer 1 ----
        wave_gemm(A, B2, quad, m16, lane, acc);
        cstore_relu_r(A, acc, ab1v, quad, m16);

        // ---- attn_nn layer 2 -> ea = exp(relu(alpha+b)) ----
        wave_gemm(A, B3, quad, m16, lane, acc);
#pragma unroll
        for (int nt = 0; nt < 8; ++nt) {
            const float b = ab2v[nt];
#pragma unroll
            for (int r = 0; r < 4; ++r)
                acc[nt][r] = __expf(fmaxf(acc[nt][r] + b, 0.f));  // alpha>=0, O(1): no max-shift
        }

        // ---- zero ea for out-of-range (clamped duplicate) edges ----
        if (e_base + EPW > E) {
#pragma unroll
            for (int r = 0; r < 4; ++r)
                if (e_base + quad * 4 + r >= E) {
#pragma unroll
                    for (int nt = 0; nt < 8; ++nt) acc[nt][r] = 0.f;
                }
        }

        // ---- transpose: A <- ea (bf16), V <- v+delta (bf16), edge-major ----
#pragma unroll
        for (int nt = 0; nt < 8; ++nt) {
#pragma unroll
            for (int r = 0; r < 4; ++r) {
                const float2 dpair = upk2(dlp[nt][r >> 1]);
                const float dlv = (r & 1) ? dpair.y : dpair.x;
                const int ridx = quad * 4 + r, cidx = nt * 16 + m16;
                const float vv = bf2f(V[ridx][cidx]);
                V[ridx][cidx] = f2bf(vv + dlv);
                A[ridx][cidx] = f2bf(acc[nt][r]);
            }
        }

        // ---- per-lane segmented scan over the 16 sorted edges ----
        // lane owns channels c2, c2+1; dst sequence is wave-uniform.
#pragma unroll 4
        for (int e = 0; e < EPW; ++e) {
            const int d = Dslab[wv][e];
            const float2 ea2 = upk2(*(const unsigned*)&A[e][c2]);
            const float2 vp2 = upk2(*(const unsigned*)&V[e][c2]);
            if (d != cur_dst) {
                if (cur_dst >= 0) {
                    float* zp = z    + (size_t)cur_dst * C + c2;
                    float* gp = aggU + (size_t)cur_dst * C + c2;
                    atomic_add_f32(zp,     zs0);
                    atomic_add_f32(zp + 1, zs1);
                    atomic_add_f32(gp,     gs0);
                    atomic_add_f32(gp + 1, gs1);
                }
                cur_dst = d;
                zs0 = ea2.x;           zs1 = ea2.y;
                gs0 = ea2.x * vp2.x;   gs1 = ea2.y * vp2.y;
            } else {
                zs0 += ea2.x;                   zs1 += ea2.y;
                gs0 = fmaf(ea2.x, vp2.x, gs0);  gs1 = fmaf(ea2.y, vp2.y, gs1);
            }
        }
    }

    // ---- final flush ----
    if (cur_dst >= 0) {
        float* zp = z    + (size_t)cur_dst * C + c2;
        float* gp = aggU + (size_t)cur_dst * C + c2;
        atomic_add_f32(zp,     zs0);
        atomic_add_f32(zp + 1, zs1);
        atomic_add_f32(gp,     gs0);
        atomic_add_f32(gp + 1, gs1);
    }
}

// ============================================================================
// kernel 3: out = relu( (aggU / (z+1e-16)) @ W_out + b_out )
// ============================================================================
extern "C" __global__ void __launch_bounds__(THREADS)
out_kernel(const float* __restrict__ aggU, const float* __restrict__ z,
           const float* __restrict__ W_out, const float* __restrict__ b_out,
           float* __restrict__ out, int N)
{
    __shared__ __align__(16) float s_in[TILE * C];
    const int tx = threadIdx.x;
    const int rg = tx >> 5;
    const int oc0 = (tx & 31) << 2;
    const int row0 = blockIdx.x * TILE;

#pragma unroll
    for (int j = 0; j < 8; ++j) {
        const int r = rg * 8 + j, n = row0 + r;
        float4 a; a.x = a.y = a.z = a.w = 0.f;
        if (n < N) {
            const float4 g  = *(const float4*)(aggU + (size_t)n * C + oc0);
            const float4 zz = *(const float4*)(z    + (size_t)n * C + oc0);
            a.x = g.x / (zz.x + 1e-16f);
            a.y = g.y / (zz.y + 1e-16f);
            a.z = g.z / (zz.z + 1e-16f);
            a.w = g.w / (zz.w + 1e-16f);
        }
        *(float4*)(s_in + r * C + oc0) = a;
    }

    float acc[8][4];
    zero_acc(acc);
    tile_gemm(s_in, W_out, acc, rg, oc0);
    bias_relu(acc, b_out, oc0);
#pragma unroll
    for (int j = 0; j < 8; ++j) {
        const int n = row0 + rg * 8 + j;
        if (n < N) { float4 t; t.x=acc[j][0]; t.y=acc[j][1]; t.z=acc[j][2]; t.w=acc[j][3];
                     *(float4*)(out + (size_t)n * C + oc0) = t; }
    }
}

// ---------------------------------------------------------------------------
extern "C" void kernel_launch(void* const* d_in, const int* in_sizes, int n_in,
                              void* d_out, int out_size, void* d_ws, size_t ws_size,
                              hipStream_t stream)
{
    const float* x     = (const float*)d_in[0];
    const float* pos   = (const float*)d_in[1];
    const int*   ei    = (const int*)  d_in[2];
    const float* W_in  = (const float*)d_in[3];
    const float* b_in  = (const float*)d_in[4];
    const float* W_lin = (const float*)d_in[5];
    const float* W_src = (const float*)d_in[6];
    const float* W_dst = (const float*)d_in[7];
    const float* pw1   = (const float*)d_in[8];
    const float* pb1   = (const float*)d_in[9];
    const float* pw2   = (const float*)d_in[10];
    const float* pb2   = (const float*)d_in[11];
    const float* aw1   = (const float*)d_in[12];
    const float* ab1   = (const float*)d_in[13];
    const float* aw2   = (const float*)d_in[14];
    const float* ab2   = (const float*)d_in[15];
    const float* W_out = (const float*)d_in[16];
    const float* b_out = (const float*)d_in[17];

    const int N = in_sizes[0] / C;
    const int E = in_sizes[2] / 2;
    const size_t NC = (size_t)N * C;

    float*   z      = (float*)d_ws;                          // [N,C] fp32
    float*   aggU   = z    + NC;                             // [N,C] fp32
    ushortT* q_bf   = (ushortT*)(aggU + NC);                 // [N,C] bf16
    ushortT* k_bf   = q_bf + NC;                             // [N,C] bf16
    ushortT* v_bf   = k_bf + NC;                             // [N,C] bf16
    ushortT* pos_bf = v_bf + NC;                             // [N,C] bf16
    ushortT* Bpack  = pos_bf + NC;                           // 65536 bf16 = 128 KB
    int*     deg    = (int*)(Bpack + 65536);                 // [N]
    int*     curp   = deg + N;                               // [N]
    int*     offp   = curp + N;                              // [N]
    int*     ss     = offp + N;                              // [E] sorted src
    int*     sdst   = ss + E;                                // [E] sorted dst

    hipMemsetAsync(z, 0, 2 * NC * sizeof(float), stream);
    hipMemsetAsync(deg, 0, 2 * (size_t)N * sizeof(int), stream);   // deg + cur

    // counting sort of edges by dst
    const int ebks = (E + 255) / 256;
    k_hist<<<ebks, 256, 0, stream>>>(ei, deg, E);
    k_scan<<<1, 1024, 0, stream>>>(deg, offp, N);
    k_scatter<<<ebks, 256, 0, stream>>>(ei, offp, curp, ss, sdst, E);

    pack_w<<<256, 256, 0, stream>>>(pw1, pw2, aw1, aw2, Bpack);
    cvt_bf<<<((int)NC + 255) / 256, 256, 0, stream>>>(pos, pos_bf, (int)NC);

    const int nb = (N + TILE - 1) / TILE;
    const int edges_per_block = 4 * GTILES * EPW;            // 512
    const int eb = (E + edges_per_block - 1) / edges_per_block;

    node_qkv<<<nb, THREADS, 0, stream>>>(x, W_in, b_in, W_lin, W_src, W_dst, q_bf, k_bf, v_bf, N);
    edge_mfma<<<eb, THREADS, 0, stream>>>(pos_bf, ss, sdst, q_bf, k_bf, v_bf, Bpack,
                                          pb1, pb2, ab1, ab2, z, aggU, E);
    out_kernel<<<nb, THREADS, 0, stream>>>(aggU, z, W_out, b_out, (float*)d_out, N);
}

// Round 3
// 767.089 us; speedup vs baseline: 1.3139x; 1.0510x over previous
//
#include <hip/hip_runtime.h>
#include <hip/hip_bf16.h>

#define C 128
#define THREADS 256      // 4 waves/block
#define TILE 64          // node rows per block (fp32 kernels)
#define EPW 16           // edges per wave-tile
#define GTILES 8         // tiles per wave, steady-state loop (NOT unrolled)
#define LDSPAD 8
#define LDSW (C + LDSPAD)    // 136 ushorts/row

typedef unsigned short ushortT;
typedef __attribute__((ext_vector_type(8))) short short8;
typedef __attribute__((ext_vector_type(8))) ushortT ushort8;
typedef __attribute__((ext_vector_type(4))) float floatx4;
typedef __attribute__((ext_vector_type(4))) unsigned uintx4;

// ---- bf16 helpers ----
__device__ __forceinline__ unsigned pk2(float a, float b) {     // float2 -> 2x bf16 (RNE, 1 inst)
    float2 f; f.x = a; f.y = b;
    union { unsigned u; __hip_bfloat162 h; } cv; cv.h = __float22bfloat162_rn(f);
    return cv.u;
}
__device__ __forceinline__ ushortT f2bf(float x) {              // HW RNE via cvt_pk (not manual)
    return (ushortT)(pk2(x, x) & 0xffffu);
}
__device__ __forceinline__ float bf2f(ushortT h) {
    union { unsigned u; float f; } v; v.u = ((unsigned)h) << 16;
    return v.f;
}
__device__ __forceinline__ float2 upk2(unsigned u) {            // 2x bf16 -> float2
    union { unsigned u; __hip_bfloat162 h; } cv; cv.u = u;
    return __bfloat1622float2(cv.h);
}
__device__ __forceinline__ void atomic_add_f32(float* p, float v) {
    __hip_atomic_fetch_add(p, v, __ATOMIC_RELAXED, __HIP_MEMORY_SCOPE_AGENT);
}

// ============================================================================
// fp32 micro-GEMM helpers for node-level kernels
// ============================================================================
__device__ __forceinline__ void zero_acc(float acc[8][4]) {
#pragma unroll
    for (int j = 0; j < 8; ++j)
#pragma unroll
        for (int i = 0; i < 4; ++i) acc[j][i] = 0.f;
}

__device__ __forceinline__ void tile_gemm(const float* __restrict__ s_in,
                                          const float* __restrict__ W,
                                          float acc[8][4], int rg, int oc0)
{
#pragma unroll 2
    for (int kc = 0; kc < C; kc += 4) {
        const float4 w0 = *(const float4*)(W + (kc + 0) * C + oc0);
        const float4 w1 = *(const float4*)(W + (kc + 1) * C + oc0);
        const float4 w2 = *(const float4*)(W + (kc + 2) * C + oc0);
        const float4 w3 = *(const float4*)(W + (kc + 3) * C + oc0);
#pragma unroll
        for (int j = 0; j < 8; ++j) {
            const float4 a = *(const float4*)(s_in + (rg * 8 + j) * C + kc);
            acc[j][0] = fmaf(a.w, w3.x, fmaf(a.z, w2.x, fmaf(a.y, w1.x, fmaf(a.x, w0.x, acc[j][0]))));
            acc[j][1] = fmaf(a.w, w3.y, fmaf(a.z, w2.y, fmaf(a.y, w1.y, fmaf(a.x, w0.y, acc[j][1]))));
            acc[j][2] = fmaf(a.w, w3.z, fmaf(a.z, w2.z, fmaf(a.y, w1.z, fmaf(a.x, w0.z, acc[j][2]))));
            acc[j][3] = fmaf(a.w, w3.w, fmaf(a.z, w2.w, fmaf(a.y, w1.w, fmaf(a.x, w0.w, acc[j][3]))));
        }
    }
}

__device__ __forceinline__ void bias_relu(float acc[8][4], const float* __restrict__ b, int oc0) {
    const float4 bv = *(const float4*)(b + oc0);
#pragma unroll
    for (int j = 0; j < 8; ++j) {
        acc[j][0] = fmaxf(acc[j][0] + bv.x, 0.f);
        acc[j][1] = fmaxf(acc[j][1] + bv.y, 0.f);
        acc[j][2] = fmaxf(acc[j][2] + bv.z, 0.f);
        acc[j][3] = fmaxf(acc[j][3] + bv.w, 0.f);
    }
}

// ============================================================================
// edge sort by dst: histogram -> exclusive scan -> scatter (counting sort)
// ============================================================================
extern "C" __global__ void k_hist(const int* __restrict__ ei, int* __restrict__ deg, int E)
{
    const int e = blockIdx.x * 256 + threadIdx.x;
    if (e < E) atomicAdd(&deg[ei[E + e]], 1);
}

extern "C" __global__ void __launch_bounds__(1024)
k_scan(const int* __restrict__ deg, int* __restrict__ off, int n)
{
    __shared__ int part[1024];
    const int t = threadIdx.x;
    const int chunk = (n + 1023) / 1024;
    const int lo = t * chunk, hi = min(lo + chunk, n);
    int s = 0;
    for (int i = lo; i < hi; ++i) s += deg[i];
    part[t] = s;
    __syncthreads();
    for (int d = 1; d < 1024; d <<= 1) {
        int v = (t >= d) ? part[t - d] : 0;
        __syncthreads();
        part[t] += v;
        __syncthreads();
    }
    int run = (t == 0) ? 0 : part[t - 1];
    for (int i = lo; i < hi; ++i) { off[i] = run; run += deg[i]; }
}

extern "C" __global__ void k_scatter(const int* __restrict__ ei, const int* __restrict__ off,
                                     int* __restrict__ cur, int* __restrict__ ss,
                                     int* __restrict__ sd, int E)
{
    const int e = blockIdx.x * 256 + threadIdx.x;
    if (e < E) {
        const int d = ei[E + e];
        const int p = off[d] + atomicAdd(&cur[d], 1);
        ss[p] = ei[e];
        sd[p] = d;
    }
}

// ============================================================================
// pack 4 weight matrices into MFMA B-fragment order (bf16), f = ks*8+nt
// ============================================================================
extern "C" __global__ void pack_w(const float* __restrict__ w0, const float* __restrict__ w1,
                                  const float* __restrict__ w2, const float* __restrict__ w3,
                                  ushortT* __restrict__ out)
{
    const int t = blockIdx.x * 256 + threadIdx.x;      // 65536 threads
    const int j = t & 7, lane = (t >> 3) & 63, f = (t >> 9) & 31, s = t >> 14;
    const float* W = (s == 0) ? w0 : (s == 1) ? w1 : (s == 2) ? w2 : w3;
    const int nt = f & 7, ks = f >> 3;
    const int n = nt * 16 + (lane & 15);
    const int k = ks * 32 + (lane >> 4) * 8 + j;
    out[t] = f2bf(W[k * C + n]);
}

extern "C" __global__ void cvt_bf(const float* __restrict__ in, ushortT* __restrict__ out, int n)
{
    const int t = blockIdx.x * 256 + threadIdx.x;
    if (t < n) out[t] = f2bf(in[t]);
}

// ============================================================================
// MFMA wave-GEMM: acc initialized with per-channel bias (MFMA accumulates
// onto C-in, so the bias add is free).
// ============================================================================
__device__ __forceinline__ void wave_gemm(const ushortT (*A)[LDSW],
                                          const ushortT* __restrict__ Bp,
                                          int quad, int m16, int lane,
                                          floatx4 acc[8], const float binit[8])
{
#pragma unroll
    for (int nt = 0; nt < 8; ++nt) {
        acc[nt][0] = binit[nt]; acc[nt][1] = binit[nt];
        acc[nt][2] = binit[nt]; acc[nt][3] = binit[nt];
    }
#pragma unroll 1
    for (int ks = 0; ks < 4; ++ks) {
        const short8 af = *(const short8*)&A[m16][ks * 32 + quad * 8];
        const ushortT* bpk = Bp + (size_t)ks * 4096 + (size_t)lane * 8;
#pragma unroll
        for (int nt = 0; nt < 8; ++nt) {
            const short8 bf = *(const short8*)(bpk + nt * 512);
            acc[nt] = __builtin_amdgcn_mfma_f32_16x16x32_bf16(af, bf, acc[nt], 0, 0, 0);
        }
    }
}

__device__ __forceinline__ void cstore_relu(ushortT (*A)[LDSW], floatx4 acc[8],
                                            int quad, int m16)
{
#pragma unroll
    for (int nt = 0; nt < 8; ++nt) {
#pragma unroll
        for (int r = 0; r < 4; r += 2) {
            const unsigned p = pk2(fmaxf(acc[nt][r], 0.f), fmaxf(acc[nt][r + 1], 0.f));
            A[quad * 4 + r][nt * 16 + m16]     = (ushortT)(p & 0xffffu);
            A[quad * 4 + r + 1][nt * 16 + m16] = (ushortT)(p >> 16);
        }
    }
}

// ============================================================================
// kernel 1: h = relu(x@W_in+b_in) in exact fp32; then q/k/v = h@W via bf16
// MFMA (3 GEMMs). h->bf16 staged in LDS; per-wave MFMA over 16 rows; C-frag
// repacked through LDS for coalesced 16B bf16 stores. No cross-wave barriers
// except one (ostage overlays s_in).
// ============================================================================
extern "C" __global__ void __launch_bounds__(THREADS)
node_qkv(const float* __restrict__ x,
         const float* __restrict__ W_in, const float* __restrict__ b_in,
         const ushortT* __restrict__ Bp2,
         ushortT* __restrict__ q_bf, ushortT* __restrict__ k_bf, ushortT* __restrict__ v_bf, int N)
{
    __shared__ __align__(16) float s_in[TILE * C];          // 32 KB
    __shared__ __align__(16) ushortT h_bf[TILE][LDSW];      // 17.4 KB
    ushortT (*ostage)[LDSW] = (ushortT (*)[LDSW])s_in;      // overlay (17.4 KB of 32 KB)
    const int tx = threadIdx.x;
    const int rg = tx >> 5;
    const int oc0 = (tx & 31) << 2;
    const int row0 = blockIdx.x * TILE;

    // ---- fp32 phase: h = relu(x @ W_in + b_in), exact as reference path ----
#pragma unroll
    for (int j = 0; j < 8; ++j) {
        const int r = rg * 8 + j, n = row0 + r;
        float4 xv; xv.x = xv.y = xv.z = xv.w = 0.f;
        if (n < N) xv = *(const float4*)(x + n * C + oc0);
        *(float4*)(s_in + r * C + oc0) = xv;
    }
    // rows rg*8+j written and read by the same wave half -> no barrier

    float acc[8][4];
    zero_acc(acc);
    tile_gemm(s_in, W_in, acc, rg, oc0);
    bias_relu(acc, b_in, oc0);

    // h -> bf16 LDS (u32 pair writes)
#pragma unroll
    for (int j = 0; j < 8; ++j) {
        const int r = rg * 8 + j;
        *(unsigned*)&h_bf[r][oc0]     = pk2(acc[j][0], acc[j][1]);
        *(unsigned*)&h_bf[r][oc0 + 2] = pk2(acc[j][2], acc[j][3]);
    }

    __syncthreads();   // all s_in reads done before ostage overlay is written

    // ---- MFMA phase: wave wv handles rows wv*16 .. wv*16+15 ----
    const int wv = tx >> 6, lane = tx & 63;
    const int quad = lane >> 4, m16 = lane & 15;
    const int row = lane >> 2, li = lane & 3;
    const ushortT (*Aw)[LDSW] = (const ushortT (*)[LDSW])&h_bf[wv * 16];
    ushortT (*OS)[LDSW] = (ushortT (*)[LDSW])&ostage[wv * 16];
    const float zb[8] = {0.f, 0.f, 0.f, 0.f, 0.f, 0.f, 0.f, 0.f};

    ushortT* outs[3];
    outs[0] = q_bf; outs[1] = k_bf; outs[2] = v_bf;

    floatx4 macc[8];
#pragma unroll 1
    for (int m = 0; m < 3; ++m) {
        wave_gemm(Aw, Bp2 + (size_t)m * 16384, quad, m16, lane, macc, zb);
        // C-frag -> ostage (bf16, linear output: no relu)
#pragma unroll
        for (int nt = 0; nt < 8; ++nt) {
#pragma unroll
            for (int r = 0; r < 4; r += 2) {
                const unsigned p = pk2(macc[nt][r], macc[nt][r + 1]);
                OS[quad * 4 + r][nt * 16 + m16]     = (ushortT)(p & 0xffffu);
                OS[quad * 4 + r + 1][nt * 16 + m16] = (ushortT)(p >> 16);
            }
        }
        // read back rows, coalesced 16B stores
        const int n = row0 + wv * 16 + row;
        if (n < N) {
#pragma unroll
            for (int i = 0; i < 4; ++i) {
                const ushort8 v8 = *(const ushort8*)&OS[row][i * 32 + li * 8];
                *(ushort8*)(outs[m] + (size_t)n * C + i * 32 + li * 8) = v8;
            }
        }
    }
}

// ============================================================================
// kernel 2 (MFMA): edges SORTED BY DST; segmented-scan epilogue (round 2).
// This round: bias folded into MFMA acc-init, HW cvt for all f32->bf16.
// ============================================================================
__device__ __forceinline__ void gather4(const ushortT* __restrict__ base, int node, int li,
                                        ushort8 dst[4])
{
    const ushort8* p = (const ushort8*)(base + (size_t)node * C) + li;
    dst[0] = p[0]; dst[1] = p[4]; dst[2] = p[8]; dst[3] = p[12];   // chunk i at ushort8 index i*4+li
}

extern "C" __global__ void __launch_bounds__(THREADS)
edge_mfma(const ushortT* __restrict__ pos_bf,
          const int* __restrict__ ss, const int* __restrict__ sd,
          const ushortT* __restrict__ q_bf, const ushortT* __restrict__ k_bf,
          const ushortT* __restrict__ v_bf, const ushortT* __restrict__ Bpack,
          const float* __restrict__ pb1, const float* __restrict__ pb2,
          const float* __restrict__ ab1, const float* __restrict__ ab2,
          float* __restrict__ z, float* __restrict__ aggU, int E)
{
    __shared__ ushortT Aslab[4][EPW][LDSW];   // 17.4 KB
    __shared__ ushortT Vslab[4][EPW][LDSW];   // 17.4 KB
    __shared__ int     Dslab[4][EPW];         // 256 B: dsts of the tile's edges
    const int tid = threadIdx.x;
    const int wv = tid >> 6, lane = tid & 63;
    const int quad = lane >> 4, m16 = lane & 15;
    const int row = lane >> 2, li = lane & 3;      // line-coherent staging mapping
    ushortT (*A)[LDSW] = Aslab[wv];
    ushortT (*V)[LDSW] = Vslab[wv];

    // tile-invariant: biases in registers (consumed as MFMA acc-init)
    float pb1v[8], pb2v[8], ab1v[8], ab2v[8];
#pragma unroll
    for (int nt = 0; nt < 8; ++nt) {
        pb1v[nt] = pb1[nt * 16 + m16]; pb2v[nt] = pb2[nt * 16 + m16];
        ab1v[nt] = ab1[nt * 16 + m16]; ab2v[nt] = ab2[nt * 16 + m16];
    }

    const ushortT* B0 = Bpack;
    const ushortT* B1 = Bpack + 16384;
    const ushortT* B2 = Bpack + 32768;
    const ushortT* B3 = Bpack + 49152;

    const int wave_base = (blockIdx.x * 4 + wv) * (GTILES * EPW);

    // segmented-scan run state (per lane, channels c2 and c2+1)
    const int c2 = lane * 2;
    int   cur_dst = -1;
    float zs0 = 0.f, zs1 = 0.f, gs0 = 0.f, gs1 = 0.f;

#pragma unroll 1
    for (int t = 0; t < GTILES; ++t) {
        const int e_base = wave_base + t * EPW;
        const int eidx = min(e_base + row, E - 1);
        const int es = ss[eidx], ed = sd[eidx];
        int sdr[4];
#pragma unroll
        for (int r = 0; r < 4; ++r)
            sdr[r] = sd[min(e_base + quad * 4 + r, E - 1)];
        if (m16 == 0) {
#pragma unroll
            for (int r = 0; r < 4; ++r) Dslab[wv][quad * 4 + r] = sdr[r];
        }

        ushort8 Pd[4], Ps[4], Qv[4], Kv[4], Vv[4];
        gather4(pos_bf, ed, li, Pd); gather4(pos_bf, es, li, Ps);
        gather4(q_bf,  ed, li, Qv); gather4(k_bf,  es, li, Kv);
        gather4(v_bf,  es, li, Vv);

        // ---- A0 = bf16(pos[dst] - pos[src]); stage v into Vslab ----
#pragma unroll
        for (int i = 0; i < 4; ++i) {
            const uintx4 pd = *(const uintx4*)&Pd[i];
            const uintx4 ps = *(const uintx4*)&Ps[i];
            uintx4 o;
#pragma unroll
            for (int w = 0; w < 4; ++w) {
                const float2 a = upk2(pd[w]), b = upk2(ps[w]);
                o[w] = pk2(a.x - b.x, a.y - b.y);
            }
            *(uintx4*)&A[row][i * 32 + li * 8] = o;
            *(ushort8*)&V[row][i * 32 + li * 8] = Vv[i];
        }

        floatx4 acc[8];

        // ---- pos_nn layer 1 (bias in acc-init) ----
        wave_gemm(A, B0, quad, m16, lane, acc, pb1v);
        cstore_relu(A, acc, quad, m16);

        // ---- pos_nn layer 2 -> delta (packed regs + slab) ----
        wave_gemm(A, B1, quad, m16, lane, acc, pb2v);
        unsigned dlp[8][2];
#pragma unroll
        for (int nt = 0; nt < 8; ++nt) {
            const unsigned p0 = pk2(fmaxf(acc[nt][0], 0.f), fmaxf(acc[nt][1], 0.f));
            const unsigned p1 = pk2(fmaxf(acc[nt][2], 0.f), fmaxf(acc[nt][3], 0.f));
            dlp[nt][0] = p0; dlp[nt][1] = p1;
            A[quad * 4 + 0][nt * 16 + m16] = (ushortT)(p0 & 0xffffu);
            A[quad * 4 + 1][nt * 16 + m16] = (ushortT)(p0 >> 16);
            A[quad * 4 + 2][nt * 16 + m16] = (ushortT)(p1 & 0xffffu);
            A[quad * 4 + 3][nt * 16 + m16] = (ushortT)(p1 >> 16);
        }

        // ---- A2 = bf16( q[dst] - k[src] + delta ) ----
#pragma unroll
        for (int i = 0; i < 4; ++i) {
            const uintx4 dv = *(const uintx4*)&A[row][i * 32 + li * 8];
            const uintx4 qv = *(const uintx4*)&Qv[i];
            const uintx4 kv = *(const uintx4*)&Kv[i];
            uintx4 o;
#pragma unroll
            for (int w = 0; w < 4; ++w) {
                const float2 qq = upk2(qv[w]), kk = upk2(kv[w]), dd = upk2(dv[w]);
                o[w] = pk2(qq.x - kk.x + dd.x, qq.y - kk.y + dd.y);
            }
            *(uintx4*)&A[row][i * 32 + li * 8] = o;
        }

        // ---- attn_nn layer 1 ----
        wave_gemm(A, B2, quad, m16, lane, acc, ab1v);
        cstore_relu(A, acc, quad, m16);

        // ---- attn_nn layer 2 -> ea = exp(relu(alpha)) (bias in init) ----
        wave_gemm(A, B3, quad, m16, lane, acc, ab2v);
#pragma unroll
        for (int nt = 0; nt < 8; ++nt) {
#pragma unroll
            for (int r = 0; r < 4; ++r)
                acc[nt][r] = __expf(fmaxf(acc[nt][r], 0.f));  // alpha>=0, O(1): no max-shift
        }

        // ---- zero ea for out-of-range (clamped duplicate) edges ----
        if (e_base + EPW > E) {
#pragma unroll
            for (int r = 0; r < 4; ++r)
                if (e_base + quad * 4 + r >= E) {
#pragma unroll
                    for (int nt = 0; nt < 8; ++nt) acc[nt][r] = 0.f;
                }
        }

        // ---- transpose: A <- ea (bf16), V <- v+delta (bf16), edge-major ----
#pragma unroll
        for (int nt = 0; nt < 8; ++nt) {
#pragma unroll
            for (int r = 0; r < 4; ++r) {
                const float2 dpair = upk2(dlp[nt][r >> 1]);
                const float dlv = (r & 1) ? dpair.y : dpair.x;
                const int ridx = quad * 4 + r, cidx = nt * 16 + m16;
                const float vv = bf2f(V[ridx][cidx]);
                V[ridx][cidx] = f2bf(vv + dlv);
                A[ridx][cidx] = f2bf(acc[nt][r]);
            }
        }

        // ---- per-lane segmented scan over the 16 sorted edges ----
#pragma unroll 4
        for (int e = 0; e < EPW; ++e) {
            const int d = Dslab[wv][e];
            const float2 ea2 = upk2(*(const unsigned*)&A[e][c2]);
            const float2 vp2 = upk2(*(const unsigned*)&V[e][c2]);
            if (d != cur_dst) {
                if (cur_dst >= 0) {
                    float* zp = z    + (size_t)cur_dst * C + c2;
                    float* gp = aggU + (size_t)cur_dst * C + c2;
                    atomic_add_f32(zp,     zs0);
                    atomic_add_f32(zp + 1, zs1);
                    atomic_add_f32(gp,     gs0);
                    atomic_add_f32(gp + 1, gs1);
                }
                cur_dst = d;
                zs0 = ea2.x;           zs1 = ea2.y;
                gs0 = ea2.x * vp2.x;   gs1 = ea2.y * vp2.y;
            } else {
                zs0 += ea2.x;                   zs1 += ea2.y;
                gs0 = fmaf(ea2.x, vp2.x, gs0);  gs1 = fmaf(ea2.y, vp2.y, gs1);
            }
        }
    }

    // ---- final flush ----
    if (cur_dst >= 0) {
        float* zp = z    + (size_t)cur_dst * C + c2;
        float* gp = aggU + (size_t)cur_dst * C + c2;
        atomic_add_f32(zp,     zs0);
        atomic_add_f32(zp + 1, zs1);
        atomic_add_f32(gp,     gs0);
        atomic_add_f32(gp + 1, gs1);
    }
}

// ============================================================================
// kernel 3: out = relu( (aggU / (z+1e-16)) @ W_out + b_out )
// ============================================================================
extern "C" __global__ void __launch_bounds__(THREADS)
out_kernel(const float* __restrict__ aggU, const float* __restrict__ z,
           const float* __restrict__ W_out, const float* __restrict__ b_out,
           float* __restrict__ out, int N)
{
    __shared__ __align__(16) float s_in[TILE * C];
    const int tx = threadIdx.x;
    const int rg = tx >> 5;
    const int oc0 = (tx & 31) << 2;
    const int row0 = blockIdx.x * TILE;

#pragma unroll
    for (int j = 0; j < 8; ++j) {
        const int r = rg * 8 + j, n = row0 + r;
        float4 a; a.x = a.y = a.z = a.w = 0.f;
        if (n < N) {
            const float4 g  = *(const float4*)(aggU + (size_t)n * C + oc0);
            const float4 zz = *(const float4*)(z    + (size_t)n * C + oc0);
            a.x = g.x / (zz.x + 1e-16f);
            a.y = g.y / (zz.y + 1e-16f);
            a.z = g.z / (zz.z + 1e-16f);
            a.w = g.w / (zz.w + 1e-16f);
        }
        *(float4*)(s_in + r * C + oc0) = a;
    }

    float acc[8][4];
    zero_acc(acc);
    tile_gemm(s_in, W_out, acc, rg, oc0);
    bias_relu(acc, b_out, oc0);
#pragma unroll
    for (int j = 0; j < 8; ++j) {
        const int n = row0 + rg * 8 + j;
        if (n < N) { float4 t; t.x=acc[j][0]; t.y=acc[j][1]; t.z=acc[j][2]; t.w=acc[j][3];
                     *(float4*)(out + (size_t)n * C + oc0) = t; }
    }
}

// ---------------------------------------------------------------------------
extern "C" void kernel_launch(void* const* d_in, const int* in_sizes, int n_in,
                              void* d_out, int out_size, void* d_ws, size_t ws_size,
                              hipStream_t stream)
{
    const float* x     = (const float*)d_in[0];
    const float* pos   = (const float*)d_in[1];
    const int*   ei    = (const int*)  d_in[2];
    const float* W_in  = (const float*)d_in[3];
    const float* b_in  = (const float*)d_in[4];
    const float* W_lin = (const float*)d_in[5];
    const float* W_src = (const float*)d_in[6];
    const float* W_dst = (const float*)d_in[7];
    const float* pw1   = (const float*)d_in[8];
    const float* pb1   = (const float*)d_in[9];
    const float* pw2   = (const float*)d_in[10];
    const float* pb2   = (const float*)d_in[11];
    const float* aw1   = (const float*)d_in[12];
    const float* ab1   = (const float*)d_in[13];
    const float* aw2   = (const float*)d_in[14];
    const float* ab2   = (const float*)d_in[15];
    const float* W_out = (const float*)d_in[16];
    const float* b_out = (const float*)d_in[17];

    const int N = in_sizes[0] / C;
    const int E = in_sizes[2] / 2;
    const size_t NC = (size_t)N * C;

    float*   z      = (float*)d_ws;                          // [N,C] fp32
    float*   aggU   = z    + NC;                             // [N,C] fp32
    ushortT* q_bf   = (ushortT*)(aggU + NC);                 // [N,C] bf16
    ushortT* k_bf   = q_bf + NC;                             // [N,C] bf16
    ushortT* v_bf   = k_bf + NC;                             // [N,C] bf16
    ushortT* pos_bf = v_bf + NC;                             // [N,C] bf16
    ushortT* Bpack  = pos_bf + NC;                           // 65536 bf16 (edge MLP weights)
    ushortT* Bpack2 = Bpack + 65536;                         // 65536 bf16 (W_dst,W_src,W_lin)
    int*     deg    = (int*)(Bpack2 + 65536);                // [N]
    int*     curp   = deg + N;                               // [N]
    int*     offp   = curp + N;                              // [N]
    int*     ss     = offp + N;                              // [E] sorted src
    int*     sdst   = ss + E;                                // [E] sorted dst

    hipMemsetAsync(z, 0, 2 * NC * sizeof(float), stream);
    hipMemsetAsync(deg, 0, 2 * (size_t)N * sizeof(int), stream);   // deg + cur

    // counting sort of edges by dst
    const int ebks = (E + 255) / 256;
    k_hist<<<ebks, 256, 0, stream>>>(ei, deg, E);
    k_scan<<<1, 1024, 0, stream>>>(deg, offp, N);
    k_scatter<<<ebks, 256, 0, stream>>>(ei, offp, curp, ss, sdst, E);

    pack_w<<<256, 256, 0, stream>>>(pw1, pw2, aw1, aw2, Bpack);
    pack_w<<<256, 256, 0, stream>>>(W_dst, W_src, W_lin, W_lin, Bpack2);
    cvt_bf<<<((int)NC + 255) / 256, 256, 0, stream>>>(pos, pos_bf, (int)NC);

    const int nb = (N + TILE - 1) / TILE;
    const int edges_per_block = 4 * GTILES * EPW;            // 512
    const int eb = (E + edges_per_block - 1) / edges_per_block;

    node_qkv<<<nb, THREADS, 0, stream>>>(x, W_in, b_in, Bpack2, q_bf, k_bf, v_bf, N);
    edge_mfma<<<eb, THREADS, 0, stream>>>(pos_bf, ss, sdst, q_bf, k_bf, v_bf, Bpack,
                                          pb1, pb2, ab1, ab2, z, aggU, E);
    out_kernel<<<nb, THREADS, 0, stream>>>(aggU, z, W_out, b_out, (float*)d_out, N);
}

// Round 4
// 748.064 us; speedup vs baseline: 1.3473x; 1.0254x over previous
//
#include <hip/hip_runtime.h>
#include <hip/hip_bf16.h>

#define C 128
#define THREADS 256      // 4 waves/block
#define TILE 64          // node rows per block
#define EPW 16           // edges per wave-tile
#define GTILES 8         // tiles per wave, steady-state loop (NOT unrolled)
#define LDSPAD 8
#define LDSW (C + LDSPAD)    // 136 ushorts/row

typedef unsigned short ushortT;
typedef __attribute__((ext_vector_type(8))) short short8;
typedef __attribute__((ext_vector_type(8))) ushortT ushort8;
typedef __attribute__((ext_vector_type(4))) float floatx4;
typedef __attribute__((ext_vector_type(4))) unsigned uintx4;

// ---- bf16 helpers ----
__device__ __forceinline__ unsigned pk2(float a, float b) {     // float2 -> 2x bf16 (RNE, 1 inst)
    float2 f; f.x = a; f.y = b;
    union { unsigned u; __hip_bfloat162 h; } cv; cv.h = __float22bfloat162_rn(f);
    return cv.u;
}
__device__ __forceinline__ ushortT f2bf(float x) {              // HW RNE via cvt_pk
    return (ushortT)(pk2(x, x) & 0xffffu);
}
__device__ __forceinline__ float bf2f(ushortT h) {
    union { unsigned u; float f; } v; v.u = ((unsigned)h) << 16;
    return v.f;
}
__device__ __forceinline__ float2 upk2(unsigned u) {            // 2x bf16 -> float2
    union { unsigned u; __hip_bfloat162 h; } cv; cv.u = u;
    return __bfloat1622float2(cv.h);
}
__device__ __forceinline__ void atomic_add_f32(float* p, float v) {
    __hip_atomic_fetch_add(p, v, __ATOMIC_RELAXED, __HIP_MEMORY_SCOPE_AGENT);
}

// ============================================================================
// fp32 micro-GEMM helpers (out_kernel only now)
// ============================================================================
__device__ __forceinline__ void zero_acc(float acc[8][4]) {
#pragma unroll
    for (int j = 0; j < 8; ++j)
#pragma unroll
        for (int i = 0; i < 4; ++i) acc[j][i] = 0.f;
}

__device__ __forceinline__ void tile_gemm(const float* __restrict__ s_in,
                                          const float* __restrict__ W,
                                          float acc[8][4], int rg, int oc0)
{
#pragma unroll 2
    for (int kc = 0; kc < C; kc += 4) {
        const float4 w0 = *(const float4*)(W + (kc + 0) * C + oc0);
        const float4 w1 = *(const float4*)(W + (kc + 1) * C + oc0);
        const float4 w2 = *(const float4*)(W + (kc + 2) * C + oc0);
        const float4 w3 = *(const float4*)(W + (kc + 3) * C + oc0);
#pragma unroll
        for (int j = 0; j < 8; ++j) {
            const float4 a = *(const float4*)(s_in + (rg * 8 + j) * C + kc);
            acc[j][0] = fmaf(a.w, w3.x, fmaf(a.z, w2.x, fmaf(a.y, w1.x, fmaf(a.x, w0.x, acc[j][0]))));
            acc[j][1] = fmaf(a.w, w3.y, fmaf(a.z, w2.y, fmaf(a.y, w1.y, fmaf(a.x, w0.y, acc[j][1]))));
            acc[j][2] = fmaf(a.w, w3.z, fmaf(a.z, w2.z, fmaf(a.y, w1.z, fmaf(a.x, w0.z, acc[j][2]))));
            acc[j][3] = fmaf(a.w, w3.w, fmaf(a.z, w2.w, fmaf(a.y, w1.w, fmaf(a.x, w0.w, acc[j][3]))));
        }
    }
}

__device__ __forceinline__ void bias_relu(float acc[8][4], const float* __restrict__ b, int oc0) {
    const float4 bv = *(const float4*)(b + oc0);
#pragma unroll
    for (int j = 0; j < 8; ++j) {
        acc[j][0] = fmaxf(acc[j][0] + bv.x, 0.f);
        acc[j][1] = fmaxf(acc[j][1] + bv.y, 0.f);
        acc[j][2] = fmaxf(acc[j][2] + bv.z, 0.f);
        acc[j][3] = fmaxf(acc[j][3] + bv.w, 0.f);
    }
}

// ============================================================================
// MFMA helpers (round-2 codegen: zero-init acc, bias in epilogue)
// ============================================================================
__device__ __forceinline__ void wave_gemm(const ushortT (*A)[LDSW],
                                          const ushortT* __restrict__ Bp,
                                          int quad, int m16, int lane,
                                          floatx4 acc[8])
{
#pragma unroll
    for (int nt = 0; nt < 8; ++nt) { acc[nt][0]=0.f; acc[nt][1]=0.f; acc[nt][2]=0.f; acc[nt][3]=0.f; }
#pragma unroll 1
    for (int ks = 0; ks < 4; ++ks) {
        const short8 af = *(const short8*)&A[m16][ks * 32 + quad * 8];
        const ushortT* bpk = Bp + (size_t)ks * 4096 + (size_t)lane * 8;
#pragma unroll
        for (int nt = 0; nt < 8; ++nt) {
            const short8 bf = *(const short8*)(bpk + nt * 512);
            acc[nt] = __builtin_amdgcn_mfma_f32_16x16x32_bf16(af, bf, acc[nt], 0, 0, 0);
        }
    }
}

__device__ __forceinline__ void cstore_relu_r(ushortT (*A)[LDSW], floatx4 acc[8],
                                              const float bias[8], int quad, int m16)
{
#pragma unroll
    for (int nt = 0; nt < 8; ++nt) {
        const float b = bias[nt];
#pragma unroll
        for (int r = 0; r < 4; r += 2) {
            const unsigned p = pk2(fmaxf(acc[nt][r] + b, 0.f), fmaxf(acc[nt][r + 1] + b, 0.f));
            A[quad * 4 + r][nt * 16 + m16]     = (ushortT)(p & 0xffffu);
            A[quad * 4 + r + 1][nt * 16 + m16] = (ushortT)(p >> 16);
        }
    }
}

// pack one matrix entry into MFMA B-fragment order
__device__ __forceinline__ ushortT pack_one(const float* __restrict__ W, int u) {
    const int j = u & 7, lane = (u >> 3) & 63, f = u >> 9;  // u in [0,16384)
    const int nt = f & 7, ks = f >> 3;
    const int n = nt * 16 + (lane & 15);
    const int k = ks * 32 + (lane >> 4) * 8 + j;
    return f2bf(W[k * C + n]);
}

// ============================================================================
// prep1 (fused): pack Bpack (edge MLP), pack Bpack2 (Wdst,Wsrc,Wlin,Win),
// cvt pos->bf16 (float4 vectorized), hist of dst degrees. Block-role ranges.
// ============================================================================
extern "C" __global__ void __launch_bounds__(256)
prep1(const float* __restrict__ pw1, const float* __restrict__ pw2,
      const float* __restrict__ aw1, const float* __restrict__ aw2,
      const float* __restrict__ Wd,  const float* __restrict__ Wsrc,
      const float* __restrict__ Wl,  const float* __restrict__ Win,
      const float* __restrict__ pos, ushortT* __restrict__ pos_bf,
      const int* __restrict__ ei, int* __restrict__ deg,
      ushortT* __restrict__ Bpack, ushortT* __restrict__ Bpack2, int N, int E)
{
    const int nb_cvt = (N * 32 + 255) / 256;
    const int b = blockIdx.x, tid = threadIdx.x;
    if (b < 256) {
        const int t = b * 256 + tid;
        const int s = t >> 14;
        const float* W = (s == 0) ? pw1 : (s == 1) ? pw2 : (s == 2) ? aw1 : aw2;
        Bpack[t] = pack_one(W, t & 16383);
    } else if (b < 512) {
        const int t = (b - 256) * 256 + tid;
        const int s = t >> 14;
        const float* W = (s == 0) ? Wd : (s == 1) ? Wsrc : (s == 2) ? Wl : Win;
        Bpack2[t] = pack_one(W, t & 16383);
    } else if (b < 512 + nb_cvt) {
        const int i = (b - 512) * 256 + tid;
        if (i < N * 32) {
            const float4 v = ((const float4*)pos)[i];
            uint2 o; o.x = pk2(v.x, v.y); o.y = pk2(v.z, v.w);
            ((uint2*)pos_bf)[i] = o;
        }
    } else {
        const int e = (b - 512 - nb_cvt) * 256 + tid;
        if (e < E) atomicAdd(&deg[ei[E + e]], 1);
    }
}

extern "C" __global__ void __launch_bounds__(1024)
k_scan(const int* __restrict__ deg, int* __restrict__ off, int n)
{
    __shared__ int part[1024];
    const int t = threadIdx.x;
    const int chunk = (n + 1023) / 1024;
    const int lo = t * chunk, hi = min(lo + chunk, n);
    int s = 0;
    for (int i = lo; i < hi; ++i) s += deg[i];
    part[t] = s;
    __syncthreads();
    for (int d = 1; d < 1024; d <<= 1) {
        int v = (t >= d) ? part[t - d] : 0;
        __syncthreads();
        part[t] += v;
        __syncthreads();
    }
    int run = (t == 0) ? 0 : part[t - 1];
    for (int i = lo; i < hi; ++i) { off[i] = run; run += deg[i]; }
}

// ============================================================================
// prep2 (fused): node role (all-MFMA qkv) + scatter role.
// Node: x->bf16 LDS (wave-private 16 rows); h = relu(x@Win+b) via MFMA into
// h slab; then q/k/v = h@W via MFMA, repacked through ostage (overlays x slab)
// for coalesced 16B bf16 stores. Barriers: one (overlay safety).
// ============================================================================
extern "C" __global__ void __launch_bounds__(256)
prep2(const float* __restrict__ x, const float* __restrict__ b_in,
      const ushortT* __restrict__ Bp2,
      ushortT* __restrict__ q_bf, ushortT* __restrict__ k_bf, ushortT* __restrict__ v_bf,
      const int* __restrict__ ei, const int* __restrict__ offp, int* __restrict__ curp,
      int* __restrict__ ss, int* __restrict__ sd, int N, int E, int nb_node)
{
    __shared__ ushortT xs[TILE][LDSW];   // 17.4 KB (ostage overlays this)
    __shared__ ushortT hs[TILE][LDSW];   // 17.4 KB
    const int b = blockIdx.x, tx = threadIdx.x;

    if (b >= nb_node) {
        // ---- scatter role ----
        const int e = (b - nb_node) * 256 + tx;
        if (e < E) {
            const int d = ei[E + e];
            const int p = offp[d] + atomicAdd(&curp[d], 1);
            ss[p] = ei[e];
            sd[p] = d;
        }
        return;
    }

    // ---- node role ----
    const int rg = tx >> 5;
    const int oc0 = (tx & 31) << 2;
    const int row0 = b * TILE;

    // stage x -> bf16 (wave-private rows)
#pragma unroll
    for (int j = 0; j < 8; ++j) {
        const int r = rg * 8 + j, n = row0 + r;
        float4 xv; xv.x = xv.y = xv.z = xv.w = 0.f;
        if (n < N) xv = *(const float4*)(x + (size_t)n * C + oc0);
        *(unsigned*)&xs[r][oc0]     = pk2(xv.x, xv.y);
        *(unsigned*)&xs[r][oc0 + 2] = pk2(xv.z, xv.w);
    }

    const int wv = tx >> 6, lane = tx & 63;
    const int quad = lane >> 4, m16 = lane & 15;
    const int row = lane >> 2, li = lane & 3;

    float binv[8];
#pragma unroll
    for (int nt = 0; nt < 8; ++nt) binv[nt] = b_in[nt * 16 + m16];

    const ushortT (*Ax)[LDSW] = (const ushortT (*)[LDSW])&xs[wv * 16];
    ushortT (*Ah)[LDSW] = (ushortT (*)[LDSW])&hs[wv * 16];

    floatx4 macc[8];
    // h = relu(x @ W_in + b_in)   (W_in in Bpack2 slot 3)
    wave_gemm(Ax, Bp2 + (size_t)3 * 16384, quad, m16, lane, macc);
    cstore_relu_r(Ah, macc, binv, quad, m16);

    __syncthreads();   // all xs reads done before ostage overlay writes

    ushortT (*OS)[LDSW] = (ushortT (*)[LDSW])&xs[wv * 16];   // ostage overlay
    ushortT* outs[3];
    outs[0] = q_bf; outs[1] = k_bf; outs[2] = v_bf;

#pragma unroll 1
    for (int m = 0; m < 3; ++m) {
        wave_gemm((const ushortT (*)[LDSW])Ah, Bp2 + (size_t)m * 16384, quad, m16, lane, macc);
#pragma unroll
        for (int nt = 0; nt < 8; ++nt) {
#pragma unroll
            for (int r = 0; r < 4; r += 2) {
                const unsigned p = pk2(macc[nt][r], macc[nt][r + 1]);
                OS[quad * 4 + r][nt * 16 + m16]     = (ushortT)(p & 0xffffu);
                OS[quad * 4 + r + 1][nt * 16 + m16] = (ushortT)(p >> 16);
            }
        }
        const int n = row0 + wv * 16 + row;
        if (n < N) {
#pragma unroll
            for (int i = 0; i < 4; ++i) {
                const ushort8 v8 = *(const ushort8*)&OS[row][i * 32 + li * 8];
                *(ushort8*)(outs[m] + (size_t)n * C + i * 32 + li * 8) = v8;
            }
        }
    }
}

// ============================================================================
// kernel 2 (MFMA): edges SORTED BY DST; segmented-scan epilogue.
// Round-2 structure (zero-init acc, epilogue bias) + 1-inst f2bf.
// ============================================================================
__device__ __forceinline__ void gather4(const ushortT* __restrict__ base, int node, int li,
                                        ushort8 dst[4])
{
    const ushort8* p = (const ushort8*)(base + (size_t)node * C) + li;
    dst[0] = p[0]; dst[1] = p[4]; dst[2] = p[8]; dst[3] = p[12];   // chunk i at ushort8 index i*4+li
}

extern "C" __global__ void __launch_bounds__(THREADS)
edge_mfma(const ushortT* __restrict__ pos_bf,
          const int* __restrict__ ss, const int* __restrict__ sd,
          const ushortT* __restrict__ q_bf, const ushortT* __restrict__ k_bf,
          const ushortT* __restrict__ v_bf, const ushortT* __restrict__ Bpack,
          const float* __restrict__ pb1, const float* __restrict__ pb2,
          const float* __restrict__ ab1, const float* __restrict__ ab2,
          float* __restrict__ z, float* __restrict__ aggU, int E)
{
    __shared__ ushortT Aslab[4][EPW][LDSW];   // 17.4 KB
    __shared__ ushortT Vslab[4][EPW][LDSW];   // 17.4 KB
    __shared__ int     Dslab[4][EPW];         // 256 B
    const int tid = threadIdx.x;
    const int wv = tid >> 6, lane = tid & 63;
    const int quad = lane >> 4, m16 = lane & 15;
    const int row = lane >> 2, li = lane & 3;      // line-coherent staging mapping
    ushortT (*A)[LDSW] = Aslab[wv];
    ushortT (*V)[LDSW] = Vslab[wv];

    float pb1v[8], pb2v[8], ab1v[8], ab2v[8];
#pragma unroll
    for (int nt = 0; nt < 8; ++nt) {
        pb1v[nt] = pb1[nt * 16 + m16]; pb2v[nt] = pb2[nt * 16 + m16];
        ab1v[nt] = ab1[nt * 16 + m16]; ab2v[nt] = ab2[nt * 16 + m16];
    }

    const ushortT* B0 = Bpack;
    const ushortT* B1 = Bpack + 16384;
    const ushortT* B2 = Bpack + 32768;
    const ushortT* B3 = Bpack + 49152;

    const int wave_base = (blockIdx.x * 4 + wv) * (GTILES * EPW);

    const int c2 = lane * 2;
    int   cur_dst = -1;
    float zs0 = 0.f, zs1 = 0.f, gs0 = 0.f, gs1 = 0.f;

#pragma unroll 1
    for (int t = 0; t < GTILES; ++t) {
        const int e_base = wave_base + t * EPW;
        const int eidx = min(e_base + row, E - 1);
        const int es = ss[eidx], ed = sd[eidx];
        int sdr[4];
#pragma unroll
        for (int r = 0; r < 4; ++r)
            sdr[r] = sd[min(e_base + quad * 4 + r, E - 1)];
        if (m16 == 0) {
#pragma unroll
            for (int r = 0; r < 4; ++r) Dslab[wv][quad * 4 + r] = sdr[r];
        }

        ushort8 Pd[4], Ps[4], Qv[4], Kv[4], Vv[4];
        gather4(pos_bf, ed, li, Pd); gather4(pos_bf, es, li, Ps);
        gather4(q_bf,  ed, li, Qv); gather4(k_bf,  es, li, Kv);
        gather4(v_bf,  es, li, Vv);

        // ---- A0 = bf16(pos[dst] - pos[src]); stage v into Vslab ----
#pragma unroll
        for (int i = 0; i < 4; ++i) {
            const uintx4 pd = *(const uintx4*)&Pd[i];
            const uintx4 ps = *(const uintx4*)&Ps[i];
            uintx4 o;
#pragma unroll
            for (int w = 0; w < 4; ++w) {
                const float2 a = upk2(pd[w]), b = upk2(ps[w]);
                o[w] = pk2(a.x - b.x, a.y - b.y);
            }
            *(uintx4*)&A[row][i * 32 + li * 8] = o;
            *(ushort8*)&V[row][i * 32 + li * 8] = Vv[i];
        }

        floatx4 acc[8];

        // ---- pos_nn layer 1 ----
        wave_gemm(A, B0, quad, m16, lane, acc);
        cstore_relu_r(A, acc, pb1v, quad, m16);

        // ---- pos_nn layer 2 -> delta (packed regs + slab) ----
        wave_gemm(A, B1, quad, m16, lane, acc);
        unsigned dlp[8][2];
#pragma unroll
        for (int nt = 0; nt < 8; ++nt) {
            const float b = pb2v[nt];
            const unsigned p0 = pk2(fmaxf(acc[nt][0] + b, 0.f), fmaxf(acc[nt][1] + b, 0.f));
            const unsigned p1 = pk2(fmaxf(acc[nt][2] + b, 0.f), fmaxf(acc[nt][3] + b, 0.f));
            dlp[nt][0] = p0; dlp[nt][1] = p1;
            A[quad * 4 + 0][nt * 16 + m16] = (ushortT)(p0 & 0xffffu);
            A[quad * 4 + 1][nt * 16 + m16] = (ushortT)(p0 >> 16);
            A[quad * 4 + 2][nt * 16 + m16] = (ushortT)(p1 & 0xffffu);
            A[quad * 4 + 3][nt * 16 + m16] = (ushortT)(p1 >> 16);
        }

        // ---- A2 = bf16( q[dst] - k[src] + delta ) ----
#pragma unroll
        for (int i = 0; i < 4; ++i) {
            const uintx4 dv = *(const uintx4*)&A[row][i * 32 + li * 8];
            const uintx4 qv = *(const uintx4*)&Qv[i];
            const uintx4 kv = *(const uintx4*)&Kv[i];
            uintx4 o;
#pragma unroll
            for (int w = 0; w < 4; ++w) {
                const float2 qq = upk2(qv[w]), kk = upk2(kv[w]), dd = upk2(dv[w]);
                o[w] = pk2(qq.x - kk.x + dd.x, qq.y - kk.y + dd.y);
            }
            *(uintx4*)&A[row][i * 32 + li * 8] = o;
        }

        // ---- attn_nn layer 1 ----
        wave_gemm(A, B2, quad, m16, lane, acc);
        cstore_relu_r(A, acc, ab1v, quad, m16);

        // ---- attn_nn layer 2 -> ea = exp(relu(alpha+b)) ----
        wave_gemm(A, B3, quad, m16, lane, acc);
#pragma unroll
        for (int nt = 0; nt < 8; ++nt) {
            const float b = ab2v[nt];
#pragma unroll
            for (int r = 0; r < 4; ++r)
                acc[nt][r] = __expf(fmaxf(acc[nt][r] + b, 0.f));  // alpha>=0, O(1): no max-shift
        }

        // ---- zero ea for out-of-range (clamped duplicate) edges ----
        if (e_base + EPW > E) {
#pragma unroll
            for (int r = 0; r < 4; ++r)
                if (e_base + quad * 4 + r >= E) {
#pragma unroll
                    for (int nt = 0; nt < 8; ++nt) acc[nt][r] = 0.f;
                }
        }

        // ---- transpose: A <- ea (bf16), V <- v+delta (bf16), edge-major ----
#pragma unroll
        for (int nt = 0; nt < 8; ++nt) {
#pragma unroll
            for (int r = 0; r < 4; ++r) {
                const float2 dpair = upk2(dlp[nt][r >> 1]);
                const float dlv = (r & 1) ? dpair.y : dpair.x;
                const int ridx = quad * 4 + r, cidx = nt * 16 + m16;
                const float vv = bf2f(V[ridx][cidx]);
                V[ridx][cidx] = f2bf(vv + dlv);
                A[ridx][cidx] = f2bf(acc[nt][r]);
            }
        }

        // ---- per-lane segmented scan over the 16 sorted edges ----
#pragma unroll 4
        for (int e = 0; e < EPW; ++e) {
            const int d = Dslab[wv][e];
            const float2 ea2 = upk2(*(const unsigned*)&A[e][c2]);
            const float2 vp2 = upk2(*(const unsigned*)&V[e][c2]);
            if (d != cur_dst) {
                if (cur_dst >= 0) {
                    float* zp = z    + (size_t)cur_dst * C + c2;
                    float* gp = aggU + (size_t)cur_dst * C + c2;
                    atomic_add_f32(zp,     zs0);
                    atomic_add_f32(zp + 1, zs1);
                    atomic_add_f32(gp,     gs0);
                    atomic_add_f32(gp + 1, gs1);
                }
                cur_dst = d;
                zs0 = ea2.x;           zs1 = ea2.y;
                gs0 = ea2.x * vp2.x;   gs1 = ea2.y * vp2.y;
            } else {
                zs0 += ea2.x;                   zs1 += ea2.y;
                gs0 = fmaf(ea2.x, vp2.x, gs0);  gs1 = fmaf(ea2.y, vp2.y, gs1);
            }
        }
    }

    // ---- final flush ----
    if (cur_dst >= 0) {
        float* zp = z    + (size_t)cur_dst * C + c2;
        float* gp = aggU + (size_t)cur_dst * C + c2;
        atomic_add_f32(zp,     zs0);
        atomic_add_f32(zp + 1, zs1);
        atomic_add_f32(gp,     gs0);
        atomic_add_f32(gp + 1, gs1);
    }
}

// ============================================================================
// kernel 3: out = relu( (aggU / (z+1e-16)) @ W_out + b_out )  [exact fp32]
// ============================================================================
extern "C" __global__ void __launch_bounds__(THREADS)
out_kernel(const float* __restrict__ aggU, const float* __restrict__ z,
           const float* __restrict__ W_out, const float* __restrict__ b_out,
           float* __restrict__ out, int N)
{
    __shared__ __align__(16) float s_in[TILE * C];
    const int tx = threadIdx.x;
    const int rg = tx >> 5;
    const int oc0 = (tx & 31) << 2;
    const int row0 = blockIdx.x * TILE;

#pragma unroll
    for (int j = 0; j < 8; ++j) {
        const int r = rg * 8 + j, n = row0 + r;
        float4 a; a.x = a.y = a.z = a.w = 0.f;
        if (n < N) {
            const float4 g  = *(const float4*)(aggU + (size_t)n * C + oc0);
            const float4 zz = *(const float4*)(z    + (size_t)n * C + oc0);
            a.x = g.x / (zz.x + 1e-16f);
            a.y = g.y / (zz.y + 1e-16f);
            a.z = g.z / (zz.z + 1e-16f);
            a.w = g.w / (zz.w + 1e-16f);
        }
        *(float4*)(s_in + r * C + oc0) = a;
    }

    float acc[8][4];
    zero_acc(acc);
    tile_gemm(s_in, W_out, acc, rg, oc0);
    bias_relu(acc, b_out, oc0);
#pragma unroll
    for (int j = 0; j < 8; ++j) {
        const int n = row0 + rg * 8 + j;
        if (n < N) { float4 t; t.x=acc[j][0]; t.y=acc[j][1]; t.z=acc[j][2]; t.w=acc[j][3];
                     *(float4*)(out + (size_t)n * C + oc0) = t; }
    }
}

// ---------------------------------------------------------------------------
extern "C" void kernel_launch(void* const* d_in, const int* in_sizes, int n_in,
                              void* d_out, int out_size, void* d_ws, size_t ws_size,
                              hipStream_t stream)
{
    const float* x     = (const float*)d_in[0];
    const float* pos   = (const float*)d_in[1];
    const int*   ei    = (const int*)  d_in[2];
    const float* W_in  = (const float*)d_in[3];
    const float* b_in  = (const float*)d_in[4];
    const float* W_lin = (const float*)d_in[5];
    const float* W_src = (const float*)d_in[6];
    const float* W_dst = (const float*)d_in[7];
    const float* pw1   = (const float*)d_in[8];
    const float* pb1   = (const float*)d_in[9];
    const float* pw2   = (const float*)d_in[10];
    const float* pb2   = (const float*)d_in[11];
    const float* aw1   = (const float*)d_in[12];
    const float* ab1   = (const float*)d_in[13];
    const float* aw2   = (const float*)d_in[14];
    const float* ab2   = (const float*)d_in[15];
    const float* W_out = (const float*)d_in[16];
    const float* b_out = (const float*)d_in[17];

    const int N = in_sizes[0] / C;
    const int E = in_sizes[2] / 2;
    const size_t NC = (size_t)N * C;

    // workspace layout: [z | aggU | deg | cur] (one memset) | off | ss | sd |
    //                   q | k | v | pos_bf | Bpack | Bpack2
    float*   z      = (float*)d_ws;                          // [N,C] fp32
    float*   aggU   = z + NC;                                // [N,C] fp32
    int*     deg    = (int*)(aggU + NC);                     // [N]
    int*     curp   = deg + N;                               // [N]
    int*     offp   = curp + N;                              // [N]
    int*     ss     = offp + N;                              // [E] sorted src
    int*     sdst   = ss + E;                                // [E] sorted dst
    ushortT* q_bf   = (ushortT*)(sdst + E);                  // [N,C] bf16
    ushortT* k_bf   = q_bf + NC;
    ushortT* v_bf   = k_bf + NC;
    ushortT* pos_bf = v_bf + NC;
    ushortT* Bpack  = pos_bf + NC;                           // 65536 bf16 (edge MLP weights)
    ushortT* Bpack2 = Bpack + 65536;                         // 65536 bf16 (Wdst,Wsrc,Wlin,Win)

    hipMemsetAsync(z, 0, 2 * NC * sizeof(float) + 2 * (size_t)N * sizeof(int), stream);

    const int nb_cvt  = (N * 32 + 255) / 256;
    const int nb_hist = (E + 255) / 256;
    prep1<<<512 + nb_cvt + nb_hist, 256, 0, stream>>>(pw1, pw2, aw1, aw2,
                                                      W_dst, W_src, W_lin, W_in,
                                                      pos, pos_bf, ei, deg,
                                                      Bpack, Bpack2, N, E);

    k_scan<<<1, 1024, 0, stream>>>(deg, offp, N);

    const int nb = (N + TILE - 1) / TILE;
    prep2<<<nb + nb_hist, 256, 0, stream>>>(x, b_in, Bpack2, q_bf, k_bf, v_bf,
                                            ei, offp, curp, ss, sdst, N, E, nb);

    const int edges_per_block = 4 * GTILES * EPW;            // 512
    const int eb = (E + edges_per_block - 1) / edges_per_block;
    edge_mfma<<<eb, THREADS, 0, stream>>>(pos_bf, ss, sdst, q_bf, k_bf, v_bf, Bpack,
                                          pb1, pb2, ab1, ab2, z, aggU, E);
    out_kernel<<<nb, THREADS, 0, stream>>>(aggU, z, W_out, b_out, (float*)d_out, N);
}

// Round 5
// 709.649 us; speedup vs baseline: 1.4202x; 1.0541x over previous
//
#include <hip/hip_runtime.h>
#include <hip/hip_bf16.h>

#define C 128
#define THREADS 256      // 4 waves/block
#define TILE 64          // node rows per block
#define EPW 16           // edges per wave-tile
#define GTILES 8         // tiles per wave, steady-state loop (NOT unrolled)
#define LDSPAD 8
#define LDSW (C + LDSPAD)    // 136 ushorts/row

typedef unsigned short ushortT;
typedef __attribute__((ext_vector_type(8))) short short8;
typedef __attribute__((ext_vector_type(8))) ushortT ushort8;
typedef __attribute__((ext_vector_type(4))) float floatx4;
typedef __attribute__((ext_vector_type(4))) unsigned uintx4;

// ---- bf16 helpers ----
__device__ __forceinline__ unsigned pk2(float a, float b) {     // float2 -> 2x bf16 (RNE, 1 inst)
    float2 f; f.x = a; f.y = b;
    union { unsigned u; __hip_bfloat162 h; } cv; cv.h = __float22bfloat162_rn(f);
    return cv.u;
}
__device__ __forceinline__ ushortT f2bf(float x) {              // HW RNE via cvt_pk
    return (ushortT)(pk2(x, x) & 0xffffu);
}
__device__ __forceinline__ float bf2f(ushortT h) {
    union { unsigned u; float f; } v; v.u = ((unsigned)h) << 16;
    return v.f;
}
__device__ __forceinline__ float2 upk2(unsigned u) {            // 2x bf16 -> float2
    union { unsigned u; __hip_bfloat162 h; } cv; cv.u = u;
    return __bfloat1622float2(cv.h);
}
__device__ __forceinline__ void atomic_add_f32(float* p, float v) {
    __hip_atomic_fetch_add(p, v, __ATOMIC_RELAXED, __HIP_MEMORY_SCOPE_AGENT);
}

// ============================================================================
// fp32 micro-GEMM helpers (out_kernel only)
// ============================================================================
__device__ __forceinline__ void zero_acc(float acc[8][4]) {
#pragma unroll
    for (int j = 0; j < 8; ++j)
#pragma unroll
        for (int i = 0; i < 4; ++i) acc[j][i] = 0.f;
}

__device__ __forceinline__ void tile_gemm(const float* __restrict__ s_in,
                                          const float* __restrict__ W,
                                          float acc[8][4], int rg, int oc0)
{
#pragma unroll 2
    for (int kc = 0; kc < C; kc += 4) {
        const float4 w0 = *(const float4*)(W + (kc + 0) * C + oc0);
        const float4 w1 = *(const float4*)(W + (kc + 1) * C + oc0);
        const float4 w2 = *(const float4*)(W + (kc + 2) * C + oc0);
        const float4 w3 = *(const float4*)(W + (kc + 3) * C + oc0);
#pragma unroll
        for (int j = 0; j < 8; ++j) {
            const float4 a = *(const float4*)(s_in + (rg * 8 + j) * C + kc);
            acc[j][0] = fmaf(a.w, w3.x, fmaf(a.z, w2.x, fmaf(a.y, w1.x, fmaf(a.x, w0.x, acc[j][0]))));
            acc[j][1] = fmaf(a.w, w3.y, fmaf(a.z, w2.y, fmaf(a.y, w1.y, fmaf(a.x, w0.y, acc[j][1]))));
            acc[j][2] = fmaf(a.w, w3.z, fmaf(a.z, w2.z, fmaf(a.y, w1.z, fmaf(a.x, w0.z, acc[j][2]))));
            acc[j][3] = fmaf(a.w, w3.w, fmaf(a.z, w2.w, fmaf(a.y, w1.w, fmaf(a.x, w0.w, acc[j][3]))));
        }
    }
}

__device__ __forceinline__ void bias_relu(float acc[8][4], const float* __restrict__ b, int oc0) {
    const float4 bv = *(const float4*)(b + oc0);
#pragma unroll
    for (int j = 0; j < 8; ++j) {
        acc[j][0] = fmaxf(acc[j][0] + bv.x, 0.f);
        acc[j][1] = fmaxf(acc[j][1] + bv.y, 0.f);
        acc[j][2] = fmaxf(acc[j][2] + bv.z, 0.f);
        acc[j][3] = fmaxf(acc[j][3] + bv.w, 0.f);
    }
}

// ============================================================================
// MFMA helpers (zero-init acc, bias in epilogue — round-2-proven codegen)
// ============================================================================
__device__ __forceinline__ void wave_gemm(const ushortT (*A)[LDSW],
                                          const ushortT* __restrict__ Bp,
                                          int quad, int m16, int lane,
                                          floatx4 acc[8])
{
#pragma unroll
    for (int nt = 0; nt < 8; ++nt) { acc[nt][0]=0.f; acc[nt][1]=0.f; acc[nt][2]=0.f; acc[nt][3]=0.f; }
#pragma unroll 1
    for (int ks = 0; ks < 4; ++ks) {
        const short8 af = *(const short8*)&A[m16][ks * 32 + quad * 8];
        const ushortT* bpk = Bp + (size_t)ks * 4096 + (size_t)lane * 8;
#pragma unroll
        for (int nt = 0; nt < 8; ++nt) {
            const short8 bf = *(const short8*)(bpk + nt * 512);
            acc[nt] = __builtin_amdgcn_mfma_f32_16x16x32_bf16(af, bf, acc[nt], 0, 0, 0);
        }
    }
}

__device__ __forceinline__ void cstore_relu_r(ushortT (*A)[LDSW], floatx4 acc[8],
                                              const float bias[8], int quad, int m16)
{
#pragma unroll
    for (int nt = 0; nt < 8; ++nt) {
        const float b = bias[nt];
#pragma unroll
        for (int r = 0; r < 4; r += 2) {
            const unsigned p = pk2(fmaxf(acc[nt][r] + b, 0.f), fmaxf(acc[nt][r + 1] + b, 0.f));
            A[quad * 4 + r][nt * 16 + m16]     = (ushortT)(p & 0xffffu);
            A[quad * 4 + r + 1][nt * 16 + m16] = (ushortT)(p >> 16);
        }
    }
}

// pack one matrix entry into MFMA B-fragment order
__device__ __forceinline__ ushortT pack_one(const float* __restrict__ W, int u) {
    const int j = u & 7, lane = (u >> 3) & 63, f = u >> 9;  // u in [0,16384)
    const int nt = f & 7, ks = f >> 3;
    const int n = nt * 16 + (lane & 15);
    const int k = ks * 32 + (lane >> 4) * 8 + j;
    return f2bf(W[k * C + n]);
}

// ============================================================================
// prep1 (fused): pack Bpack (edge MLP), pack Bpack2 (Wdst,Wsrc,Wlin,Win),
// cvt pos->bf16 (float4 vectorized), hist of dst degrees. Block-role ranges.
// ============================================================================
extern "C" __global__ void __launch_bounds__(256)
prep1(const float* __restrict__ pw1, const float* __restrict__ pw2,
      const float* __restrict__ aw1, const float* __restrict__ aw2,
      const float* __restrict__ Wd,  const float* __restrict__ Wsrc,
      const float* __restrict__ Wl,  const float* __restrict__ Win,
      const float* __restrict__ pos, ushortT* __restrict__ pos_bf,
      const int* __restrict__ ei, int* __restrict__ deg,
      ushortT* __restrict__ Bpack, ushortT* __restrict__ Bpack2, int N, int E)
{
    const int nb_cvt = (N * 32 + 255) / 256;
    const int b = blockIdx.x, tid = threadIdx.x;
    if (b < 256) {
        const int t = b * 256 + tid;
        const int s = t >> 14;
        const float* W = (s == 0) ? pw1 : (s == 1) ? pw2 : (s == 2) ? aw1 : aw2;
        Bpack[t] = pack_one(W, t & 16383);
    } else if (b < 512) {
        const int t = (b - 256) * 256 + tid;
        const int s = t >> 14;
        const float* W = (s == 0) ? Wd : (s == 1) ? Wsrc : (s == 2) ? Wl : Win;
        Bpack2[t] = pack_one(W, t & 16383);
    } else if (b < 512 + nb_cvt) {
        const int i = (b - 512) * 256 + tid;
        if (i < N * 32) {
            const float4 v = ((const float4*)pos)[i];
            uint2 o; o.x = pk2(v.x, v.y); o.y = pk2(v.z, v.w);
            ((uint2*)pos_bf)[i] = o;
        }
    } else {
        const int e = (b - 512 - nb_cvt) * 256 + tid;
        if (e < E) atomicAdd(&deg[ei[E + e]], 1);
    }
}

extern "C" __global__ void __launch_bounds__(1024)
k_scan(const int* __restrict__ deg, int* __restrict__ off, int n)
{
    __shared__ int part[1024];
    const int t = threadIdx.x;
    const int chunk = (n + 1023) / 1024;
    const int lo = t * chunk, hi = min(lo + chunk, n);
    int s = 0;
    for (int i = lo; i < hi; ++i) s += deg[i];
    part[t] = s;
    __syncthreads();
    for (int d = 1; d < 1024; d <<= 1) {
        int v = (t >= d) ? part[t - d] : 0;
        __syncthreads();
        part[t] += v;
        __syncthreads();
    }
    int run = (t == 0) ? 0 : part[t - 1];
    for (int i = lo; i < hi; ++i) { off[i] = run; run += deg[i]; }
}

// ============================================================================
// prep2 (fused): node role (all-MFMA qkv) + scatter role.
// ============================================================================
extern "C" __global__ void __launch_bounds__(256)
prep2(const float* __restrict__ x, const float* __restrict__ b_in,
      const ushortT* __restrict__ Bp2,
      ushortT* __restrict__ q_bf, ushortT* __restrict__ k_bf, ushortT* __restrict__ v_bf,
      const int* __restrict__ ei, const int* __restrict__ offp, int* __restrict__ curp,
      int* __restrict__ ss, int* __restrict__ sd, int N, int E, int nb_node)
{
    __shared__ ushortT xs[TILE][LDSW];   // 17.4 KB (ostage overlays this)
    __shared__ ushortT hs[TILE][LDSW];   // 17.4 KB
    const int b = blockIdx.x, tx = threadIdx.x;

    if (b >= nb_node) {
        // ---- scatter role ----
        const int e = (b - nb_node) * 256 + tx;
        if (e < E) {
            const int d = ei[E + e];
            const int p = offp[d] + atomicAdd(&curp[d], 1);
            ss[p] = ei[e];
            sd[p] = d;
        }
        return;
    }

    // ---- node role ----
    const int rg = tx >> 5;
    const int oc0 = (tx & 31) << 2;
    const int row0 = b * TILE;

    // stage x -> bf16 (wave-private rows)
#pragma unroll
    for (int j = 0; j < 8; ++j) {
        const int r = rg * 8 + j, n = row0 + r;
        float4 xv; xv.x = xv.y = xv.z = xv.w = 0.f;
        if (n < N) xv = *(const float4*)(x + (size_t)n * C + oc0);
        *(unsigned*)&xs[r][oc0]     = pk2(xv.x, xv.y);
        *(unsigned*)&xs[r][oc0 + 2] = pk2(xv.z, xv.w);
    }

    const int wv = tx >> 6, lane = tx & 63;
    const int quad = lane >> 4, m16 = lane & 15;
    const int row = lane >> 2, li = lane & 3;

    float binv[8];
#pragma unroll
    for (int nt = 0; nt < 8; ++nt) binv[nt] = b_in[nt * 16 + m16];

    const ushortT (*Ax)[LDSW] = (const ushortT (*)[LDSW])&xs[wv * 16];
    ushortT (*Ah)[LDSW] = (ushortT (*)[LDSW])&hs[wv * 16];

    floatx4 macc[8];
    // h = relu(x @ W_in + b_in)   (W_in in Bpack2 slot 3)
    wave_gemm(Ax, Bp2 + (size_t)3 * 16384, quad, m16, lane, macc);
    cstore_relu_r(Ah, macc, binv, quad, m16);

    __syncthreads();   // all xs reads done before ostage overlay writes

    ushortT (*OS)[LDSW] = (ushortT (*)[LDSW])&xs[wv * 16];   // ostage overlay
    ushortT* outs[3];
    outs[0] = q_bf; outs[1] = k_bf; outs[2] = v_bf;

#pragma unroll 1
    for (int m = 0; m < 3; ++m) {
        wave_gemm((const ushortT (*)[LDSW])Ah, Bp2 + (size_t)m * 16384, quad, m16, lane, macc);
#pragma unroll
        for (int nt = 0; nt < 8; ++nt) {
#pragma unroll
            for (int r = 0; r < 4; r += 2) {
                const unsigned p = pk2(macc[nt][r], macc[nt][r + 1]);
                OS[quad * 4 + r][nt * 16 + m16]     = (ushortT)(p & 0xffffu);
                OS[quad * 4 + r + 1][nt * 16 + m16] = (ushortT)(p >> 16);
            }
        }
        const int n = row0 + wv * 16 + row;
        if (n < N) {
#pragma unroll
            for (int i = 0; i < 4; ++i) {
                const ushort8 v8 = *(const ushort8*)&OS[row][i * 32 + li * 8];
                *(ushort8*)(outs[m] + (size_t)n * C + i * 32 + li * 8) = v8;
            }
        }
    }
}

// ============================================================================
// kernel 2 (MFMA): edges SORTED BY DST; segmented-scan epilogue.
// This round: 256B-aligned gather arrays + next-tile index prefetch.
// ============================================================================
__device__ __forceinline__ void gather4(const ushortT* __restrict__ base, int node, int li,
                                        ushort8 dst[4])
{
    const ushort8* p = (const ushort8*)(base + (size_t)node * C) + li;
    dst[0] = p[0]; dst[1] = p[4]; dst[2] = p[8]; dst[3] = p[12];   // chunk i at ushort8 index i*4+li
}

extern "C" __global__ void __launch_bounds__(THREADS)
edge_mfma(const ushortT* __restrict__ pos_bf,
          const int* __restrict__ ss, const int* __restrict__ sd,
          const ushortT* __restrict__ q_bf, const ushortT* __restrict__ k_bf,
          const ushortT* __restrict__ v_bf, const ushortT* __restrict__ Bpack,
          const float* __restrict__ pb1, const float* __restrict__ pb2,
          const float* __restrict__ ab1, const float* __restrict__ ab2,
          float* __restrict__ z, float* __restrict__ aggU, int E)
{
    __shared__ ushortT Aslab[4][EPW][LDSW];   // 17.4 KB
    __shared__ ushortT Vslab[4][EPW][LDSW];   // 17.4 KB
    __shared__ int     Dslab[4][EPW];         // 256 B
    const int tid = threadIdx.x;
    const int wv = tid >> 6, lane = tid & 63;
    const int quad = lane >> 4, m16 = lane & 15;
    const int row = lane >> 2, li = lane & 3;      // line-coherent staging mapping
    ushortT (*A)[LDSW] = Aslab[wv];
    ushortT (*V)[LDSW] = Vslab[wv];

    float pb1v[8], pb2v[8], ab1v[8], ab2v[8];
#pragma unroll
    for (int nt = 0; nt < 8; ++nt) {
        pb1v[nt] = pb1[nt * 16 + m16]; pb2v[nt] = pb2[nt * 16 + m16];
        ab1v[nt] = ab1[nt * 16 + m16]; ab2v[nt] = ab2[nt * 16 + m16];
    }

    const ushortT* B0 = Bpack;
    const ushortT* B1 = Bpack + 16384;
    const ushortT* B2 = Bpack + 32768;
    const ushortT* B3 = Bpack + 49152;

    const int wave_base = (blockIdx.x * 4 + wv) * (GTILES * EPW);

    const int c2 = lane * 2;
    int   cur_dst = -1;
    float zs0 = 0.f, zs1 = 0.f, gs0 = 0.f, gs1 = 0.f;

    // ---- prologue: indices for tile 0 ----
    int es, ed, sdr[4];
    {
        const int eidx = min(wave_base + row, E - 1);
        es = ss[eidx]; ed = sd[eidx];
#pragma unroll
        for (int r = 0; r < 4; ++r)
            sdr[r] = sd[min(wave_base + quad * 4 + r, E - 1)];
    }

#pragma unroll 1
    for (int t = 0; t < GTILES; ++t) {
        const int e_base = wave_base + t * EPW;
        if (m16 == 0) {
#pragma unroll
            for (int r = 0; r < 4; ++r) Dslab[wv][quad * 4 + r] = sdr[r];
        }

        ushort8 Pd[4], Ps[4], Qv[4], Kv[4], Vv[4];
        gather4(pos_bf, ed, li, Pd); gather4(pos_bf, es, li, Ps);
        gather4(q_bf,  ed, li, Qv); gather4(k_bf,  es, li, Kv);
        gather4(v_bf,  es, li, Vv);

        // ---- A0 = bf16(pos[dst] - pos[src]); stage v into Vslab ----
#pragma unroll
        for (int i = 0; i < 4; ++i) {
            const uintx4 pd = *(const uintx4*)&Pd[i];
            const uintx4 ps = *(const uintx4*)&Ps[i];
            uintx4 o;
#pragma unroll
            for (int w = 0; w < 4; ++w) {
                const float2 a = upk2(pd[w]), b = upk2(ps[w]);
                o[w] = pk2(a.x - b.x, a.y - b.y);
            }
            *(uintx4*)&A[row][i * 32 + li * 8] = o;
            *(ushort8*)&V[row][i * 32 + li * 8] = Vv[i];
        }

        floatx4 acc[8];

        // ---- pos_nn layer 1 ----
        wave_gemm(A, B0, quad, m16, lane, acc);
        cstore_relu_r(A, acc, pb1v, quad, m16);

        // ---- pos_nn layer 2 -> delta (packed regs + slab) ----
        wave_gemm(A, B1, quad, m16, lane, acc);
        unsigned dlp[8][2];
#pragma unroll
        for (int nt = 0; nt < 8; ++nt) {
            const float b = pb2v[nt];
            const unsigned p0 = pk2(fmaxf(acc[nt][0] + b, 0.f), fmaxf(acc[nt][1] + b, 0.f));
            const unsigned p1 = pk2(fmaxf(acc[nt][2] + b, 0.f), fmaxf(acc[nt][3] + b, 0.f));
            dlp[nt][0] = p0; dlp[nt][1] = p1;
            A[quad * 4 + 0][nt * 16 + m16] = (ushortT)(p0 & 0xffffu);
            A[quad * 4 + 1][nt * 16 + m16] = (ushortT)(p0 >> 16);
            A[quad * 4 + 2][nt * 16 + m16] = (ushortT)(p1 & 0xffffu);
            A[quad * 4 + 3][nt * 16 + m16] = (ushortT)(p1 >> 16);
        }

        // ---- A2 = bf16( q[dst] - k[src] + delta ) ----
#pragma unroll
        for (int i = 0; i < 4; ++i) {
            const uintx4 dv = *(const uintx4*)&A[row][i * 32 + li * 8];
            const uintx4 qv = *(const uintx4*)&Qv[i];
            const uintx4 kv = *(const uintx4*)&Kv[i];
            uintx4 o;
#pragma unroll
            for (int w = 0; w < 4; ++w) {
                const float2 qq = upk2(qv[w]), kk = upk2(kv[w]), dd = upk2(dv[w]);
                o[w] = pk2(qq.x - kk.x + dd.x, qq.y - kk.y + dd.y);
            }
            *(uintx4*)&A[row][i * 32 + li * 8] = o;
        }

        // ---- prefetch next tile's indices (hides under attn MFMAs + scan) ----
        int nes = es, ned = ed, nsdr[4];
#pragma unroll
        for (int r = 0; r < 4; ++r) nsdr[r] = sdr[r];
        if (t + 1 < GTILES) {
            const int e2 = e_base + EPW;
            const int ei2 = min(e2 + row, E - 1);
            nes = ss[ei2]; ned = sd[ei2];
#pragma unroll
            for (int r = 0; r < 4; ++r)
                nsdr[r] = sd[min(e2 + quad * 4 + r, E - 1)];
        }

        // ---- attn_nn layer 1 ----
        wave_gemm(A, B2, quad, m16, lane, acc);
        cstore_relu_r(A, acc, ab1v, quad, m16);

        // ---- attn_nn layer 2 -> ea = exp(relu(alpha+b)) ----
        wave_gemm(A, B3, quad, m16, lane, acc);
#pragma unroll
        for (int nt = 0; nt < 8; ++nt) {
            const float b = ab2v[nt];
#pragma unroll
            for (int r = 0; r < 4; ++r)
                acc[nt][r] = __expf(fmaxf(acc[nt][r] + b, 0.f));  // alpha>=0, O(1): no max-shift
        }

        // ---- zero ea for out-of-range (clamped duplicate) edges ----
        if (e_base + EPW > E) {
#pragma unroll
            for (int r = 0; r < 4; ++r)
                if (e_base + quad * 4 + r >= E) {
#pragma unroll
                    for (int nt = 0; nt < 8; ++nt) acc[nt][r] = 0.f;
                }
        }

        // ---- transpose: A <- ea (bf16), V <- v+delta (bf16), edge-major ----
#pragma unroll
        for (int nt = 0; nt < 8; ++nt) {
#pragma unroll
            for (int r = 0; r < 4; ++r) {
                const float2 dpair = upk2(dlp[nt][r >> 1]);
                const float dlv = (r & 1) ? dpair.y : dpair.x;
                const int ridx = quad * 4 + r, cidx = nt * 16 + m16;
                const float vv = bf2f(V[ridx][cidx]);
                V[ridx][cidx] = f2bf(vv + dlv);
                A[ridx][cidx] = f2bf(acc[nt][r]);
            }
        }

        // ---- per-lane segmented scan over the 16 sorted edges ----
#pragma unroll 4
        for (int e = 0; e < EPW; ++e) {
            const int d = Dslab[wv][e];
            const float2 ea2 = upk2(*(const unsigned*)&A[e][c2]);
            const float2 vp2 = upk2(*(const unsigned*)&V[e][c2]);
            if (d != cur_dst) {
                if (cur_dst >= 0) {
                    float* zp = z    + (size_t)cur_dst * C + c2;
                    float* gp = aggU + (size_t)cur_dst * C + c2;
                    atomic_add_f32(zp,     zs0);
                    atomic_add_f32(zp + 1, zs1);
                    atomic_add_f32(gp,     gs0);
                    atomic_add_f32(gp + 1, gs1);
                }
                cur_dst = d;
                zs0 = ea2.x;           zs1 = ea2.y;
                gs0 = ea2.x * vp2.x;   gs1 = ea2.y * vp2.y;
            } else {
                zs0 += ea2.x;                   zs1 += ea2.y;
                gs0 = fmaf(ea2.x, vp2.x, gs0);  gs1 = fmaf(ea2.y, vp2.y, gs1);
            }
        }

        // rotate prefetched indices
        es = nes; ed = ned;
#pragma unroll
        for (int r = 0; r < 4; ++r) sdr[r] = nsdr[r];
    }

    // ---- final flush ----
    if (cur_dst >= 0) {
        float* zp = z    + (size_t)cur_dst * C + c2;
        float* gp = aggU + (size_t)cur_dst * C + c2;
        atomic_add_f32(zp,     zs0);
        atomic_add_f32(zp + 1, zs1);
        atomic_add_f32(gp,     gs0);
        atomic_add_f32(gp + 1, gs1);
    }
}

// ============================================================================
// kernel 3: out = relu( (aggU / (z+1e-16)) @ W_out + b_out )  [exact fp32]
// ============================================================================
extern "C" __global__ void __launch_bounds__(THREADS)
out_kernel(const float* __restrict__ aggU, const float* __restrict__ z,
           const float* __restrict__ W_out, const float* __restrict__ b_out,
           float* __restrict__ out, int N)
{
    __shared__ __align__(16) float s_in[TILE * C];
    const int tx = threadIdx.x;
    const int rg = tx >> 5;
    const int oc0 = (tx & 31) << 2;
    const int row0 = blockIdx.x * TILE;

#pragma unroll
    for (int j = 0; j < 8; ++j) {
        const int r = rg * 8 + j, n = row0 + r;
        float4 a; a.x = a.y = a.z = a.w = 0.f;
        if (n < N) {
            const float4 g  = *(const float4*)(aggU + (size_t)n * C + oc0);
            const float4 zz = *(const float4*)(z    + (size_t)n * C + oc0);
            a.x = g.x / (zz.x + 1e-16f);
            a.y = g.y / (zz.y + 1e-16f);
            a.z = g.z / (zz.z + 1e-16f);
            a.w = g.w / (zz.w + 1e-16f);
        }
        *(float4*)(s_in + r * C + oc0) = a;
    }

    float acc[8][4];
    zero_acc(acc);
    tile_gemm(s_in, W_out, acc, rg, oc0);
    bias_relu(acc, b_out, oc0);
#pragma unroll
    for (int j = 0; j < 8; ++j) {
        const int n = row0 + rg * 8 + j;
        if (n < N) { float4 t; t.x=acc[j][0]; t.y=acc[j][1]; t.z=acc[j][2]; t.w=acc[j][3];
                     *(float4*)(out + (size_t)n * C + oc0) = t; }
    }
}

// ---------------------------------------------------------------------------
extern "C" void kernel_launch(void* const* d_in, const int* in_sizes, int n_in,
                              void* d_out, int out_size, void* d_ws, size_t ws_size,
                              hipStream_t stream)
{
    const float* x     = (const float*)d_in[0];
    const float* pos   = (const float*)d_in[1];
    const int*   ei    = (const int*)  d_in[2];
    const float* W_in  = (const float*)d_in[3];
    const float* b_in  = (const float*)d_in[4];
    const float* W_lin = (const float*)d_in[5];
    const float* W_src = (const float*)d_in[6];
    const float* W_dst = (const float*)d_in[7];
    const float* pw1   = (const float*)d_in[8];
    const float* pb1   = (const float*)d_in[9];
    const float* pw2   = (const float*)d_in[10];
    const float* pb2   = (const float*)d_in[11];
    const float* aw1   = (const float*)d_in[12];
    const float* ab1   = (const float*)d_in[13];
    const float* aw2   = (const float*)d_in[14];
    const float* ab2   = (const float*)d_in[15];
    const float* W_out = (const float*)d_in[16];
    const float* b_out = (const float*)d_in[17];

    const int N = in_sizes[0] / C;
    const int E = in_sizes[2] / 2;
    const size_t NC = (size_t)N * C;

    // workspace layout — ALL gathered bf16 arrays 256-B aligned:
    //   z | aggU | q | k | v | pos_bf | Bpack | Bpack2 | deg | cur | off | ss | sd
    // (NC*4 and NC*2 are multiples of 256 for N=50000,C=128; d_ws is page-aligned)
    float*   z      = (float*)d_ws;                          // [N,C] fp32
    float*   aggU   = z + NC;                                // [N,C] fp32
    ushortT* q_bf   = (ushortT*)(aggU + NC);                 // [N,C] bf16 (256B-aligned)
    ushortT* k_bf   = q_bf + NC;
    ushortT* v_bf   = k_bf + NC;
    ushortT* pos_bf = v_bf + NC;
    ushortT* Bpack  = pos_bf + NC;                           // 65536 bf16 (edge MLP weights)
    ushortT* Bpack2 = Bpack + 65536;                         // 65536 bf16 (Wdst,Wsrc,Wlin,Win)
    int*     deg    = (int*)(Bpack2 + 65536);                // [N]
    int*     curp   = deg + N;                               // [N]
    int*     offp   = curp + N;                              // [N]
    int*     ss     = offp + N;                              // [E] sorted src
    int*     sdst   = ss + E;                                // [E] sorted dst

    hipMemsetAsync(z, 0, 2 * NC * sizeof(float), stream);
    hipMemsetAsync(deg, 0, 2 * (size_t)N * sizeof(int), stream);  // deg + cur

    const int nb_cvt  = (N * 32 + 255) / 256;
    const int nb_hist = (E + 255) / 256;
    prep1<<<512 + nb_cvt + nb_hist, 256, 0, stream>>>(pw1, pw2, aw1, aw2,
                                                      W_dst, W_src, W_lin, W_in,
                                                      pos, pos_bf, ei, deg,
                                                      Bpack, Bpack2, N, E);

    k_scan<<<1, 1024, 0, stream>>>(deg, offp, N);

    const int nb = (N + TILE - 1) / TILE;
    prep2<<<nb + nb_hist, 256, 0, stream>>>(x, b_in, Bpack2, q_bf, k_bf, v_bf,
                                            ei, offp, curp, ss, sdst, N, E, nb);

    const int edges_per_block = 4 * GTILES * EPW;            // 512
    const int eb = (E + edges_per_block - 1) / edges_per_block;
    edge_mfma<<<eb, THREADS, 0, stream>>>(pos_bf, ss, sdst, q_bf, k_bf, v_bf, Bpack,
                                          pb1, pb2, ab1, ab2, z, aggU, E);
    out_kernel<<<nb, THREADS, 0, stream>>>(aggU, z, W_out, b_out, (float*)d_out, N);
}

// Round 6
// 621.059 us; speedup vs baseline: 1.6228x; 1.1426x over previous
//
#include <hip/hip_runtime.h>
#include <hip/hip_bf16.h>

#define C 128
#define THREADS 256      // 4 waves/block
#define TILE 64          // node rows per block
#define EPW 16           // edges per wave-tile
#define GTILES 8         // tiles per wave, steady-state loop (NOT unrolled)
#define LDSPAD 8
#define LDSW (C + LDSPAD)    // 136 ushorts/row

typedef unsigned short ushortT;
typedef __attribute__((ext_vector_type(8))) short short8;
typedef __attribute__((ext_vector_type(8))) ushortT ushort8;
typedef __attribute__((ext_vector_type(4))) float floatx4;
typedef __attribute__((ext_vector_type(4))) unsigned uintx4;

// ---- bf16 helpers ----
__device__ __forceinline__ unsigned pk2(float a, float b) {     // float2 -> 2x bf16 (RNE, 1 inst)
    float2 f; f.x = a; f.y = b;
    union { unsigned u; __hip_bfloat162 h; } cv; cv.h = __float22bfloat162_rn(f);
    return cv.u;
}
__device__ __forceinline__ ushortT f2bf(float x) {              // HW RNE via cvt_pk
    return (ushortT)(pk2(x, x) & 0xffffu);
}
__device__ __forceinline__ float bf2f(ushortT h) {
    union { unsigned u; float f; } v; v.u = ((unsigned)h) << 16;
    return v.f;
}
__device__ __forceinline__ float2 upk2(unsigned u) {            // 2x bf16 -> float2
    union { unsigned u; __hip_bfloat162 h; } cv; cv.u = u;
    return __bfloat1622float2(cv.h);
}
__device__ __forceinline__ void atomic_add_f32(float* p, float v) {
    __hip_atomic_fetch_add(p, v, __ATOMIC_RELAXED, __HIP_MEMORY_SCOPE_AGENT);
}

// ============================================================================
// fp32 micro-GEMM helpers (out_kernel only)
// ============================================================================
__device__ __forceinline__ void zero_acc(float acc[8][4]) {
#pragma unroll
    for (int j = 0; j < 8; ++j)
#pragma unroll
        for (int i = 0; i < 4; ++i) acc[j][i] = 0.f;
}

__device__ __forceinline__ void tile_gemm(const float* __restrict__ s_in,
                                          const float* __restrict__ W,
                                          float acc[8][4], int rg, int oc0)
{
#pragma unroll 2
    for (int kc = 0; kc < C; kc += 4) {
        const float4 w0 = *(const float4*)(W + (kc + 0) * C + oc0);
        const float4 w1 = *(const float4*)(W + (kc + 1) * C + oc0);
        const float4 w2 = *(const float4*)(W + (kc + 2) * C + oc0);
        const float4 w3 = *(const float4*)(W + (kc + 3) * C + oc0);
#pragma unroll
        for (int j = 0; j < 8; ++j) {
            const float4 a = *(const float4*)(s_in + (rg * 8 + j) * C + kc);
            acc[j][0] = fmaf(a.w, w3.x, fmaf(a.z, w2.x, fmaf(a.y, w1.x, fmaf(a.x, w0.x, acc[j][0]))));
            acc[j][1] = fmaf(a.w, w3.y, fmaf(a.z, w2.y, fmaf(a.y, w1.y, fmaf(a.x, w0.y, acc[j][1]))));
            acc[j][2] = fmaf(a.w, w3.z, fmaf(a.z, w2.z, fmaf(a.y, w1.z, fmaf(a.x, w0.z, acc[j][2]))));
            acc[j][3] = fmaf(a.w, w3.w, fmaf(a.z, w2.w, fmaf(a.y, w1.w, fmaf(a.x, w0.w, acc[j][3]))));
        }
    }
}

__device__ __forceinline__ void bias_relu(float acc[8][4], const float* __restrict__ b, int oc0) {
    const float4 bv = *(const float4*)(b + oc0);
#pragma unroll
    for (int j = 0; j < 8; ++j) {
        acc[j][0] = fmaxf(acc[j][0] + bv.x, 0.f);
        acc[j][1] = fmaxf(acc[j][1] + bv.y, 0.f);
        acc[j][2] = fmaxf(acc[j][2] + bv.z, 0.f);
        acc[j][3] = fmaxf(acc[j][3] + bv.w, 0.f);
    }
}

// ============================================================================
// MFMA helpers (zero-init acc, bias in epilogue — round-2-proven codegen)
// ============================================================================
__device__ __forceinline__ void wave_gemm(const ushortT (*A)[LDSW],
                                          const ushortT* __restrict__ Bp,
                                          int quad, int m16, int lane,
                                          floatx4 acc[8])
{
#pragma unroll
    for (int nt = 0; nt < 8; ++nt) { acc[nt][0]=0.f; acc[nt][1]=0.f; acc[nt][2]=0.f; acc[nt][3]=0.f; }
#pragma unroll 1
    for (int ks = 0; ks < 4; ++ks) {
        const short8 af = *(const short8*)&A[m16][ks * 32 + quad * 8];
        const ushortT* bpk = Bp + (size_t)ks * 4096 + (size_t)lane * 8;
#pragma unroll
        for (int nt = 0; nt < 8; ++nt) {
            const short8 bf = *(const short8*)(bpk + nt * 512);
            acc[nt] = __builtin_amdgcn_mfma_f32_16x16x32_bf16(af, bf, acc[nt], 0, 0, 0);
        }
    }
}

__device__ __forceinline__ void cstore_relu_r(ushortT (*A)[LDSW], floatx4 acc[8],
                                              const float bias[8], int quad, int m16)
{
#pragma unroll
    for (int nt = 0; nt < 8; ++nt) {
        const float b = bias[nt];
#pragma unroll
        for (int r = 0; r < 4; r += 2) {
            const unsigned p = pk2(fmaxf(acc[nt][r] + b, 0.f), fmaxf(acc[nt][r + 1] + b, 0.f));
            A[quad * 4 + r][nt * 16 + m16]     = (ushortT)(p & 0xffffu);
            A[quad * 4 + r + 1][nt * 16 + m16] = (ushortT)(p >> 16);
        }
    }
}

// pack one matrix entry into MFMA B-fragment order
__device__ __forceinline__ ushortT pack_one(const float* __restrict__ W, int u) {
    const int j = u & 7, lane = (u >> 3) & 63, f = u >> 9;  // u in [0,16384)
    const int nt = f & 7, ks = f >> 3;
    const int n = nt * 16 + (lane & 15);
    const int k = ks * 32 + (lane >> 4) * 8 + j;
    return f2bf(W[k * C + n]);
}

// ============================================================================
// prep1 (fused): pack Bpack (edge MLP), pack Bpack2 (Wdst,Wsrc,Wlin,Win),
// cvt pos->bf16 (float4 vectorized), hist of dst degrees. Block-role ranges.
// ============================================================================
extern "C" __global__ void __launch_bounds__(256)
prep1(const float* __restrict__ pw1, const float* __restrict__ pw2,
      const float* __restrict__ aw1, const float* __restrict__ aw2,
      const float* __restrict__ Wd,  const float* __restrict__ Wsrc,
      const float* __restrict__ Wl,  const float* __restrict__ Win,
      const float* __restrict__ pos, ushortT* __restrict__ pos_bf,
      const int* __restrict__ ei, int* __restrict__ deg,
      ushortT* __restrict__ Bpack, ushortT* __restrict__ Bpack2, int N, int E)
{
    const int nb_cvt = (N * 32 + 255) / 256;
    const int b = blockIdx.x, tid = threadIdx.x;
    if (b < 256) {
        const int t = b * 256 + tid;
        const int s = t >> 14;
        const float* W = (s == 0) ? pw1 : (s == 1) ? pw2 : (s == 2) ? aw1 : aw2;
        Bpack[t] = pack_one(W, t & 16383);
    } else if (b < 512) {
        const int t = (b - 256) * 256 + tid;
        const int s = t >> 14;
        const float* W = (s == 0) ? Wd : (s == 1) ? Wsrc : (s == 2) ? Wl : Win;
        Bpack2[t] = pack_one(W, t & 16383);
    } else if (b < 512 + nb_cvt) {
        const int i = (b - 512) * 256 + tid;
        if (i < N * 32) {
            const float4 v = ((const float4*)pos)[i];
            uint2 o; o.x = pk2(v.x, v.y); o.y = pk2(v.z, v.w);
            ((uint2*)pos_bf)[i] = o;
        }
    } else {
        const int e = (b - 512 - nb_cvt) * 256 + tid;
        if (e < E) atomicAdd(&deg[ei[E + e]], 1);
    }
}

extern "C" __global__ void __launch_bounds__(1024)
k_scan(const int* __restrict__ deg, int* __restrict__ off, int n)
{
    __shared__ int part[1024];
    const int t = threadIdx.x;
    const int chunk = (((n + 1023) / 1024) + 3) & ~3;      // multiple of 4
    const int lo = t * chunk, hi = min(lo + chunk, n);      // n%4==0 -> hi-lo %4==0
    int s = 0;
    for (int i = lo; i < hi; i += 4) {
        const int4 d4 = *(const int4*)(deg + i);
        s += d4.x + d4.y + d4.z + d4.w;
    }
    part[t] = s;
    __syncthreads();
    for (int d = 1; d < 1024; d <<= 1) {
        int v = (t >= d) ? part[t - d] : 0;
        __syncthreads();
        part[t] += v;
        __syncthreads();
    }
    int run = (t == 0) ? 0 : part[t - 1];
    for (int i = lo; i < hi; i += 4) {
        const int4 d4 = *(const int4*)(deg + i);
        int4 o;
        o.x = run;
        o.y = o.x + d4.x;
        o.z = o.y + d4.y;
        o.w = o.z + d4.z;
        *(int4*)(off + i) = o;
        run = o.w + d4.w;
    }
}

// ============================================================================
// prep2 (fused): node role (all-MFMA qkv + P = pos@pw1 hoist) + scatter role.
// Pd_arr = pos@pw1 + pb1 (bf16), Ps_arr = pos@pw1 (bf16): pos_nn layer 1
// becomes an elementwise relu(Pd[d]-Ps[s]) at the edge kernel (linearity).
// ============================================================================
extern "C" __global__ void __launch_bounds__(256)
prep2(const float* __restrict__ x, const float* __restrict__ b_in,
      const ushortT* __restrict__ Bp2, const ushortT* __restrict__ Bpk,
      const float* __restrict__ pb1, const ushortT* __restrict__ pos_bf,
      ushortT* __restrict__ q_bf, ushortT* __restrict__ k_bf, ushortT* __restrict__ v_bf,
      ushortT* __restrict__ Pd_arr, ushortT* __restrict__ Ps_arr,
      const int* __restrict__ ei, const int* __restrict__ offp, int* __restrict__ curp,
      int* __restrict__ ss, int* __restrict__ sd, int N, int E, int nb_node)
{
    __shared__ ushortT xs[TILE][LDSW];   // 17.4 KB (ostage overlays this)
    __shared__ ushortT hs[TILE][LDSW];   // 17.4 KB
    const int b = blockIdx.x, tx = threadIdx.x;

    if (b >= nb_node) {
        // ---- scatter role ----
        const int e = (b - nb_node) * 256 + tx;
        if (e < E) {
            const int d = ei[E + e];
            const int p = offp[d] + atomicAdd(&curp[d], 1);
            ss[p] = ei[e];
            sd[p] = d;
        }
        return;
    }

    // ---- node role ----
    const int rg = tx >> 5;
    const int oc0 = (tx & 31) << 2;
    const int row0 = b * TILE;

    // stage x -> bf16 (wave-private rows)
#pragma unroll
    for (int j = 0; j < 8; ++j) {
        const int r = rg * 8 + j, n = row0 + r;
        float4 xv; xv.x = xv.y = xv.z = xv.w = 0.f;
        if (n < N) xv = *(const float4*)(x + (size_t)n * C + oc0);
        *(unsigned*)&xs[r][oc0]     = pk2(xv.x, xv.y);
        *(unsigned*)&xs[r][oc0 + 2] = pk2(xv.z, xv.w);
    }

    const int wv = tx >> 6, lane = tx & 63;
    const int quad = lane >> 4, m16 = lane & 15;
    const int row = lane >> 2, li = lane & 3;

    float binv[8];
#pragma unroll
    for (int nt = 0; nt < 8; ++nt) binv[nt] = b_in[nt * 16 + m16];

    const ushortT (*Ax)[LDSW] = (const ushortT (*)[LDSW])&xs[wv * 16];
    ushortT (*Ah)[LDSW] = (ushortT (*)[LDSW])&hs[wv * 16];

    floatx4 macc[8];
    // h = relu(x @ W_in + b_in)   (W_in in Bpack2 slot 3)
    wave_gemm(Ax, Bp2 + (size_t)3 * 16384, quad, m16, lane, macc);
    cstore_relu_r(Ah, macc, binv, quad, m16);

    __syncthreads();   // all xs reads done before ostage overlay is written

    ushortT (*OS)[LDSW] = (ushortT (*)[LDSW])&xs[wv * 16];   // ostage overlay
    ushortT* outs[3];
    outs[0] = q_bf; outs[1] = k_bf; outs[2] = v_bf;

    const int nrow = row0 + wv * 16 + row;

#pragma unroll 1
    for (int m = 0; m < 3; ++m) {
        wave_gemm((const ushortT (*)[LDSW])Ah, Bp2 + (size_t)m * 16384, quad, m16, lane, macc);
#pragma unroll
        for (int nt = 0; nt < 8; ++nt) {
#pragma unroll
            for (int r = 0; r < 4; r += 2) {
                const unsigned p = pk2(macc[nt][r], macc[nt][r + 1]);
                OS[quad * 4 + r][nt * 16 + m16]     = (ushortT)(p & 0xffffu);
                OS[quad * 4 + r + 1][nt * 16 + m16] = (ushortT)(p >> 16);
            }
        }
        if (nrow < N) {
#pragma unroll
            for (int i = 0; i < 4; ++i) {
                const ushort8 v8 = *(const ushort8*)&OS[row][i * 32 + li * 8];
                *(ushort8*)(outs[m] + (size_t)nrow * C + i * 32 + li * 8) = v8;
            }
        }
    }

    // ---- P = pos @ pw1 (hoisted pos_nn layer-1 GEMM) ----
    __syncthreads();   // hs reads (gemms) + OS reads (stores) all complete
    {
        const ushortT* srcp = pos_bf + (size_t)min(nrow, N - 1) * C;
#pragma unroll
        for (int i = 0; i < 4; ++i) {
            const ushort8 v8 = *(const ushort8*)(srcp + i * 32 + li * 8);
            *(ushort8*)&hs[wv * 16 + row][i * 32 + li * 8] = v8;
        }
    }
    __syncthreads();
    wave_gemm((const ushortT (*)[LDSW])Ah, Bpk /*slot 0 = pw1*/, quad, m16, lane, macc);

    float b1v[8];
#pragma unroll
    for (int nt = 0; nt < 8; ++nt) b1v[nt] = pb1[nt * 16 + m16];

    // pass 1: Pd = P + b1
#pragma unroll
    for (int nt = 0; nt < 8; ++nt) {
#pragma unroll
        for (int r = 0; r < 4; r += 2) {
            const unsigned p = pk2(macc[nt][r] + b1v[nt], macc[nt][r + 1] + b1v[nt]);
            OS[quad * 4 + r][nt * 16 + m16]     = (ushortT)(p & 0xffffu);
            OS[quad * 4 + r + 1][nt * 16 + m16] = (ushortT)(p >> 16);
        }
    }
    if (nrow < N) {
#pragma unroll
        for (int i = 0; i < 4; ++i) {
            const ushort8 v8 = *(const ushort8*)&OS[row][i * 32 + li * 8];
            *(ushort8*)(Pd_arr + (size_t)nrow * C + i * 32 + li * 8) = v8;
        }
    }
    __syncthreads();
    // pass 2: Ps = P
#pragma unroll
    for (int nt = 0; nt < 8; ++nt) {
#pragma unroll
        for (int r = 0; r < 4; r += 2) {
            const unsigned p = pk2(macc[nt][r], macc[nt][r + 1]);
            OS[quad * 4 + r][nt * 16 + m16]     = (ushortT)(p & 0xffffu);
            OS[quad * 4 + r + 1][nt * 16 + m16] = (ushortT)(p >> 16);
        }
    }
    if (nrow < N) {
#pragma unroll
        for (int i = 0; i < 4; ++i) {
            const ushort8 v8 = *(const ushort8*)&OS[row][i * 32 + li * 8];
            *(ushort8*)(Ps_arr + (size_t)nrow * C + i * 32 + li * 8) = v8;
        }
    }
}

// ============================================================================
// kernel 2 (MFMA): edges SORTED BY DST; segmented-scan epilogue.
// pos_nn layer 1 hoisted: A1 = relu(Pd[dst] - Ps[src]) built at staging,
// 3 wave_gemms/tile instead of 4.
// ============================================================================
__device__ __forceinline__ void gather4(const ushortT* __restrict__ base, int node, int li,
                                        ushort8 dst[4])
{
    const ushort8* p = (const ushort8*)(base + (size_t)node * C) + li;
    dst[0] = p[0]; dst[1] = p[4]; dst[2] = p[8]; dst[3] = p[12];   // chunk i at ushort8 index i*4+li
}

extern "C" __global__ void __launch_bounds__(THREADS)
edge_mfma(const ushortT* __restrict__ Pd_arr, const ushortT* __restrict__ Ps_arr,
          const int* __restrict__ ss, const int* __restrict__ sd,
          const ushortT* __restrict__ q_bf, const ushortT* __restrict__ k_bf,
          const ushortT* __restrict__ v_bf, const ushortT* __restrict__ Bpack,
          const float* __restrict__ pb2,
          const float* __restrict__ ab1, const float* __restrict__ ab2,
          float* __restrict__ z, float* __restrict__ aggU, int E)
{
    __shared__ ushortT Aslab[4][EPW][LDSW];   // 17.4 KB
    __shared__ ushortT Vslab[4][EPW][LDSW];   // 17.4 KB
    __shared__ int     Dslab[4][EPW];         // 256 B
    const int tid = threadIdx.x;
    const int wv = tid >> 6, lane = tid & 63;
    const int quad = lane >> 4, m16 = lane & 15;
    const int row = lane >> 2, li = lane & 3;      // line-coherent staging mapping
    ushortT (*A)[LDSW] = Aslab[wv];
    ushortT (*V)[LDSW] = Vslab[wv];

    float pb2v[8], ab1v[8], ab2v[8];
#pragma unroll
    for (int nt = 0; nt < 8; ++nt) {
        pb2v[nt] = pb2[nt * 16 + m16];
        ab1v[nt] = ab1[nt * 16 + m16]; ab2v[nt] = ab2[nt * 16 + m16];
    }

    const ushortT* B1 = Bpack + 16384;
    const ushortT* B2 = Bpack + 32768;
    const ushortT* B3 = Bpack + 49152;

    const int wave_base = (blockIdx.x * 4 + wv) * (GTILES * EPW);

    const int c2 = lane * 2;
    int   cur_dst = -1;
    float zs0 = 0.f, zs1 = 0.f, gs0 = 0.f, gs1 = 0.f;

    // ---- prologue: indices for tile 0 ----
    int es, ed, sdr[4];
    {
        const int eidx = min(wave_base + row, E - 1);
        es = ss[eidx]; ed = sd[eidx];
#pragma unroll
        for (int r = 0; r < 4; ++r)
            sdr[r] = sd[min(wave_base + quad * 4 + r, E - 1)];
    }

#pragma unroll 1
    for (int t = 0; t < GTILES; ++t) {
        const int e_base = wave_base + t * EPW;
        if (m16 == 0) {
#pragma unroll
            for (int r = 0; r < 4; ++r) Dslab[wv][quad * 4 + r] = sdr[r];
        }

        ushort8 Pd[4], Ps[4], Qv[4], Kv[4], Vv[4];
        gather4(Pd_arr, ed, li, Pd); gather4(Ps_arr, es, li, Ps);
        gather4(q_bf,  ed, li, Qv); gather4(k_bf,  es, li, Kv);
        gather4(v_bf,  es, li, Vv);

        // ---- A1 = relu(Pd[dst] - Ps[src])  (pos_nn layer 1, hoisted GEMM);
        //      stage v into Vslab ----
#pragma unroll
        for (int i = 0; i < 4; ++i) {
            const uintx4 pd = *(const uintx4*)&Pd[i];
            const uintx4 ps = *(const uintx4*)&Ps[i];
            uintx4 o;
#pragma unroll
            for (int w = 0; w < 4; ++w) {
                const float2 a = upk2(pd[w]), b = upk2(ps[w]);
                o[w] = pk2(fmaxf(a.x - b.x, 0.f), fmaxf(a.y - b.y, 0.f));
            }
            *(uintx4*)&A[row][i * 32 + li * 8] = o;
            *(ushort8*)&V[row][i * 32 + li * 8] = Vv[i];
        }

        floatx4 acc[8];

        // ---- pos_nn layer 2 -> delta (packed regs + slab) ----
        wave_gemm(A, B1, quad, m16, lane, acc);
        unsigned dlp[8][2];
#pragma unroll
        for (int nt = 0; nt < 8; ++nt) {
            const float b = pb2v[nt];
            const unsigned p0 = pk2(fmaxf(acc[nt][0] + b, 0.f), fmaxf(acc[nt][1] + b, 0.f));
            const unsigned p1 = pk2(fmaxf(acc[nt][2] + b, 0.f), fmaxf(acc[nt][3] + b, 0.f));
            dlp[nt][0] = p0; dlp[nt][1] = p1;
            A[quad * 4 + 0][nt * 16 + m16] = (ushortT)(p0 & 0xffffu);
            A[quad * 4 + 1][nt * 16 + m16] = (ushortT)(p0 >> 16);
            A[quad * 4 + 2][nt * 16 + m16] = (ushortT)(p1 & 0xffffu);
            A[quad * 4 + 3][nt * 16 + m16] = (ushortT)(p1 >> 16);
        }

        // ---- A2 = bf16( q[dst] - k[src] + delta ) ----
#pragma unroll
        for (int i = 0; i < 4; ++i) {
            const uintx4 dv = *(const uintx4*)&A[row][i * 32 + li * 8];
            const uintx4 qv = *(const uintx4*)&Qv[i];
            const uintx4 kv = *(const uintx4*)&Kv[i];
            uintx4 o;
#pragma unroll
            for (int w = 0; w < 4; ++w) {
                const float2 qq = upk2(qv[w]), kk = upk2(kv[w]), dd = upk2(dv[w]);
                o[w] = pk2(qq.x - kk.x + dd.x, qq.y - kk.y + dd.y);
            }
            *(uintx4*)&A[row][i * 32 + li * 8] = o;
        }

        // ---- prefetch next tile's indices (hides under attn MFMAs + scan) ----
        int nes = es, ned = ed, nsdr[4];
#pragma unroll
        for (int r = 0; r < 4; ++r) nsdr[r] = sdr[r];
        if (t + 1 < GTILES) {
            const int e2 = e_base + EPW;
            const int ei2 = min(e2 + row, E - 1);
            nes = ss[ei2]; ned = sd[ei2];
#pragma unroll
            for (int r = 0; r < 4; ++r)
                nsdr[r] = sd[min(e2 + quad * 4 + r, E - 1)];
        }

        // ---- attn_nn layer 1 ----
        wave_gemm(A, B2, quad, m16, lane, acc);
        cstore_relu_r(A, acc, ab1v, quad, m16);

        // ---- attn_nn layer 2 -> ea = exp(relu(alpha+b)) ----
        wave_gemm(A, B3, quad, m16, lane, acc);
#pragma unroll
        for (int nt = 0; nt < 8; ++nt) {
            const float b = ab2v[nt];
#pragma unroll
            for (int r = 0; r < 4; ++r)
                acc[nt][r] = __expf(fmaxf(acc[nt][r] + b, 0.f));  // alpha>=0, O(1): no max-shift
        }

        // ---- zero ea for out-of-range (clamped duplicate) edges ----
        if (e_base + EPW > E) {
#pragma unroll
            for (int r = 0; r < 4; ++r)
                if (e_base + quad * 4 + r >= E) {
#pragma unroll
                    for (int nt = 0; nt < 8; ++nt) acc[nt][r] = 0.f;
                }
        }

        // ---- transpose: A <- ea (bf16), V <- v+delta (bf16), edge-major ----
#pragma unroll
        for (int nt = 0; nt < 8; ++nt) {
#pragma unroll
            for (int r = 0; r < 4; ++r) {
                const float2 dpair = upk2(dlp[nt][r >> 1]);
                const float dlv = (r & 1) ? dpair.y : dpair.x;
                const int ridx = quad * 4 + r, cidx = nt * 16 + m16;
                const float vv = bf2f(V[ridx][cidx]);
                V[ridx][cidx] = f2bf(vv + dlv);
                A[ridx][cidx] = f2bf(acc[nt][r]);
            }
        }

        // ---- per-lane segmented scan over the 16 sorted edges ----
#pragma unroll 4
        for (int e = 0; e < EPW; ++e) {
            const int d = Dslab[wv][e];
            const float2 ea2 = upk2(*(const unsigned*)&A[e][c2]);
            const float2 vp2 = upk2(*(const unsigned*)&V[e][c2]);
            if (d != cur_dst) {
                if (cur_dst >= 0) {
                    float* zp = z    + (size_t)cur_dst * C + c2;
                    float* gp = aggU + (size_t)cur_dst * C + c2;
                    atomic_add_f32(zp,     zs0);
                    atomic_add_f32(zp + 1, zs1);
                    atomic_add_f32(gp,     gs0);
                    atomic_add_f32(gp + 1, gs1);
                }
                cur_dst = d;
                zs0 = ea2.x;           zs1 = ea2.y;
                gs0 = ea2.x * vp2.x;   gs1 = ea2.y * vp2.y;
            } else {
                zs0 += ea2.x;                   zs1 += ea2.y;
                gs0 = fmaf(ea2.x, vp2.x, gs0);  gs1 = fmaf(ea2.y, vp2.y, gs1);
            }
        }

        // rotate prefetched indices
        es = nes; ed = ned;
#pragma unroll
        for (int r = 0; r < 4; ++r) sdr[r] = nsdr[r];
    }

    // ---- final flush ----
    if (cur_dst >= 0) {
        float* zp = z    + (size_t)cur_dst * C + c2;
        float* gp = aggU + (size_t)cur_dst * C + c2;
        atomic_add_f32(zp,     zs0);
        atomic_add_f32(zp + 1, zs1);
        atomic_add_f32(gp,     gs0);
        atomic_add_f32(gp + 1, gs1);
    }
}

// ============================================================================
// kernel 3: out = relu( (aggU / (z+1e-16)) @ W_out + b_out )  [exact fp32]
// ============================================================================
extern "C" __global__ void __launch_bounds__(THREADS)
out_kernel(const float* __restrict__ aggU, const float* __restrict__ z,
           const float* __restrict__ W_out, const float* __restrict__ b_out,
           float* __restrict__ out, int N)
{
    __shared__ __align__(16) float s_in[TILE * C];
    const int tx = threadIdx.x;
    const int rg = tx >> 5;
    const int oc0 = (tx & 31) << 2;
    const int row0 = blockIdx.x * TILE;

#pragma unroll
    for (int j = 0; j < 8; ++j) {
        const int r = rg * 8 + j, n = row0 + r;
        float4 a; a.x = a.y = a.z = a.w = 0.f;
        if (n < N) {
            const float4 g  = *(const float4*)(aggU + (size_t)n * C + oc0);
            const float4 zz = *(const float4*)(z    + (size_t)n * C + oc0);
            a.x = g.x / (zz.x + 1e-16f);
            a.y = g.y / (zz.y + 1e-16f);
            a.z = g.z / (zz.z + 1e-16f);
            a.w = g.w / (zz.w + 1e-16f);
        }
        *(float4*)(s_in + r * C + oc0) = a;
    }

    float acc[8][4];
    zero_acc(acc);
    tile_gemm(s_in, W_out, acc, rg, oc0);
    bias_relu(acc, b_out, oc0);
#pragma unroll
    for (int j = 0; j < 8; ++j) {
        const int n = row0 + rg * 8 + j;
        if (n < N) { float4 t; t.x=acc[j][0]; t.y=acc[j][1]; t.z=acc[j][2]; t.w=acc[j][3];
                     *(float4*)(out + (size_t)n * C + oc0) = t; }
    }
}

// ---------------------------------------------------------------------------
extern "C" void kernel_launch(void* const* d_in, const int* in_sizes, int n_in,
                              void* d_out, int out_size, void* d_ws, size_t ws_size,
                              hipStream_t stream)
{
    const float* x     = (const float*)d_in[0];
    const float* pos   = (const float*)d_in[1];
    const int*   ei    = (const int*)  d_in[2];
    const float* W_in  = (const float*)d_in[3];
    const float* b_in  = (const float*)d_in[4];
    const float* W_lin = (const float*)d_in[5];
    const float* W_src = (const float*)d_in[6];
    const float* W_dst = (const float*)d_in[7];
    const float* pw1   = (const float*)d_in[8];
    const float* pb1   = (const float*)d_in[9];
    const float* pw2   = (const float*)d_in[10];
    const float* pb2   = (const float*)d_in[11];
    const float* aw1   = (const float*)d_in[12];
    const float* ab1   = (const float*)d_in[13];
    const float* aw2   = (const float*)d_in[14];
    const float* ab2   = (const float*)d_in[15];
    const float* W_out = (const float*)d_in[16];
    const float* b_out = (const float*)d_in[17];

    const int N = in_sizes[0] / C;
    const int E = in_sizes[2] / 2;
    const size_t NC = (size_t)N * C;

    // workspace layout — ALL gathered bf16 arrays 256-B aligned:
    //   z | aggU | q | k | v | Pd | Ps | pos_bf | Bpack | Bpack2 | deg | cur | off | ss | sd
    float*   z      = (float*)d_ws;                          // [N,C] fp32
    float*   aggU   = z + NC;                                // [N,C] fp32
    ushortT* q_bf   = (ushortT*)(aggU + NC);                 // [N,C] bf16 (256B-aligned)
    ushortT* k_bf   = q_bf + NC;
    ushortT* v_bf   = k_bf + NC;
    ushortT* Pd_arr = v_bf + NC;                             // [N,C] bf16: pos@pw1 + pb1
    ushortT* Ps_arr = Pd_arr + NC;                           // [N,C] bf16: pos@pw1
    ushortT* pos_bf = Ps_arr + NC;
    ushortT* Bpack  = pos_bf + NC;                           // 65536 bf16 (edge MLP weights)
    ushortT* Bpack2 = Bpack + 65536;                         // 65536 bf16 (Wdst,Wsrc,Wlin,Win)
    int*     deg    = (int*)(Bpack2 + 65536);                // [N]
    int*     curp   = deg + N;                               // [N]
    int*     offp   = curp + N;                              // [N]
    int*     ss     = offp + N;                              // [E] sorted src
    int*     sdst   = ss + E;                                // [E] sorted dst

    hipMemsetAsync(z, 0, 2 * NC * sizeof(float), stream);
    hipMemsetAsync(deg, 0, 2 * (size_t)N * sizeof(int), stream);  // deg + cur

    const int nb_cvt  = (N * 32 + 255) / 256;
    const int nb_hist = (E + 255) / 256;
    prep1<<<512 + nb_cvt + nb_hist, 256, 0, stream>>>(pw1, pw2, aw1, aw2,
                                                      W_dst, W_src, W_lin, W_in,
                                                      pos, pos_bf, ei, deg,
                                                      Bpack, Bpack2, N, E);

    k_scan<<<1, 1024, 0, stream>>>(deg, offp, N);

    const int nb = (N + TILE - 1) / TILE;
    prep2<<<nb + nb_hist, 256, 0, stream>>>(x, b_in, Bpack2, Bpack, pb1, pos_bf,
                                            q_bf, k_bf, v_bf, Pd_arr, Ps_arr,
                                            ei, offp, curp, ss, sdst, N, E, nb);

    const int edges_per_block = 4 * GTILES * EPW;            // 512
    const int eb = (E + edges_per_block - 1) / edges_per_block;
    edge_mfma<<<eb, THREADS, 0, stream>>>(Pd_arr, Ps_arr, ss, sdst, q_bf, k_bf, v_bf, Bpack,
                                          pb2, ab1, ab2, z, aggU, E);
    out_kernel<<<nb, THREADS, 0, stream>>>(aggU, z, W_out, b_out, (float*)d_out, N);
}

// Round 7
// 603.382 us; speedup vs baseline: 1.6703x; 1.0293x over previous
//
#include <hip/hip_runtime.h>
#include <hip/hip_bf16.h>

#define C 128
#define THREADS 256      // 4 waves/block
#define TILE 64          // node rows per block
#define EPW 16           // edges per wave-tile
#define GTILES 8         // tiles per wave, steady-state loop (NOT unrolled)
#define LDSPAD 8
#define LDSW (C + LDSPAD)    // 136 ushorts/row
#define LOG2E 1.44269504088896340736f

typedef unsigned short ushortT;
typedef __attribute__((ext_vector_type(8))) short short8;
typedef __attribute__((ext_vector_type(8))) ushortT ushort8;
typedef __attribute__((ext_vector_type(4))) float floatx4;
typedef __attribute__((ext_vector_type(4))) unsigned uintx4;

// ---- bf16 helpers ----
__device__ __forceinline__ unsigned pk2(float a, float b) {     // float2 -> 2x bf16 (RNE, 1 inst)
    float2 f; f.x = a; f.y = b;
    union { unsigned u; __hip_bfloat162 h; } cv; cv.h = __float22bfloat162_rn(f);
    return cv.u;
}
__device__ __forceinline__ ushortT f2bf(float x) {              // HW RNE via cvt_pk
    return (ushortT)(pk2(x, x) & 0xffffu);
}
__device__ __forceinline__ float bf2f(ushortT h) {
    union { unsigned u; float f; } v; v.u = ((unsigned)h) << 16;
    return v.f;
}
__device__ __forceinline__ float2 upk2(unsigned u) {            // 2x bf16 -> float2
    union { unsigned u; __hip_bfloat162 h; } cv; cv.u = u;
    return __bfloat1622float2(cv.h);
}
__device__ __forceinline__ float exp2_hw(float x) {             // 2^x, single v_exp_f32
    float r; asm("v_exp_f32 %0, %1" : "=v"(r) : "v"(x)); return r;
}
__device__ __forceinline__ void atomic_add_f32(float* p, float v) {
    __hip_atomic_fetch_add(p, v, __ATOMIC_RELAXED, __HIP_MEMORY_SCOPE_AGENT);
}

// ============================================================================
// MFMA helpers (zero-init acc, bias in epilogue — round-2-proven codegen)
// ============================================================================
__device__ __forceinline__ void wave_gemm(const ushortT (*A)[LDSW],
                                          const ushortT* __restrict__ Bp,
                                          int quad, int m16, int lane,
                                          floatx4 acc[8])
{
#pragma unroll
    for (int nt = 0; nt < 8; ++nt) { acc[nt][0]=0.f; acc[nt][1]=0.f; acc[nt][2]=0.f; acc[nt][3]=0.f; }
#pragma unroll 1
    for (int ks = 0; ks < 4; ++ks) {
        const short8 af = *(const short8*)&A[m16][ks * 32 + quad * 8];
        const ushortT* bpk = Bp + (size_t)ks * 4096 + (size_t)lane * 8;
#pragma unroll
        for (int nt = 0; nt < 8; ++nt) {
            const short8 bf = *(const short8*)(bpk + nt * 512);
            acc[nt] = __builtin_amdgcn_mfma_f32_16x16x32_bf16(af, bf, acc[nt], 0, 0, 0);
        }
    }
}

__device__ __forceinline__ void cstore_relu_r(ushortT (*A)[LDSW], floatx4 acc[8],
                                              const float bias[8], int quad, int m16)
{
#pragma unroll
    for (int nt = 0; nt < 8; ++nt) {
        const float b = bias[nt];
#pragma unroll
        for (int r = 0; r < 4; r += 2) {
            const unsigned p = pk2(fmaxf(acc[nt][r] + b, 0.f), fmaxf(acc[nt][r + 1] + b, 0.f));
            A[quad * 4 + r][nt * 16 + m16]     = (ushortT)(p & 0xffffu);
            A[quad * 4 + r + 1][nt * 16 + m16] = (ushortT)(p >> 16);
        }
    }
}

// pack one matrix entry into MFMA B-fragment order
__device__ __forceinline__ ushortT pack_one(const float* __restrict__ W, int u) {
    const int j = u & 7, lane = (u >> 3) & 63, f = u >> 9;  // u in [0,16384)
    const int nt = f & 7, ks = f >> 3;
    const int n = nt * 16 + (lane & 15);
    const int k = ks * 32 + (lane >> 4) * 8 + j;
    return f2bf(W[k * C + n]);
}

// ============================================================================
// prep1 (fused): pack Bpack (edge MLP, aw2 pre-scaled by log2e),
// pack Bpack2 (Wdst,Wsrc,Wlin,Win), pack BpackO (W_out),
// cvt pos->bf16 (float4 vectorized), hist of dst degrees. Block-role ranges.
// ============================================================================
extern "C" __global__ void __launch_bounds__(256)
prep1(const float* __restrict__ pw1, const float* __restrict__ pw2,
      const float* __restrict__ aw1, const float* __restrict__ aw2,
      const float* __restrict__ Wd,  const float* __restrict__ Wsrc,
      const float* __restrict__ Wl,  const float* __restrict__ Win,
      const float* __restrict__ Wout,
      const float* __restrict__ pos, ushortT* __restrict__ pos_bf,
      const int* __restrict__ ei, int* __restrict__ deg,
      ushortT* __restrict__ Bpack, ushortT* __restrict__ Bpack2,
      ushortT* __restrict__ BpackO, int N, int E)
{
    const int nb_cvt = (N * 32 + 255) / 256;
    const int b = blockIdx.x, tid = threadIdx.x;
    if (b < 256) {
        const int t = b * 256 + tid;
        const int s = t >> 14;
        const float* W = (s == 0) ? pw1 : (s == 1) ? pw2 : (s == 2) ? aw1 : aw2;
        const int u = t & 16383;
        const int j = u & 7, lane = (u >> 3) & 63, f = u >> 9;
        const int nt = f & 7, ks = f >> 3;
        const int n = nt * 16 + (lane & 15);
        const int k = ks * 32 + (lane >> 4) * 8 + j;
        float v = W[k * C + n];
        if (s == 3) v *= LOG2E;          // exp2 fold: attn layer-2 in log2 domain
        Bpack[t] = f2bf(v);
    } else if (b < 512) {
        const int t = (b - 256) * 256 + tid;
        const int s = t >> 14;
        const float* W = (s == 0) ? Wd : (s == 1) ? Wsrc : (s == 2) ? Wl : Win;
        Bpack2[t] = pack_one(W, t & 16383);
    } else if (b < 576) {
        const int t = (b - 512) * 256 + tid;     // [0, 16384)
        BpackO[t] = pack_one(Wout, t);
    } else if (b < 576 + nb_cvt) {
        const int i = (b - 576) * 256 + tid;
        if (i < N * 32) {
            const float4 v = ((const float4*)pos)[i];
            uint2 o; o.x = pk2(v.x, v.y); o.y = pk2(v.z, v.w);
            ((uint2*)pos_bf)[i] = o;
        }
    } else {
        const int e = (b - 576 - nb_cvt) * 256 + tid;
        if (e < E) atomicAdd(&deg[ei[E + e]], 1);
    }
}

extern "C" __global__ void __launch_bounds__(1024)
k_scan(const int* __restrict__ deg, int* __restrict__ off, int n)
{
    __shared__ int part[1024];
    const int t = threadIdx.x;
    const int chunk = (((n + 1023) / 1024) + 3) & ~3;      // multiple of 4
    const int lo = t * chunk, hi = min(lo + chunk, n);      // n%4==0 -> hi-lo %4==0
    int s = 0;
    for (int i = lo; i < hi; i += 4) {
        const int4 d4 = *(const int4*)(deg + i);
        s += d4.x + d4.y + d4.z + d4.w;
    }
    part[t] = s;
    __syncthreads();
    for (int d = 1; d < 1024; d <<= 1) {
        int v = (t >= d) ? part[t - d] : 0;
        __syncthreads();
        part[t] += v;
        __syncthreads();
    }
    int run = (t == 0) ? 0 : part[t - 1];
    for (int i = lo; i < hi; i += 4) {
        const int4 d4 = *(const int4*)(deg + i);
        int4 o;
        o.x = run;
        o.y = o.x + d4.x;
        o.z = o.y + d4.y;
        o.w = o.z + d4.z;
        *(int4*)(off + i) = o;
        run = o.w + d4.w;
    }
}

// ============================================================================
// prep2 (fused): node role (all-MFMA qkv + P = pos@pw1 hoist) + scatter role.
// ============================================================================
extern "C" __global__ void __launch_bounds__(256)
prep2(const float* __restrict__ x, const float* __restrict__ b_in,
      const ushortT* __restrict__ Bp2, const ushortT* __restrict__ Bpk,
      const float* __restrict__ pb1, const ushortT* __restrict__ pos_bf,
      ushortT* __restrict__ q_bf, ushortT* __restrict__ k_bf, ushortT* __restrict__ v_bf,
      ushortT* __restrict__ Pd_arr, ushortT* __restrict__ Ps_arr,
      const int* __restrict__ ei, const int* __restrict__ offp, int* __restrict__ curp,
      int* __restrict__ ss, int* __restrict__ sd, int N, int E, int nb_node)
{
    __shared__ ushortT xs[TILE][LDSW];   // 17.4 KB (ostage overlays this)
    __shared__ ushortT hs[TILE][LDSW];   // 17.4 KB
    const int b = blockIdx.x, tx = threadIdx.x;

    if (b >= nb_node) {
        // ---- scatter role ----
        const int e = (b - nb_node) * 256 + tx;
        if (e < E) {
            const int d = ei[E + e];
            const int p = offp[d] + atomicAdd(&curp[d], 1);
            ss[p] = ei[e];
            sd[p] = d;
        }
        return;
    }

    // ---- node role ----
    const int rg = tx >> 5;
    const int oc0 = (tx & 31) << 2;
    const int row0 = b * TILE;

    // stage x -> bf16 (wave-private rows)
#pragma unroll
    for (int j = 0; j < 8; ++j) {
        const int r = rg * 8 + j, n = row0 + r;
        float4 xv; xv.x = xv.y = xv.z = xv.w = 0.f;
        if (n < N) xv = *(const float4*)(x + (size_t)n * C + oc0);
        *(unsigned*)&xs[r][oc0]     = pk2(xv.x, xv.y);
        *(unsigned*)&xs[r][oc0 + 2] = pk2(xv.z, xv.w);
    }

    const int wv = tx >> 6, lane = tx & 63;
    const int quad = lane >> 4, m16 = lane & 15;
    const int row = lane >> 2, li = lane & 3;

    float binv[8];
#pragma unroll
    for (int nt = 0; nt < 8; ++nt) binv[nt] = b_in[nt * 16 + m16];

    const ushortT (*Ax)[LDSW] = (const ushortT (*)[LDSW])&xs[wv * 16];
    ushortT (*Ah)[LDSW] = (ushortT (*)[LDSW])&hs[wv * 16];

    floatx4 macc[8];
    // h = relu(x @ W_in + b_in)   (W_in in Bpack2 slot 3)
    wave_gemm(Ax, Bp2 + (size_t)3 * 16384, quad, m16, lane, macc);
    cstore_relu_r(Ah, macc, binv, quad, m16);

    __syncthreads();   // all xs reads done before ostage overlay is written

    ushortT (*OS)[LDSW] = (ushortT (*)[LDSW])&xs[wv * 16];   // ostage overlay
    ushortT* outs[3];
    outs[0] = q_bf; outs[1] = k_bf; outs[2] = v_bf;

    const int nrow = row0 + wv * 16 + row;

#pragma unroll 1
    for (int m = 0; m < 3; ++m) {
        wave_gemm((const ushortT (*)[LDSW])Ah, Bp2 + (size_t)m * 16384, quad, m16, lane, macc);
#pragma unroll
        for (int nt = 0; nt < 8; ++nt) {
#pragma unroll
            for (int r = 0; r < 4; r += 2) {
                const unsigned p = pk2(macc[nt][r], macc[nt][r + 1]);
                OS[quad * 4 + r][nt * 16 + m16]     = (ushortT)(p & 0xffffu);
                OS[quad * 4 + r + 1][nt * 16 + m16] = (ushortT)(p >> 16);
            }
        }
        if (nrow < N) {
#pragma unroll
            for (int i = 0; i < 4; ++i) {
                const ushort8 v8 = *(const ushort8*)&OS[row][i * 32 + li * 8];
                *(ushort8*)(outs[m] + (size_t)nrow * C + i * 32 + li * 8) = v8;
            }
        }
    }

    // ---- P = pos @ pw1 (hoisted pos_nn layer-1 GEMM) ----
    __syncthreads();   // hs reads (gemms) + OS reads (stores) all complete
    {
        const ushortT* srcp = pos_bf + (size_t)min(nrow, N - 1) * C;
#pragma unroll
        for (int i = 0; i < 4; ++i) {
            const ushort8 v8 = *(const ushort8*)(srcp + i * 32 + li * 8);
            *(ushort8*)&hs[wv * 16 + row][i * 32 + li * 8] = v8;
        }
    }
    __syncthreads();
    wave_gemm((const ushortT (*)[LDSW])Ah, Bpk /*slot 0 = pw1*/, quad, m16, lane, macc);

    float b1v[8];
#pragma unroll
    for (int nt = 0; nt < 8; ++nt) b1v[nt] = pb1[nt * 16 + m16];

    // pass 1: Pd = P + b1
#pragma unroll
    for (int nt = 0; nt < 8; ++nt) {
#pragma unroll
        for (int r = 0; r < 4; r += 2) {
            const unsigned p = pk2(macc[nt][r] + b1v[nt], macc[nt][r + 1] + b1v[nt]);
            OS[quad * 4 + r][nt * 16 + m16]     = (ushortT)(p & 0xffffu);
            OS[quad * 4 + r + 1][nt * 16 + m16] = (ushortT)(p >> 16);
        }
    }
    if (nrow < N) {
#pragma unroll
        for (int i = 0; i < 4; ++i) {
            const ushort8 v8 = *(const ushort8*)&OS[row][i * 32 + li * 8];
            *(ushort8*)(Pd_arr + (size_t)nrow * C + i * 32 + li * 8) = v8;
        }
    }
    __syncthreads();
    // pass 2: Ps = P
#pragma unroll
    for (int nt = 0; nt < 8; ++nt) {
#pragma unroll
        for (int r = 0; r < 4; r += 2) {
            const unsigned p = pk2(macc[nt][r], macc[nt][r + 1]);
            OS[quad * 4 + r][nt * 16 + m16]     = (ushortT)(p & 0xffffu);
            OS[quad * 4 + r + 1][nt * 16 + m16] = (ushortT)(p >> 16);
        }
    }
    if (nrow < N) {
#pragma unroll
        for (int i = 0; i < 4; ++i) {
            const ushort8 v8 = *(const ushort8*)&OS[row][i * 32 + li * 8];
            *(ushort8*)(Ps_arr + (size_t)nrow * C + i * 32 + li * 8) = v8;
        }
    }
}

// ============================================================================
// kernel 2 (MFMA): edges SORTED BY DST; segmented-scan epilogue.
// pos_nn layer 1 hoisted; attn layer 2 in log2 domain (single v_exp_f32).
// ============================================================================
__device__ __forceinline__ void gather4(const ushortT* __restrict__ base, int node, int li,
                                        ushort8 dst[4])
{
    const ushort8* p = (const ushort8*)(base + (size_t)node * C) + li;
    dst[0] = p[0]; dst[1] = p[4]; dst[2] = p[8]; dst[3] = p[12];   // chunk i at ushort8 index i*4+li
}

extern "C" __global__ void __launch_bounds__(THREADS)
edge_mfma(const ushortT* __restrict__ Pd_arr, const ushortT* __restrict__ Ps_arr,
          const int* __restrict__ ss, const int* __restrict__ sd,
          const ushortT* __restrict__ q_bf, const ushortT* __restrict__ k_bf,
          const ushortT* __restrict__ v_bf, const ushortT* __restrict__ Bpack,
          const float* __restrict__ pb2,
          const float* __restrict__ ab1, const float* __restrict__ ab2,
          float* __restrict__ z, float* __restrict__ aggU, int E)
{
    __shared__ ushortT Aslab[4][EPW][LDSW];   // 17.4 KB
    __shared__ ushortT Vslab[4][EPW][LDSW];   // 17.4 KB
    __shared__ int     Dslab[4][EPW];         // 256 B
    const int tid = threadIdx.x;
    const int wv = tid >> 6, lane = tid & 63;
    const int quad = lane >> 4, m16 = lane & 15;
    const int row = lane >> 2, li = lane & 3;      // line-coherent staging mapping
    ushortT (*A)[LDSW] = Aslab[wv];
    ushortT (*V)[LDSW] = Vslab[wv];

    float pb2v[8], ab1v[8], ab2v[8];
#pragma unroll
    for (int nt = 0; nt < 8; ++nt) {
        pb2v[nt] = pb2[nt * 16 + m16];
        ab1v[nt] = ab1[nt * 16 + m16];
        ab2v[nt] = ab2[nt * 16 + m16] * LOG2E;     // log2-domain bias
    }

    const ushortT* B1 = Bpack + 16384;
    const ushortT* B2 = Bpack + 32768;
    const ushortT* B3 = Bpack + 49152;

    const int wave_base = (blockIdx.x * 4 + wv) * (GTILES * EPW);

    const int c2 = lane * 2;
    int   cur_dst = -1;
    float zs0 = 0.f, zs1 = 0.f, gs0 = 0.f, gs1 = 0.f;

    // ---- prologue: indices for tile 0 ----
    int es, ed, sdr[4];
    {
        const int eidx = min(wave_base + row, E - 1);
        es = ss[eidx]; ed = sd[eidx];
#pragma unroll
        for (int r = 0; r < 4; ++r)
            sdr[r] = sd[min(wave_base + quad * 4 + r, E - 1)];
    }

#pragma unroll 1
    for (int t = 0; t < GTILES; ++t) {
        const int e_base = wave_base + t * EPW;
        if (m16 == 0) {
#pragma unroll
            for (int r = 0; r < 4; ++r) Dslab[wv][quad * 4 + r] = sdr[r];
        }

        ushort8 Pd[4], Ps[4], Qv[4], Kv[4], Vv[4];
        gather4(Pd_arr, ed, li, Pd); gather4(Ps_arr, es, li, Ps);
        gather4(q_bf,  ed, li, Qv); gather4(k_bf,  es, li, Kv);
        gather4(v_bf,  es, li, Vv);

        // ---- A1 = relu(Pd[dst] - Ps[src])  (pos_nn layer 1, hoisted GEMM);
        //      stage v into Vslab ----
#pragma unroll
        for (int i = 0; i < 4; ++i) {
            const uintx4 pd = *(const uintx4*)&Pd[i];
            const uintx4 ps = *(const uintx4*)&Ps[i];
            uintx4 o;
#pragma unroll
            for (int w = 0; w < 4; ++w) {
                const float2 a = upk2(pd[w]), b = upk2(ps[w]);
                o[w] = pk2(fmaxf(a.x - b.x, 0.f), fmaxf(a.y - b.y, 0.f));
            }
            *(uintx4*)&A[row][i * 32 + li * 8] = o;
            *(ushort8*)&V[row][i * 32 + li * 8] = Vv[i];
        }

        floatx4 acc[8];

        // ---- pos_nn layer 2 -> delta (packed regs + slab) ----
        wave_gemm(A, B1, quad, m16, lane, acc);
        unsigned dlp[8][2];
#pragma unroll
        for (int nt = 0; nt < 8; ++nt) {
            const float b = pb2v[nt];
            const unsigned p0 = pk2(fmaxf(acc[nt][0] + b, 0.f), fmaxf(acc[nt][1] + b, 0.f));
            const unsigned p1 = pk2(fmaxf(acc[nt][2] + b, 0.f), fmaxf(acc[nt][3] + b, 0.f));
            dlp[nt][0] = p0; dlp[nt][1] = p1;
            A[quad * 4 + 0][nt * 16 + m16] = (ushortT)(p0 & 0xffffu);
            A[quad * 4 + 1][nt * 16 + m16] = (ushortT)(p0 >> 16);
            A[quad * 4 + 2][nt * 16 + m16] = (ushortT)(p1 & 0xffffu);
            A[quad * 4 + 3][nt * 16 + m16] = (ushortT)(p1 >> 16);
        }

        // ---- A2 = bf16( q[dst] - k[src] + delta ) ----
#pragma unroll
        for (int i = 0; i < 4; ++i) {
            const uintx4 dv = *(const uintx4*)&A[row][i * 32 + li * 8];
            const uintx4 qv = *(const uintx4*)&Qv[i];
            const uintx4 kv = *(const uintx4*)&Kv[i];
            uintx4 o;
#pragma unroll
            for (int w = 0; w < 4; ++w) {
                const float2 qq = upk2(qv[w]), kk = upk2(kv[w]), dd = upk2(dv[w]);
                o[w] = pk2(qq.x - kk.x + dd.x, qq.y - kk.y + dd.y);
            }
            *(uintx4*)&A[row][i * 32 + li * 8] = o;
        }

        // ---- prefetch next tile's indices (hides under attn MFMAs + scan) ----
        int nes = es, ned = ed, nsdr[4];
#pragma unroll
        for (int r = 0; r < 4; ++r) nsdr[r] = sdr[r];
        if (t + 1 < GTILES) {
            const int e2 = e_base + EPW;
            const int ei2 = min(e2 + row, E - 1);
            nes = ss[ei2]; ned = sd[ei2];
#pragma unroll
            for (int r = 0; r < 4; ++r)
                nsdr[r] = sd[min(e2 + quad * 4 + r, E - 1)];
        }

        // ---- attn_nn layer 1 ----
        wave_gemm(A, B2, quad, m16, lane, acc);
        cstore_relu_r(A, acc, ab1v, quad, m16);

        // ---- attn_nn layer 2 (log2 domain) -> ea = exp2(relu(alpha'+b')) ----
        wave_gemm(A, B3, quad, m16, lane, acc);
#pragma unroll
        for (int nt = 0; nt < 8; ++nt) {
            const float b = ab2v[nt];
#pragma unroll
            for (int r = 0; r < 4; ++r)
                acc[nt][r] = exp2_hw(fmaxf(acc[nt][r] + b, 0.f));  // == exp(relu(alpha))
        }

        // ---- zero ea for out-of-range (clamped duplicate) edges ----
        if (e_base + EPW > E) {
#pragma unroll
            for (int r = 0; r < 4; ++r)
                if (e_base + quad * 4 + r >= E) {
#pragma unroll
                    for (int nt = 0; nt < 8; ++nt) acc[nt][r] = 0.f;
                }
        }

        // ---- transpose: A <- ea (bf16), V <- v+delta (bf16), edge-major ----
#pragma unroll
        for (int nt = 0; nt < 8; ++nt) {
#pragma unroll
            for (int r = 0; r < 4; ++r) {
                const float2 dpair = upk2(dlp[nt][r >> 1]);
                const float dlv = (r & 1) ? dpair.y : dpair.x;
                const int ridx = quad * 4 + r, cidx = nt * 16 + m16;
                const float vv = bf2f(V[ridx][cidx]);
                V[ridx][cidx] = f2bf(vv + dlv);
                A[ridx][cidx] = f2bf(acc[nt][r]);
            }
        }

        // ---- per-lane segmented scan over the 16 sorted edges ----
#pragma unroll 4
        for (int e = 0; e < EPW; ++e) {
            const int d = Dslab[wv][e];
            const float2 ea2 = upk2(*(const unsigned*)&A[e][c2]);
            const float2 vp2 = upk2(*(const unsigned*)&V[e][c2]);
            if (d != cur_dst) {
                if (cur_dst >= 0) {
                    float* zp = z    + (size_t)cur_dst * C + c2;
                    float* gp = aggU + (size_t)cur_dst * C + c2;
                    atomic_add_f32(zp,     zs0);
                    atomic_add_f32(zp + 1, zs1);
                    atomic_add_f32(gp,     gs0);
                    atomic_add_f32(gp + 1, gs1);
                }
                cur_dst = d;
                zs0 = ea2.x;           zs1 = ea2.y;
                gs0 = ea2.x * vp2.x;   gs1 = ea2.y * vp2.y;
            } else {
                zs0 += ea2.x;                   zs1 += ea2.y;
                gs0 = fmaf(ea2.x, vp2.x, gs0);  gs1 = fmaf(ea2.y, vp2.y, gs1);
            }
        }

        // rotate prefetched indices
        es = nes; ed = ned;
#pragma unroll
        for (int r = 0; r < 4; ++r) sdr[r] = nsdr[r];
    }

    // ---- final flush ----
    if (cur_dst >= 0) {
        float* zp = z    + (size_t)cur_dst * C + c2;
        float* gp = aggU + (size_t)cur_dst * C + c2;
        atomic_add_f32(zp,     zs0);
        atomic_add_f32(zp + 1, zs1);
        atomic_add_f32(gp,     gs0);
        atomic_add_f32(gp + 1, gs1);
    }
}

// ============================================================================
// kernel 3 (MFMA): out = relu( bf16(aggU/(z+1e-16)) @ W_out + b_out )
// Division exact fp32; GEMM bf16 MFMA; bias+relu fp32; direct stores.
// ============================================================================
extern "C" __global__ void __launch_bounds__(THREADS)
out_kernel(const float* __restrict__ aggU, const float* __restrict__ z,
           const ushortT* __restrict__ BpO, const float* __restrict__ b_out,
           float* __restrict__ out, int N)
{
    __shared__ ushortT us[TILE][LDSW];   // 17.4 KB
    const int tx = threadIdx.x;
    const int rg = tx >> 5;
    const int oc0 = (tx & 31) << 2;
    const int row0 = blockIdx.x * TILE;

#pragma unroll
    for (int j = 0; j < 8; ++j) {
        const int r = rg * 8 + j, n = row0 + r;
        float4 a; a.x = a.y = a.z = a.w = 0.f;
        if (n < N) {
            const float4 g  = *(const float4*)(aggU + (size_t)n * C + oc0);
            const float4 zz = *(const float4*)(z    + (size_t)n * C + oc0);
            a.x = g.x / (zz.x + 1e-16f);
            a.y = g.y / (zz.y + 1e-16f);
            a.z = g.z / (zz.z + 1e-16f);
            a.w = g.w / (zz.w + 1e-16f);
        }
        *(unsigned*)&us[r][oc0]     = pk2(a.x, a.y);
        *(unsigned*)&us[r][oc0 + 2] = pk2(a.z, a.w);
    }
    // rows rg*8+j are wave-private (rg in {2wv,2wv+1}) -> no barrier

    const int wv = tx >> 6, lane = tx & 63;
    const int quad = lane >> 4, m16 = lane & 15;

    floatx4 macc[8];
    wave_gemm((const ushortT (*)[LDSW])&us[wv * 16], BpO, quad, m16, lane, macc);

    float bo[8];
#pragma unroll
    for (int nt = 0; nt < 8; ++nt) bo[nt] = b_out[nt * 16 + m16];

#pragma unroll
    for (int r = 0; r < 4; ++r) {
        const int n = row0 + wv * 16 + quad * 4 + r;
        if (n < N) {
            float* op = out + (size_t)n * C + m16;
#pragma unroll
            for (int nt = 0; nt < 8; ++nt)
                op[nt * 16] = fmaxf(macc[nt][r] + bo[nt], 0.f);
        }
    }
}

// ---------------------------------------------------------------------------
extern "C" void kernel_launch(void* const* d_in, const int* in_sizes, int n_in,
                              void* d_out, int out_size, void* d_ws, size_t ws_size,
                              hipStream_t stream)
{
    const float* x     = (const float*)d_in[0];
    const float* pos   = (const float*)d_in[1];
    const int*   ei    = (const int*)  d_in[2];
    const float* W_in  = (const float*)d_in[3];
    const float* b_in  = (const float*)d_in[4];
    const float* W_lin = (const float*)d_in[5];
    const float* W_src = (const float*)d_in[6];
    const float* W_dst = (const float*)d_in[7];
    const float* pw1   = (const float*)d_in[8];
    const float* pb1   = (const float*)d_in[9];
    const float* pw2   = (const float*)d_in[10];
    const float* pb2   = (const float*)d_in[11];
    const float* aw1   = (const float*)d_in[12];
    const float* ab1   = (const float*)d_in[13];
    const float* aw2   = (const float*)d_in[14];
    const float* ab2   = (const float*)d_in[15];
    const float* W_out = (const float*)d_in[16];
    const float* b_out = (const float*)d_in[17];

    const int N = in_sizes[0] / C;
    const int E = in_sizes[2] / 2;
    const size_t NC = (size_t)N * C;

    // workspace layout — ALL gathered bf16 arrays 256-B aligned:
    //   z | aggU | q | k | v | Pd | Ps | pos_bf | Bpack | Bpack2 | BpackO |
    //   deg | cur | off | ss | sd
    float*   z      = (float*)d_ws;                          // [N,C] fp32
    float*   aggU   = z + NC;                                // [N,C] fp32
    ushortT* q_bf   = (ushortT*)(aggU + NC);                 // [N,C] bf16 (256B-aligned)
    ushortT* k_bf   = q_bf + NC;
    ushortT* v_bf   = k_bf + NC;
    ushortT* Pd_arr = v_bf + NC;                             // [N,C] bf16: pos@pw1 + pb1
    ushortT* Ps_arr = Pd_arr + NC;                           // [N,C] bf16: pos@pw1
    ushortT* pos_bf = Ps_arr + NC;
    ushortT* Bpack  = pos_bf + NC;                           // 65536 bf16 (edge MLP weights)
    ushortT* Bpack2 = Bpack + 65536;                         // 65536 bf16 (Wdst,Wsrc,Wlin,Win)
    ushortT* BpackO = Bpack2 + 65536;                        // 16384 bf16 (W_out)
    int*     deg    = (int*)(BpackO + 16384);                // [N]
    int*     curp   = deg + N;                               // [N]
    int*     offp   = curp + N;                              // [N]
    int*     ss     = offp + N;                              // [E] sorted src
    int*     sdst   = ss + E;                                // [E] sorted dst

    hipMemsetAsync(z, 0, 2 * NC * sizeof(float), stream);
    hipMemsetAsync(deg, 0, 2 * (size_t)N * sizeof(int), stream);  // deg + cur

    const int nb_cvt  = (N * 32 + 255) / 256;
    const int nb_hist = (E + 255) / 256;
    prep1<<<576 + nb_cvt + nb_hist, 256, 0, stream>>>(pw1, pw2, aw1, aw2,
                                                      W_dst, W_src, W_lin, W_in, W_out,
                                                      pos, pos_bf, ei, deg,
                                                      Bpack, Bpack2, BpackO, N, E);

    k_scan<<<1, 1024, 0, stream>>>(deg, offp, N);

    const int nb = (N + TILE - 1) / TILE;
    prep2<<<nb + nb_hist, 256, 0, stream>>>(x, b_in, Bpack2, Bpack, pb1, pos_bf,
                                            q_bf, k_bf, v_bf, Pd_arr, Ps_arr,
                                            ei, offp, curp, ss, sdst, N, E, nb);

    const int edges_per_block = 4 * GTILES * EPW;            // 512
    const int eb = (E + edges_per_block - 1) / edges_per_block;
    edge_mfma<<<eb, THREADS, 0, stream>>>(Pd_arr, Ps_arr, ss, sdst, q_bf, k_bf, v_bf, Bpack,
                                          pb2, ab1, ab2, z, aggU, E);
    out_kernel<<<nb, THREADS, 0, stream>>>(aggU, z, BpackO, b_out, (float*)d_out, N);
}

// Round 10
// 588.506 us; speedup vs baseline: 1.7126x; 1.0253x over previous
//
#include <hip/hip_runtime.h>
#include <hip/hip_bf16.h>

#define C 128
#define THREADS 256      // node/prep kernels: 4 waves/block
#define ETHREADS 128     // edge kernel: 2 waves/block (LDS 17.5 KB -> high residency)
#define EWPB 2           // edge waves per block
#define TILE 64          // node rows per block
#define EPW 16           // edges per wave-tile
#define GTILES 8         // tiles per wave, steady-state loop (NOT unrolled)
#define LDSPAD 8
#define LDSW (C + LDSPAD)    // 136 ushorts/row
#define LOG2E 1.44269504088896340736f

typedef unsigned short ushortT;
typedef __attribute__((ext_vector_type(8))) short short8;
typedef __attribute__((ext_vector_type(8))) ushortT ushort8;
typedef __attribute__((ext_vector_type(4))) float floatx4;
typedef __attribute__((ext_vector_type(4))) unsigned uintx4;

// ---- bf16 helpers ----
__device__ __forceinline__ unsigned pk2(float a, float b) {     // float2 -> 2x bf16 (RNE, 1 inst)
    float2 f; f.x = a; f.y = b;
    union { unsigned u; __hip_bfloat162 h; } cv; cv.h = __float22bfloat162_rn(f);
    return cv.u;
}
__device__ __forceinline__ ushortT f2bf(float x) {              // HW RNE via cvt_pk
    return (ushortT)(pk2(x, x) & 0xffffu);
}
__device__ __forceinline__ float bf2f(ushortT h) {
    union { unsigned u; float f; } v; v.u = ((unsigned)h) << 16;
    return v.f;
}
__device__ __forceinline__ float2 upk2(unsigned u) {            // 2x bf16 -> float2
    union { unsigned u; __hip_bfloat162 h; } cv; cv.u = u;
    return __bfloat1622float2(cv.h);
}
__device__ __forceinline__ float exp2_hw(float x) {             // 2^x, single v_exp_f32
    float r; asm("v_exp_f32 %0, %1" : "=v"(r) : "v"(x)); return r;
}
__device__ __forceinline__ void atomic_add_f32(float* p, float v) {
    __hip_atomic_fetch_add(p, v, __ATOMIC_RELAXED, __HIP_MEMORY_SCOPE_AGENT);
}

// ============================================================================
// MFMA helpers (zero-init acc, bias in epilogue — round-2-proven codegen)
// ============================================================================
__device__ __forceinline__ void wave_gemm(const ushortT (*A)[LDSW],
                                          const ushortT* __restrict__ Bp,
                                          int quad, int m16, int lane,
                                          floatx4 acc[8])
{
#pragma unroll
    for (int nt = 0; nt < 8; ++nt) { acc[nt][0]=0.f; acc[nt][1]=0.f; acc[nt][2]=0.f; acc[nt][3]=0.f; }
#pragma unroll 1
    for (int ks = 0; ks < 4; ++ks) {
        const short8 af = *(const short8*)&A[m16][ks * 32 + quad * 8];
        const ushortT* bpk = Bp + (size_t)ks * 4096 + (size_t)lane * 8;
#pragma unroll
        for (int nt = 0; nt < 8; ++nt) {
            const short8 bf = *(const short8*)(bpk + nt * 512);
            acc[nt] = __builtin_amdgcn_mfma_f32_16x16x32_bf16(af, bf, acc[nt], 0, 0, 0);
        }
    }
}

__device__ __forceinline__ void cstore_relu_r(ushortT (*A)[LDSW], floatx4 acc[8],
                                              const float bias[8], int quad, int m16)
{
#pragma unroll
    for (int nt = 0; nt < 8; ++nt) {
        const float b = bias[nt];
#pragma unroll
        for (int r = 0; r < 4; r += 2) {
            const unsigned p = pk2(fmaxf(acc[nt][r] + b, 0.f), fmaxf(acc[nt][r + 1] + b, 0.f));
            A[quad * 4 + r][nt * 16 + m16]     = (ushortT)(p & 0xffffu);
            A[quad * 4 + r + 1][nt * 16 + m16] = (ushortT)(p >> 16);
        }
    }
}

// pack one matrix entry into MFMA B-fragment order
__device__ __forceinline__ ushortT pack_one(const float* __restrict__ W, int u) {
    const int j = u & 7, lane = (u >> 3) & 63, f = u >> 9;  // u in [0,16384)
    const int nt = f & 7, ks = f >> 3;
    const int n = nt * 16 + (lane & 15);
    const int k = ks * 32 + (lane >> 4) * 8 + j;
    return f2bf(W[k * C + n]);
}

// ============================================================================
// prep1 (fused): pack Bpack (edge MLP, aw2 pre-scaled by log2e),
// pack Bpack2 (Wdst,Wsrc,Wlin,Win), pack BpackO (W_out),
// cvt pos->bf16 (float4 vectorized), hist of dst degrees. Block-role ranges.
// ============================================================================
extern "C" __global__ void __launch_bounds__(256)
prep1(const float* __restrict__ pw1, const float* __restrict__ pw2,
      const float* __restrict__ aw1, const float* __restrict__ aw2,
      const float* __restrict__ Wd,  const float* __restrict__ Wsrc,
      const float* __restrict__ Wl,  const float* __restrict__ Win,
      const float* __restrict__ Wout,
      const float* __restrict__ pos, ushortT* __restrict__ pos_bf,
      const int* __restrict__ ei, int* __restrict__ deg,
      ushortT* __restrict__ Bpack, ushortT* __restrict__ Bpack2,
      ushortT* __restrict__ BpackO, int N, int E)
{
    const int nb_cvt = (N * 32 + 255) / 256;
    const int b = blockIdx.x, tid = threadIdx.x;
    if (b < 256) {
        const int t = b * 256 + tid;
        const int s = t >> 14;
        const float* W = (s == 0) ? pw1 : (s == 1) ? pw2 : (s == 2) ? aw1 : aw2;
        const int u = t & 16383;
        const int j = u & 7, lane = (u >> 3) & 63, f = u >> 9;
        const int nt = f & 7, ks = f >> 3;
        const int n = nt * 16 + (lane & 15);
        const int k = ks * 32 + (lane >> 4) * 8 + j;
        float v = W[k * C + n];
        if (s == 3) v *= LOG2E;          // exp2 fold: attn layer-2 in log2 domain
        Bpack[t] = f2bf(v);
    } else if (b < 512) {
        const int t = (b - 256) * 256 + tid;
        const int s = t >> 14;
        const float* W = (s == 0) ? Wd : (s == 1) ? Wsrc : (s == 2) ? Wl : Win;
        Bpack2[t] = pack_one(W, t & 16383);
    } else if (b < 576) {
        const int t = (b - 512) * 256 + tid;     // [0, 16384)
        BpackO[t] = pack_one(Wout, t);
    } else if (b < 576 + nb_cvt) {
        const int i = (b - 576) * 256 + tid;
        if (i < N * 32) {
            const float4 v = ((const float4*)pos)[i];
            uint2 o; o.x = pk2(v.x, v.y); o.y = pk2(v.z, v.w);
            ((uint2*)pos_bf)[i] = o;
        }
    } else {
        const int e = (b - 576 - nb_cvt) * 256 + tid;
        if (e < E) atomicAdd(&deg[ei[E + e]], 1);
    }
}

extern "C" __global__ void __launch_bounds__(1024)
k_scan(const int* __restrict__ deg, int* __restrict__ off, int n)
{
    __shared__ int part[1024];
    const int t = threadIdx.x;
    const int chunk = (((n + 1023) / 1024) + 3) & ~3;      // multiple of 4
    const int lo = t * chunk, hi = min(lo + chunk, n);      // n%4==0 -> hi-lo %4==0
    int s = 0;
    for (int i = lo; i < hi; i += 4) {
        const int4 d4 = *(const int4*)(deg + i);
        s += d4.x + d4.y + d4.z + d4.w;
    }
    part[t] = s;
    __syncthreads();
    for (int d = 1; d < 1024; d <<= 1) {
        int v = (t >= d) ? part[t - d] : 0;
        __syncthreads();
        part[t] += v;
        __syncthreads();
    }
    int run = (t == 0) ? 0 : part[t - 1];
    for (int i = lo; i < hi; i += 4) {
        const int4 d4 = *(const int4*)(deg + i);
        int4 o;
        o.x = run;
        o.y = o.x + d4.x;
        o.z = o.y + d4.y;
        o.w = o.z + d4.z;
        *(int4*)(off + i) = o;
        run = o.w + d4.w;
    }
}

// ============================================================================
// prep2 (fused): node role (all-MFMA qkv + P = pos@pw1 hoist) + scatter role.
// ============================================================================
extern "C" __global__ void __launch_bounds__(256)
prep2(const float* __restrict__ x, const float* __restrict__ b_in,
      const ushortT* __restrict__ Bp2, const ushortT* __restrict__ Bpk,
      const float* __restrict__ pb1, const ushortT* __restrict__ pos_bf,
      ushortT* __restrict__ q_bf, ushortT* __restrict__ k_bf, ushortT* __restrict__ v_bf,
      ushortT* __restrict__ Pd_arr, ushortT* __restrict__ Ps_arr,
      const int* __restrict__ ei, const int* __restrict__ offp, int* __restrict__ curp,
      int* __restrict__ ss, int* __restrict__ sd, int N, int E, int nb_node)
{
    __shared__ ushortT xs[TILE][LDSW];   // 17.4 KB (ostage overlays this)
    __shared__ ushortT hs[TILE][LDSW];   // 17.4 KB
    const int b = blockIdx.x, tx = threadIdx.x;

    if (b >= nb_node) {
        // ---- scatter role ----
        const int e = (b - nb_node) * 256 + tx;
        if (e < E) {
            const int d = ei[E + e];
            const int p = offp[d] + atomicAdd(&curp[d], 1);
            ss[p] = ei[e];
            sd[p] = d;
        }
        return;
    }

    // ---- node role ----
    const int rg = tx >> 5;
    const int oc0 = (tx & 31) << 2;
    const int row0 = b * TILE;

    // stage x -> bf16 (wave-private rows)
#pragma unroll
    for (int j = 0; j < 8; ++j) {
        const int r = rg * 8 + j, n = row0 + r;
        float4 xv; xv.x = xv.y = xv.z = xv.w = 0.f;
        if (n < N) xv = *(const float4*)(x + (size_t)n * C + oc0);
        *(unsigned*)&xs[r][oc0]     = pk2(xv.x, xv.y);
        *(unsigned*)&xs[r][oc0 + 2] = pk2(xv.z, xv.w);
    }

    const int wv = tx >> 6, lane = tx & 63;
    const int quad = lane >> 4, m16 = lane & 15;
    const int row = lane >> 2, li = lane & 3;

    float binv[8];
#pragma unroll
    for (int nt = 0; nt < 8; ++nt) binv[nt] = b_in[nt * 16 + m16];

    const ushortT (*Ax)[LDSW] = (const ushortT (*)[LDSW])&xs[wv * 16];
    ushortT (*Ah)[LDSW] = (ushortT (*)[LDSW])&hs[wv * 16];

    floatx4 macc[8];
    // h = relu(x @ W_in + b_in)   (W_in in Bpack2 slot 3)
    wave_gemm(Ax, Bp2 + (size_t)3 * 16384, quad, m16, lane, macc);
    cstore_relu_r(Ah, macc, binv, quad, m16);

    __syncthreads();   // all xs reads done before ostage overlay is written

    ushortT (*OS)[LDSW] = (ushortT (*)[LDSW])&xs[wv * 16];   // ostage overlay
    ushortT* outs[3];
    outs[0] = q_bf; outs[1] = k_bf; outs[2] = v_bf;

    const int nrow = row0 + wv * 16 + row;

#pragma unroll 1
    for (int m = 0; m < 3; ++m) {
        wave_gemm((const ushortT (*)[LDSW])Ah, Bp2 + (size_t)m * 16384, quad, m16, lane, macc);
#pragma unroll
        for (int nt = 0; nt < 8; ++nt) {
#pragma unroll
            for (int r = 0; r < 4; r += 2) {
                const unsigned p = pk2(macc[nt][r], macc[nt][r + 1]);
                OS[quad * 4 + r][nt * 16 + m16]     = (ushortT)(p & 0xffffu);
                OS[quad * 4 + r + 1][nt * 16 + m16] = (ushortT)(p >> 16);
            }
        }
        if (nrow < N) {
#pragma unroll
            for (int i = 0; i < 4; ++i) {
                const ushort8 v8 = *(const ushort8*)&OS[row][i * 32 + li * 8];
                *(ushort8*)(outs[m] + (size_t)nrow * C + i * 32 + li * 8) = v8;
            }
        }
    }

    // ---- P = pos @ pw1 (hoisted pos_nn layer-1 GEMM) ----
    __syncthreads();   // hs reads (gemms) + OS reads (stores) all complete
    {
        const ushortT* srcp = pos_bf + (size_t)min(nrow, N - 1) * C;
#pragma unroll
        for (int i = 0; i < 4; ++i) {
            const ushort8 v8 = *(const ushort8*)(srcp + i * 32 + li * 8);
            *(ushort8*)&hs[wv * 16 + row][i * 32 + li * 8] = v8;
        }
    }
    __syncthreads();
    wave_gemm((const ushortT (*)[LDSW])Ah, Bpk /*slot 0 = pw1*/, quad, m16, lane, macc);

    float b1v[8];
#pragma unroll
    for (int nt = 0; nt < 8; ++nt) b1v[nt] = pb1[nt * 16 + m16];

    // pass 1: Pd = P + b1
#pragma unroll
    for (int nt = 0; nt < 8; ++nt) {
#pragma unroll
        for (int r = 0; r < 4; r += 2) {
            const unsigned p = pk2(macc[nt][r] + b1v[nt], macc[nt][r + 1] + b1v[nt]);
            OS[quad * 4 + r][nt * 16 + m16]     = (ushortT)(p & 0xffffu);
            OS[quad * 4 + r + 1][nt * 16 + m16] = (ushortT)(p >> 16);
        }
    }
    if (nrow < N) {
#pragma unroll
        for (int i = 0; i < 4; ++i) {
            const ushort8 v8 = *(const ushort8*)&OS[row][i * 32 + li * 8];
            *(ushort8*)(Pd_arr + (size_t)nrow * C + i * 32 + li * 8) = v8;
        }
    }
    __syncthreads();
    // pass 2: Ps = P
#pragma unroll
    for (int nt = 0; nt < 8; ++nt) {
#pragma unroll
        for (int r = 0; r < 4; r += 2) {
            const unsigned p = pk2(macc[nt][r], macc[nt][r + 1]);
            OS[quad * 4 + r][nt * 16 + m16]     = (ushortT)(p & 0xffffu);
            OS[quad * 4 + r + 1][nt * 16 + m16] = (ushortT)(p >> 16);
        }
    }
    if (nrow < N) {
#pragma unroll
        for (int i = 0; i < 4; ++i) {
            const ushort8 v8 = *(const ushort8*)&OS[row][i * 32 + li * 8];
            *(ushort8*)(Ps_arr + (size_t)nrow * C + i * 32 + li * 8) = v8;
        }
    }
}

// ============================================================================
// kernel 2 (MFMA): edges SORTED BY DST; segmented-scan epilogue.
// 2-wave blocks (LDS 17.5 KB -> residency test). Dslab LDS broadcast for the
// scan dst sequence (round-6-proven; readlane variant failed correctness).
// ============================================================================
__device__ __forceinline__ void gather4(const ushortT* __restrict__ base, int node, int li,
                                        ushort8 dst[4])
{
    const ushort8* p = (const ushort8*)(base + (size_t)node * C) + li;
    dst[0] = p[0]; dst[1] = p[4]; dst[2] = p[8]; dst[3] = p[12];   // chunk i at ushort8 index i*4+li
}

extern "C" __global__ void __launch_bounds__(ETHREADS)
edge_mfma(const ushortT* __restrict__ Pd_arr, const ushortT* __restrict__ Ps_arr,
          const int* __restrict__ ss, const int* __restrict__ sd,
          const ushortT* __restrict__ q_bf, const ushortT* __restrict__ k_bf,
          const ushortT* __restrict__ v_bf, const ushortT* __restrict__ Bpack,
          const float* __restrict__ pb2,
          const float* __restrict__ ab1, const float* __restrict__ ab2,
          float* __restrict__ z, float* __restrict__ aggU, int E)
{
    __shared__ ushortT Aslab[EWPB][EPW][LDSW];   // 8.7 KB
    __shared__ ushortT Vslab[EWPB][EPW][LDSW];   // 8.7 KB
    __shared__ int     Dslab[EWPB][EPW];         // 128 B
    const int tid = threadIdx.x;
    const int wv = tid >> 6, lane = tid & 63;
    const int quad = lane >> 4, m16 = lane & 15;
    const int row = lane >> 2, li = lane & 3;      // line-coherent staging mapping
    ushortT (*A)[LDSW] = Aslab[wv];
    ushortT (*V)[LDSW] = Vslab[wv];

    float pb2v[8], ab1v[8], ab2v[8];
#pragma unroll
    for (int nt = 0; nt < 8; ++nt) {
        pb2v[nt] = pb2[nt * 16 + m16];
        ab1v[nt] = ab1[nt * 16 + m16];
        ab2v[nt] = ab2[nt * 16 + m16] * LOG2E;     // log2-domain bias
    }

    const ushortT* B1 = Bpack + 16384;
    const ushortT* B2 = Bpack + 32768;
    const ushortT* B3 = Bpack + 49152;

    const int wave_base = (blockIdx.x * EWPB + wv) * (GTILES * EPW);

    const int c2 = lane * 2;
    int   cur_dst = -1;
    float zs0 = 0.f, zs1 = 0.f, gs0 = 0.f, gs1 = 0.f;

    // ---- prologue: indices for tile 0 ----
    int es, ed, sdr[4];
    {
        const int eidx = min(wave_base + row, E - 1);
        es = ss[eidx]; ed = sd[eidx];
#pragma unroll
        for (int r = 0; r < 4; ++r)
            sdr[r] = sd[min(wave_base + quad * 4 + r, E - 1)];
    }

#pragma unroll 1
    for (int t = 0; t < GTILES; ++t) {
        const int e_base = wave_base + t * EPW;
        if (m16 == 0) {
#pragma unroll
            for (int r = 0; r < 4; ++r) Dslab[wv][quad * 4 + r] = sdr[r];
        }

        ushort8 Pd[4], Ps[4], Qv[4], Kv[4], Vv[4];
        gather4(Pd_arr, ed, li, Pd); gather4(Ps_arr, es, li, Ps);
        gather4(q_bf,  ed, li, Qv); gather4(k_bf,  es, li, Kv);
        gather4(v_bf,  es, li, Vv);

        // ---- A1 = relu(Pd[dst] - Ps[src])  (pos_nn layer 1, hoisted GEMM);
        //      stage v into Vslab ----
#pragma unroll
        for (int i = 0; i < 4; ++i) {
            const uintx4 pd = *(const uintx4*)&Pd[i];
            const uintx4 ps = *(const uintx4*)&Ps[i];
            uintx4 o;
#pragma unroll
            for (int w = 0; w < 4; ++w) {
                const float2 a = upk2(pd[w]), b = upk2(ps[w]);
                o[w] = pk2(fmaxf(a.x - b.x, 0.f), fmaxf(a.y - b.y, 0.f));
            }
            *(uintx4*)&A[row][i * 32 + li * 8] = o;
            *(ushort8*)&V[row][i * 32 + li * 8] = Vv[i];
        }

        floatx4 acc[8];

        // ---- pos_nn layer 2 -> delta (packed regs + slab) ----
        wave_gemm(A, B1, quad, m16, lane, acc);
        unsigned dlp[8][2];
#pragma unroll
        for (int nt = 0; nt < 8; ++nt) {
            const float b = pb2v[nt];
            const unsigned p0 = pk2(fmaxf(acc[nt][0] + b, 0.f), fmaxf(acc[nt][1] + b, 0.f));
            const unsigned p1 = pk2(fmaxf(acc[nt][2] + b, 0.f), fmaxf(acc[nt][3] + b, 0.f));
            dlp[nt][0] = p0; dlp[nt][1] = p1;
            A[quad * 4 + 0][nt * 16 + m16] = (ushortT)(p0 & 0xffffu);
            A[quad * 4 + 1][nt * 16 + m16] = (ushortT)(p0 >> 16);
            A[quad * 4 + 2][nt * 16 + m16] = (ushortT)(p1 & 0xffffu);
            A[quad * 4 + 3][nt * 16 + m16] = (ushortT)(p1 >> 16);
        }

        // ---- A2 = bf16( q[dst] - k[src] + delta ) ----
#pragma unroll
        for (int i = 0; i < 4; ++i) {
            const uintx4 dv = *(const uintx4*)&A[row][i * 32 + li * 8];
            const uintx4 qv = *(const uintx4*)&Qv[i];
            const uintx4 kv = *(const uintx4*)&Kv[i];
            uintx4 o;
#pragma unroll
            for (int w = 0; w < 4; ++w) {
                const float2 qq = upk2(qv[w]), kk = upk2(kv[w]), dd = upk2(dv[w]);
                o[w] = pk2(qq.x - kk.x + dd.x, qq.y - kk.y + dd.y);
            }
            *(uintx4*)&A[row][i * 32 + li * 8] = o;
        }

        // ---- prefetch next tile's indices (hides under attn MFMAs + scan) ----
        int nes = es, ned = ed, nsdr[4];
#pragma unroll
        for (int r = 0; r < 4; ++r) nsdr[r] = sdr[r];
        if (t + 1 < GTILES) {
            const int e2 = e_base + EPW;
            const int ei2 = min(e2 + row, E - 1);
            nes = ss[ei2]; ned = sd[ei2];
#pragma unroll
            for (int r = 0; r < 4; ++r)
                nsdr[r] = sd[min(e2 + quad * 4 + r, E - 1)];
        }

        // ---- attn_nn layer 1 ----
        wave_gemm(A, B2, quad, m16, lane, acc);
        cstore_relu_r(A, acc, ab1v, quad, m16);

        // ---- attn_nn layer 2 (log2 domain) -> ea = exp2(relu(alpha'+b')) ----
        wave_gemm(A, B3, quad, m16, lane, acc);
#pragma unroll
        for (int nt = 0; nt < 8; ++nt) {
            const float b = ab2v[nt];
#pragma unroll
            for (int r = 0; r < 4; ++r)
                acc[nt][r] = exp2_hw(fmaxf(acc[nt][r] + b, 0.f));  // == exp(relu(alpha))
        }

        // ---- zero ea for out-of-range (clamped duplicate) edges ----
        if (e_base + EPW > E) {
#pragma unroll
            for (int r = 0; r < 4; ++r)
                if (e_base + quad * 4 + r >= E) {
#pragma unroll
                    for (int nt = 0; nt < 8; ++nt) acc[nt][r] = 0.f;
                }
        }

        // ---- transpose: A <- ea (bf16), V <- v+delta (bf16), edge-major ----
#pragma unroll
        for (int nt = 0; nt < 8; ++nt) {
#pragma unroll
            for (int r = 0; r < 4; ++r) {
                const float2 dpair = upk2(dlp[nt][r >> 1]);
                const float dlv = (r & 1) ? dpair.y : dpair.x;
                const int ridx = quad * 4 + r, cidx = nt * 16 + m16;
                const float vv = bf2f(V[ridx][cidx]);
                V[ridx][cidx] = f2bf(vv + dlv);
                A[ridx][cidx] = f2bf(acc[nt][r]);
            }
        }

        // ---- per-lane segmented scan over the 16 sorted edges ----
#pragma unroll 4
        for (int e = 0; e < EPW; ++e) {
            const int d = Dslab[wv][e];
            const float2 ea2 = upk2(*(const unsigned*)&A[e][c2]);
            const float2 vp2 = upk2(*(const unsigned*)&V[e][c2]);
            if (d != cur_dst) {
                if (cur_dst >= 0) {
                    float* zp = z    + (size_t)cur_dst * C + c2;
                    float* gp = aggU + (size_t)cur_dst * C + c2;
                    atomic_add_f32(zp,     zs0);
                    atomic_add_f32(zp + 1, zs1);
                    atomic_add_f32(gp,     gs0);
                    atomic_add_f32(gp + 1, gs1);
                }
                cur_dst = d;
                zs0 = ea2.x;           zs1 = ea2.y;
                gs0 = ea2.x * vp2.x;   gs1 = ea2.y * vp2.y;
            } else {
                zs0 += ea2.x;                   zs1 += ea2.y;
                gs0 = fmaf(ea2.x, vp2.x, gs0);  gs1 = fmaf(ea2.y, vp2.y, gs1);
            }
        }

        // rotate prefetched indices
        es = nes; ed = ned;
#pragma unroll
        for (int r = 0; r < 4; ++r) sdr[r] = nsdr[r];
    }

    // ---- final flush ----
    if (cur_dst >= 0) {
        float* zp = z    + (size_t)cur_dst * C + c2;
        float* gp = aggU + (size_t)cur_dst * C + c2;
        atomic_add_f32(zp,     zs0);
        atomic_add_f32(zp + 1, zs1);
        atomic_add_f32(gp,     gs0);
        atomic_add_f32(gp + 1, gs1);
    }
}

// ============================================================================
// kernel 3 (MFMA): out = relu( bf16(aggU/(z+1e-16)) @ W_out + b_out )
// ============================================================================
extern "C" __global__ void __launch_bounds__(THREADS)
out_kernel(const float* __restrict__ aggU, const float* __restrict__ z,
           const ushortT* __restrict__ BpO, const float* __restrict__ b_out,
           float* __restrict__ out, int N)
{
    __shared__ ushortT us[TILE][LDSW];   // 17.4 KB
    const int tx = threadIdx.x;
    const int rg = tx >> 5;
    const int oc0 = (tx & 31) << 2;
    const int row0 = blockIdx.x * TILE;

#pragma unroll
    for (int j = 0; j < 8; ++j) {
        const int r = rg * 8 + j, n = row0 + r;
        float4 a; a.x = a.y = a.z = a.w = 0.f;
        if (n < N) {
            const float4 g  = *(const float4*)(aggU + (size_t)n * C + oc0);
            const float4 zz = *(const float4*)(z    + (size_t)n * C + oc0);
            a.x = g.x / (zz.x + 1e-16f);
            a.y = g.y / (zz.y + 1e-16f);
            a.z = g.z / (zz.z + 1e-16f);
            a.w = g.w / (zz.w + 1e-16f);
        }
        *(unsigned*)&us[r][oc0]     = pk2(a.x, a.y);
        *(unsigned*)&us[r][oc0 + 2] = pk2(a.z, a.w);
    }
    // rows rg*8+j are wave-private (rg in {2wv,2wv+1}) -> no barrier

    const int wv = tx >> 6, lane = tx & 63;
    const int quad = lane >> 4, m16 = lane & 15;

    floatx4 macc[8];
    wave_gemm((const ushortT (*)[LDSW])&us[wv * 16], BpO, quad, m16, lane, macc);

    float bo[8];
#pragma unroll
    for (int nt = 0; nt < 8; ++nt) bo[nt] = b_out[nt * 16 + m16];

#pragma unroll
    for (int r = 0; r < 4; ++r) {
        const int n = row0 + wv * 16 + quad * 4 + r;
        if (n < N) {
            float* op = out + (size_t)n * C + m16;
#pragma unroll
            for (int nt = 0; nt < 8; ++nt)
                op[nt * 16] = fmaxf(macc[nt][r] + bo[nt], 0.f);
        }
    }
}

// ---------------------------------------------------------------------------
extern "C" void kernel_launch(void* const* d_in, const int* in_sizes, int n_in,
                              void* d_out, int out_size, void* d_ws, size_t ws_size,
                              hipStream_t stream)
{
    const float* x     = (const float*)d_in[0];
    const float* pos   = (const float*)d_in[1];
    const int*   ei    = (const int*)  d_in[2];
    const float* W_in  = (const float*)d_in[3];
    const float* b_in  = (const float*)d_in[4];
    const float* W_lin = (const float*)d_in[5];
    const float* W_src = (const float*)d_in[6];
    const float* W_dst = (const float*)d_in[7];
    const float* pw1   = (const float*)d_in[8];
    const float* pb1   = (const float*)d_in[9];
    const float* pw2   = (const float*)d_in[10];
    const float* pb2   = (const float*)d_in[11];
    const float* aw1   = (const float*)d_in[12];
    const float* ab1   = (const float*)d_in[13];
    const float* aw2   = (const float*)d_in[14];
    const float* ab2   = (const float*)d_in[15];
    const float* W_out = (const float*)d_in[16];
    const float* b_out = (const float*)d_in[17];

    const int N = in_sizes[0] / C;
    const int E = in_sizes[2] / 2;
    const size_t NC = (size_t)N * C;

    // workspace layout — ALL gathered bf16 arrays 256-B aligned:
    //   z | aggU | q | k | v | Pd | Ps | pos_bf | Bpack | Bpack2 | BpackO |
    //   deg | cur | off | ss | sd
    float*   z      = (float*)d_ws;                          // [N,C] fp32
    float*   aggU   = z + NC;                                // [N,C] fp32
    ushortT* q_bf   = (ushortT*)(aggU + NC);                 // [N,C] bf16 (256B-aligned)
    ushortT* k_bf   = q_bf + NC;
    ushortT* v_bf   = k_bf + NC;
    ushortT* Pd_arr = v_bf + NC;                             // [N,C] bf16: pos@pw1 + pb1
    ushortT* Ps_arr = Pd_arr + NC;                           // [N,C] bf16: pos@pw1
    ushortT* pos_bf = Ps_arr + NC;
    ushortT* Bpack  = pos_bf + NC;                           // 65536 bf16 (edge MLP weights)
    ushortT* Bpack2 = Bpack + 65536;                         // 65536 bf16 (Wdst,Wsrc,Wlin,Win)
    ushortT* BpackO = Bpack2 + 65536;                        // 16384 bf16 (W_out)
    int*     deg    = (int*)(BpackO + 16384);                // [N]
    int*     curp   = deg + N;                               // [N]
    int*     offp   = curp + N;                              // [N]
    int*     ss     = offp + N;                              // [E] sorted src
    int*     sdst   = ss + E;                                // [E] sorted dst

    hipMemsetAsync(z, 0, 2 * NC * sizeof(float), stream);
    hipMemsetAsync(deg, 0, 2 * (size_t)N * sizeof(int), stream);  // deg + cur

    const int nb_cvt  = (N * 32 + 255) / 256;
    const int nb_hist = (E + 255) / 256;
    prep1<<<576 + nb_cvt + nb_hist, 256, 0, stream>>>(pw1, pw2, aw1, aw2,
                                                      W_dst, W_src, W_lin, W_in, W_out,
                                                      pos, pos_bf, ei, deg,
                                                      Bpack, Bpack2, BpackO, N, E);

    k_scan<<<1, 1024, 0, stream>>>(deg, offp, N);

    const int nb = (N + TILE - 1) / TILE;
    prep2<<<nb + nb_hist, 256, 0, stream>>>(x, b_in, Bpack2, Bpack, pb1, pos_bf,
                                            q_bf, k_bf, v_bf, Pd_arr, Ps_arr,
                                            ei, offp, curp, ss, sdst, N, E, nb);

    const int edges_per_block = EWPB * GTILES * EPW;         // 256
    const int eb = (E + edges_per_block - 1) / edges_per_block;
    edge_mfma<<<eb, ETHREADS, 0, stream>>>(Pd_arr, Ps_arr, ss, sdst, q_bf, k_bf, v_bf, Bpack,
                                           pb2, ab1, ab2, z, aggU, E);
    out_kernel<<<nb, THREADS, 0, stream>>>(aggU, z, BpackO, b_out, (float*)d_out, N);
}